// Round 6
// baseline (971.687 us; speedup 1.0000x reference)
//
#include <hip/hip_runtime.h>
#include <math.h>

#define SCHUNK 2048
#define PCH 128

typedef __bf16 bf16x8 __attribute__((ext_vector_type(8)));
typedef __bf16 bf16x4 __attribute__((ext_vector_type(4)));
typedef float f32x4 __attribute__((ext_vector_type(4)));

#define MFMA16(a, b, c) __builtin_amdgcn_mfma_f32_16x16x32_bf16(a, b, c, 0, 0, 0)

// weight pool offsets (elements)
#define OFF_KJ    0
#define OFF_JI    16384
#define OFF_DOWN  32768
#define OFF_UP    40960
#define OFF_RB0   49152
#define OFF_RB1   65536
#define OFF_LIN   81920
#define OFF_RA00  98304
#define OFF_RA01  114688
#define OFF_RA10  131072
#define OFF_RA11  147456

__device__ __forceinline__ float silu_f(float v) {
    return v * __builtin_amdgcn_rcpf(1.0f + __expf(-v));
}

// ---------------------------------------------------------------------------
// Wave GEMM: NB row-bands (16 rows each) x NT col-tiles (16 cols), K contraction.
// At: LDS bf16, row stride STRIDE, swizzle (c ^ ((r&7)<<3)).
// Wf: fragment-ordered weights: Wf[((kc*NTOT + ct)*64 + lane)*8 + j] =
//     W[kc*32 + (lane>>4)*8 + j][ct*16 + (lane&15)]  -> 1KB coalesced per load.
// acc[t*NB + s]: C-frag rows s*16 + (lane>>4)*4 + j, col (ct0+t)*16 + (lane&15)
// ---------------------------------------------------------------------------
template<int K, int NT, int NB, int STRIDE, int NTOT>
__device__ __forceinline__ void wgemm(const __bf16* __restrict__ At,
                                      const __bf16* __restrict__ Wf,
                                      int ct0, int lane, f32x4* __restrict__ acc) {
#pragma unroll
    for (int i = 0; i < NT * NB; ++i) acc[i] = (f32x4){0.f, 0.f, 0.f, 0.f};
    const int rl = lane & 15;
    const int kq = (lane >> 4) * 8;
    const int sw = (rl & 7) << 3;
#pragma unroll
    for (int kc = 0; kc < K / 32; ++kc) {
        const int k0 = kc * 32 + kq;
        bf16x8 a[NB];
#pragma unroll
        for (int s = 0; s < NB; ++s)
            a[s] = *(const bf16x8*)&At[(rl + 16 * s) * STRIDE + (k0 ^ sw)];
#pragma unroll
        for (int t = 0; t < NT; ++t) {
            bf16x8 b = *(const bf16x8*)&Wf[(size_t)((kc * NTOT + ct0 + t) * 64 + lane) * 8];
#pragma unroll
            for (int s = 0; s < NB; ++s)
                acc[t * NB + s] = MFMA16(a[s], b, acc[t * NB + s]);
        }
    }
}

// stage 64 x COLS f32 rows -> LDS bf16 swizzled tile, row stride 128
template<int COLS>
__device__ __forceinline__ void stage(const float* __restrict__ g, long grow0,
                                      int vr, __bf16* __restrict__ At, int tid) {
    constexpr int QUADS = COLS / 4;
#pragma unroll
    for (int i = tid; i < 64 * QUADS; i += 256) {
        int r = i / QUADS, q = i - r * QUADS;
        float4 v = make_float4(0.f, 0.f, 0.f, 0.f);
        if (r < vr) v = *(const float4*)&g[(grow0 + r) * (size_t)COLS + q * 4];
        bf16x4 w; w[0] = (__bf16)v.x; w[1] = (__bf16)v.y; w[2] = (__bf16)v.z; w[3] = (__bf16)v.w;
        *(bf16x4*)&At[r * 128 + ((q * 4) ^ ((r & 7) << 3))] = w;
    }
}

// At <- silu(acc + b)
__device__ __forceinline__ void epi_store(__bf16* __restrict__ At, const f32x4* __restrict__ acc,
                                          const float* __restrict__ bias, int lane, int colbase) {
    const int rl = lane & 15, rg = (lane >> 4) << 2;
#pragma unroll
    for (int t = 0; t < 2; ++t) {
        const int col = colbase + t * 16 + rl;
        const float bv = bias[col];
#pragma unroll
        for (int s = 0; s < 4; ++s)
#pragma unroll
            for (int j = 0; j < 4; ++j) {
                const int row = s * 16 + rg + j;
                At[row * 128 + (col ^ ((row & 7) << 3))] = (__bf16)silu_f(acc[t * 4 + s][j] + bv);
            }
    }
}

// hreg += silu(acc + b); optionally At <- bf16(hreg)
template<bool WRITE>
__device__ __forceinline__ void epi_add(__bf16* __restrict__ At, f32x4* __restrict__ hreg,
                                        const f32x4* __restrict__ acc,
                                        const float* __restrict__ bias, int lane, int colbase) {
    const int rl = lane & 15, rg = (lane >> 4) << 2;
#pragma unroll
    for (int t = 0; t < 2; ++t) {
        const int col = colbase + t * 16 + rl;
        const float bv = bias[col];
#pragma unroll
        for (int s = 0; s < 4; ++s)
#pragma unroll
            for (int j = 0; j < 4; ++j) {
                const int row = s * 16 + rg + j;
                float v = hreg[t * 4 + s][j] + silu_f(acc[t * 4 + s][j] + bv);
                hreg[t * 4 + s][j] = v;
                if (WRITE) At[row * 128 + (col ^ ((row & 7) << 3))] = (__bf16)v;
            }
    }
}

// ---------------------------------------------------------------------------
// weight prep: wcrT[128][8]; wc_sbf[42][64] f32 (fallback); wcsb fragment-order
// ---------------------------------------------------------------------------
__global__ void kweights(const float* __restrict__ W_rbf1, const float* __restrict__ W_rbf2,
                         const float* __restrict__ W_sbf1, const float* __restrict__ W_sbf2,
                         float* __restrict__ wcrT, float* __restrict__ wc_sbf,
                         __bf16* __restrict__ wcsb) {
    int tid = blockIdx.x * blockDim.x + threadIdx.x;
    int nt = blockDim.x * gridDim.x;
    for (int idx = tid; idx < 128 * 8; idx += nt) {
        int c = idx >> 3, s = idx & 7;
        float v = 0.f;
        if (s < 6) {
#pragma unroll
            for (int b = 0; b < 8; ++b) v += W_rbf1[s * 8 + b] * W_rbf2[b * 128 + c];
        }
        wcrT[idx] = v;
    }
    for (int idx = tid; idx < 42 * 64; idx += nt) {
        int r = idx / 64, c = idx - r * 64;
        float s = 0.f;
#pragma unroll
        for (int b = 0; b < 8; ++b) s += W_sbf1[r * 8 + b] * W_sbf2[b * 64 + c];
        wc_sbf[idx] = s;
    }
    // wcsb fragment order: K=64 (pad from 42), N=64, NTOT=4
    for (int idx = tid; idx < 4096; idx += nt) {
        int j = idx & 7, l = (idx >> 3) & 63, r2 = idx >> 9;
        int ct = r2 & 3, kc = r2 >> 2;
        int k = kc * 32 + ((l >> 4) << 3) + j;
        int c = ct * 16 + (l & 15);
        float v = 0.f;
        if (k < 42) {
#pragma unroll
            for (int b = 0; b < 8; ++b) v += W_sbf1[k * 8 + b] * W_sbf2[b * 64 + c];
        }
        wcsb[idx] = (__bf16)v;
    }
}

// fragment-order weight conversion
__global__ void ktrans(const float* __restrict__ W_kj, const float* __restrict__ W_ji,
                       const float* __restrict__ W_down, const float* __restrict__ W_up,
                       const float* __restrict__ W_rb, const float* __restrict__ W_lin,
                       const float* __restrict__ W_ra, __bf16* __restrict__ wt) {
    const float* src; __bf16* dst; int K, N;
    switch (blockIdx.y) {
        case 0:  src = W_kj;          dst = wt + OFF_KJ;    K = 128; N = 128; break;
        case 1:  src = W_ji;          dst = wt + OFF_JI;    K = 128; N = 128; break;
        case 2:  src = W_down;        dst = wt + OFF_DOWN;  K = 128; N = 64;  break;
        case 3:  src = W_up;          dst = wt + OFF_UP;    K = 64;  N = 128; break;
        case 4:  src = W_rb;          dst = wt + OFF_RB0;   K = 128; N = 128; break;
        case 5:  src = W_rb + 16384;  dst = wt + OFF_RB1;   K = 128; N = 128; break;
        case 6:  src = W_lin;         dst = wt + OFF_LIN;   K = 128; N = 128; break;
        case 7:  src = W_ra;          dst = wt + OFF_RA00;  K = 128; N = 128; break;
        case 8:  src = W_ra + 16384;  dst = wt + OFF_RA01;  K = 128; N = 128; break;
        case 9:  src = W_ra + 32768;  dst = wt + OFF_RA10;  K = 128; N = 128; break;
        default: src = W_ra + 49152;  dst = wt + OFF_RA11;  K = 128; N = 128; break;
    }
    const int ntot = N / 16;
    for (int i = blockIdx.x * blockDim.x + threadIdx.x; i < K * N; i += gridDim.x * blockDim.x) {
        int j = i & 7, l = (i >> 3) & 63, r2 = i >> 9;
        int ct = r2 % ntot, kc = r2 / ntot;
        int k = kc * 32 + ((l >> 4) << 3) + j;
        int n = ct * 16 + (l & 15);
        dst[i] = (__bf16)src[(size_t)k * N + n];
    }
}

// ---------------------------------------------------------------------------
// pre phase: xkd = silu( (silu(x@W_kj+b_kj) * (rbf@Wc_rbf)) @ W_down )  [E,64]
// 64 rows/block, 4 waves x 32 cols, double-buffered LDS
// ---------------------------------------------------------------------------
__global__ __launch_bounds__(256, 4) void kpre_m(
        const float* __restrict__ x, const float* __restrict__ rbf,
        const __bf16* __restrict__ wt, const float* __restrict__ b_kj,
        const float* __restrict__ wcrT, float* __restrict__ xkd, int E) {
    __shared__ __bf16 A0[64 * 128];
    __shared__ __bf16 A1[64 * 128];
    __shared__ float rbt[64 * 8];
    const int tid = threadIdx.x, lane = tid & 63, wv = tid >> 6;
    const int colbase = wv * 32;
    const long r0 = (long)blockIdx.x * 64;
    if (r0 >= E) return;
    const int vr = (E - r0) < 64 ? (int)(E - r0) : 64;
    const int rl = lane & 15, rg = (lane >> 4) << 2;

    stage<128>(x, r0, vr, A0, tid);
    for (int i = tid; i < 64 * 8; i += 256) {
        int r = i >> 3, s = i & 7;
        rbt[i] = (s < 6 && r < vr) ? rbf[(r0 + r) * 6 + s] : 0.f;
    }
    __syncthreads();

    f32x4 acc[8];
    wgemm<128, 2, 4, 128, 8>(A0, wt + OFF_KJ, wv * 2, lane, acc);

    float wv6[2][6];
#pragma unroll
    for (int t = 0; t < 2; ++t) {
        const int col = colbase + t * 16 + rl;
#pragma unroll
        for (int s = 0; s < 6; ++s) wv6[t][s] = wcrT[col * 8 + s];
    }
#pragma unroll
    for (int s = 0; s < 4; ++s)
#pragma unroll
        for (int j = 0; j < 4; ++j) {
            const int row = s * 16 + rg + j;
            float4 r4 = *(const float4*)&rbt[row * 8];
            float2 r2 = *(const float2*)&rbt[row * 8 + 4];
#pragma unroll
            for (int t = 0; t < 2; ++t) {
                const int col = colbase + t * 16 + rl;
                float re = r4.x * wv6[t][0] + r4.y * wv6[t][1] + r4.z * wv6[t][2]
                         + r4.w * wv6[t][3] + r2.x * wv6[t][4] + r2.y * wv6[t][5];
                float v = silu_f(acc[t * 4 + s][j] + b_kj[col]) * re;
                A1[row * 128 + (col ^ ((row & 7) << 3))] = (__bf16)v;
            }
        }
    __syncthreads();

    f32x4 acc2[4];
    wgemm<128, 1, 4, 128, 4>(A1, wt + OFF_DOWN, wv, lane, acc2);
    const int col = wv * 16 + rl;
#pragma unroll
    for (int s = 0; s < 4; ++s)
#pragma unroll
        for (int j = 0; j < 4; ++j) {
            const int row = s * 16 + rg + j;
            if (row < vr) xkd[(r0 + row) * 64 + col] = silu_f(acc2[s][j]);
        }
}

// ---------------------------------------------------------------------------
// post phase: 9 GEMMs, 1 barrier each (A0/A1 ping-pong)
// ---------------------------------------------------------------------------
__global__ __launch_bounds__(256, 4) void kpost_m(
        const float* __restrict__ x, const float* __restrict__ agg,
        const __bf16* __restrict__ wt, const float* __restrict__ b_ji,
        const float* __restrict__ b_rb, const float* __restrict__ b_lin,
        const float* __restrict__ b_ra, float* __restrict__ out, int E) {
    __shared__ __bf16 A0[64 * 128];
    __shared__ __bf16 A1[64 * 128];
    const int tid = threadIdx.x, lane = tid & 63, wv = tid >> 6;
    const int colbase = wv * 32;
    const long r0 = (long)blockIdx.x * 64;
    if (r0 >= E) return;
    const int vr = (E - r0) < 64 ? (int)(E - r0) : 64;
    const int rl = lane & 15, rg = (lane >> 4) << 2;
    f32x4 acc[8], hreg[8];

    stage<64>(agg, r0, vr, A0, tid);
    stage<128>(x, r0, vr, A1, tid);
    __syncthreads();

    // hreg = silu(agg @ W_up); acc = x @ W_ji
    wgemm<64, 2, 4, 128, 8>(A0, wt + OFF_UP, wv * 2, lane, acc);
#pragma unroll
    for (int i = 0; i < 8; ++i)
#pragma unroll
        for (int j = 0; j < 4; ++j) hreg[i][j] = silu_f(acc[i][j]);
    wgemm<128, 2, 4, 128, 8>(A1, wt + OFF_JI, wv * 2, lane, acc);
    __syncthreads();
    epi_add<true>(A0, hreg, acc, b_ji, lane, colbase);   // A0 <- h
    __syncthreads();

    // res_before
    wgemm<128, 2, 4, 128, 8>(A0, wt + OFF_RB0, wv * 2, lane, acc);
    epi_store(A1, acc, b_rb, lane, colbase);
    __syncthreads();
    wgemm<128, 2, 4, 128, 8>(A1, wt + OFF_RB1, wv * 2, lane, acc);
    epi_add<true>(A0, hreg, acc, b_rb + 128, lane, colbase);
    __syncthreads();

    // h = silu(h @ W_lin + b_lin) + x
    wgemm<128, 2, 4, 128, 8>(A0, wt + OFF_LIN, wv * 2, lane, acc);
#pragma unroll
    for (int t = 0; t < 2; ++t) {
        const int col = colbase + t * 16 + rl;
        const float bv = b_lin[col];
#pragma unroll
        for (int s = 0; s < 4; ++s)
#pragma unroll
            for (int j = 0; j < 4; ++j) {
                const int row = s * 16 + rg + j;
                float xv = (row < vr) ? x[(r0 + row) * 128 + col] : 0.f;
                float v = silu_f(acc[t * 4 + s][j] + bv) + xv;
                hreg[t * 4 + s][j] = v;
                A1[row * 128 + (col ^ ((row & 7) << 3))] = (__bf16)v;
            }
    }
    __syncthreads();

    // res_after layer 0
    wgemm<128, 2, 4, 128, 8>(A1, wt + OFF_RA00, wv * 2, lane, acc);
    epi_store(A0, acc, b_ra, lane, colbase);
    __syncthreads();
    wgemm<128, 2, 4, 128, 8>(A0, wt + OFF_RA01, wv * 2, lane, acc);
    epi_add<true>(A1, hreg, acc, b_ra + 128, lane, colbase);
    __syncthreads();

    // res_after layer 1
    wgemm<128, 2, 4, 128, 8>(A1, wt + OFF_RA10, wv * 2, lane, acc);
    epi_store(A0, acc, b_ra + 256, lane, colbase);
    __syncthreads();
    wgemm<128, 2, 4, 128, 8>(A0, wt + OFF_RA11, wv * 2, lane, acc);
    epi_add<false>(nullptr, hreg, acc, b_ra + 384, lane, colbase);

    // out <- hreg
#pragma unroll
    for (int t = 0; t < 2; ++t) {
        const int col = colbase + t * 16 + rl;
#pragma unroll
        for (int s = 0; s < 4; ++s)
#pragma unroll
            for (int j = 0; j < 4; ++j) {
                const int row = s * 16 + rg + j;
                if (row < vr) out[(r0 + row) * 128 + col] = hreg[t * 4 + s][j];
            }
    }
}

// ---------------------------------------------------------------------------
// CSR: histogram -> scan -> scatter
// ---------------------------------------------------------------------------
__global__ void khist(const int* __restrict__ idx_ji, int* __restrict__ cnt, int T) {
    int t = blockIdx.x * blockDim.x + threadIdx.x;
    int nt = gridDim.x * blockDim.x;
    for (; t < T; t += nt) atomicAdd(&cnt[idx_ji[t]], 1);
}

__global__ __launch_bounds__(256) void kscan1(int* __restrict__ a, int* __restrict__ bsum) {
    __shared__ int sc[256];
    const int tid = threadIdx.x;
    const int base = blockIdx.x * SCHUNK + tid * 8;
    int4 p0 = *(const int4*)&a[base];
    int4 p1 = *(const int4*)&a[base + 4];
    int v[8] = {p0.x, p0.y, p0.z, p0.w, p1.x, p1.y, p1.z, p1.w};
    int s = 0;
#pragma unroll
    for (int i = 0; i < 8; ++i) s += v[i];
    sc[tid] = s;
    __syncthreads();
    for (int off = 1; off < 256; off <<= 1) {
        int t2 = (tid >= off) ? sc[tid - off] : 0;
        __syncthreads();
        sc[tid] += t2;
        __syncthreads();
    }
    int run = sc[tid] - s;
    if (tid == 255) bsum[blockIdx.x] = sc[255];
    int o[8];
#pragma unroll
    for (int i = 0; i < 8; ++i) { o[i] = run; run += v[i]; }
    *(int4*)&a[base]     = make_int4(o[0], o[1], o[2], o[3]);
    *(int4*)&a[base + 4] = make_int4(o[4], o[5], o[6], o[7]);
}

__global__ void kscan2(int* __restrict__ bsum, int nb) {
    if (threadIdx.x == 0 && blockIdx.x == 0) {
        int run = 0;
        for (int i = 0; i < nb; ++i) { int v = bsum[i]; bsum[i] = run; run += v; }
    }
}

__global__ void kscan3(int* __restrict__ a, const int* __restrict__ bsum,
                       int* __restrict__ cursor, int n) {
    int i = blockIdx.x * blockDim.x + threadIdx.x;
    if (i < n) {
        int v = a[i] + bsum[i >> 11];
        a[i] = v;
        cursor[i] = v;
    }
}

__global__ void kscatter(const int* __restrict__ idx_ji, int* __restrict__ cursor,
                         int* __restrict__ recT, int T) {
    int t = blockIdx.x * blockDim.x + threadIdx.x;
    int nt = gridDim.x * blockDim.x;
    for (; t < T; t += nt) {
        int pos = atomicAdd(&cursor[idx_ji[t]], 1);
        recT[pos] = t;
    }
}

// ---------------------------------------------------------------------------
// kperm (MFMA, t-order): P[128,64] = sbf_tile @ Wc; mperm[t,c] = P * xkd[kj(t),c]
// ---------------------------------------------------------------------------
__global__ __launch_bounds__(256, 4) void kperm(
        const float* __restrict__ sbf, const int* __restrict__ idx_kj,
        const float* __restrict__ xkd, const __bf16* __restrict__ wcsb,
        __bf16* __restrict__ mperm, int T) {
    __shared__ __bf16 S[PCH * 64];
    __shared__ int kidx[PCH];
    const int tid = threadIdx.x, lane = tid & 63, wv = tid >> 6;
    const long p0 = (long)blockIdx.x * PCH;
    const int np = (T - p0) > PCH ? PCH : (int)(T - p0);

    for (int i = tid; i < PCH * 64 / 8; i += 256)
        *(bf16x8*)&S[i * 8] = (bf16x8){0, 0, 0, 0, 0, 0, 0, 0};
    for (int i = tid; i < PCH; i += 256) kidx[i] = (i < np) ? idx_kj[p0 + i] : 0;
    __syncthreads();
    for (int i = tid; i < np * 21; i += 256) {
        int pos = i / 21, q = i - pos * 21;
        float2 v = *(const float2*)&sbf[(p0 + pos) * 42 + 2 * q];
        __bf16* d = &S[pos * 64 + ((2 * q) ^ ((pos & 7) << 3))];
        d[0] = (__bf16)v.x; d[1] = (__bf16)v.y;
    }
    __syncthreads();

    const int r0w = wv * 32;
    f32x4 acc[8];
    wgemm<64, 4, 2, 64, 4>(S + r0w * 64, wcsb, 0, lane, acc);

    const int rl = lane & 15, rg = (lane >> 4) << 2;
#pragma unroll
    for (int s = 0; s < 2; ++s)
#pragma unroll
        for (int j = 0; j < 4; ++j) {
            const int pos = r0w + s * 16 + rg + j;
            const int kj = kidx[pos];
            if (pos < np) {
#pragma unroll
                for (int t = 0; t < 4; ++t) {
                    const int col = t * 16 + rl;
                    float xv = xkd[(size_t)kj * 64 + col];
                    mperm[(p0 + pos) * 64 + col] = (__bf16)(acc[t * 2 + s][j] * xv);
                }
            }
        }
}

// ---------------------------------------------------------------------------
// kreduce: agg[e,lane] = sum over bucket of gathered mperm rows
// ---------------------------------------------------------------------------
__global__ __launch_bounds__(256) void kreduce(
        const __bf16* __restrict__ mperm, const int* __restrict__ recT,
        const int* __restrict__ rs, float* __restrict__ agg, int E) {
    const int lane = threadIdx.x & 63;
    const int e = blockIdx.x * 4 + (threadIdx.x >> 6);
    if (e >= E) return;
    const int j0 = rs[e], j1 = rs[e + 1];
    float a0 = 0.f, a1 = 0.f, a2 = 0.f, a3 = 0.f;
    for (int base = j0; base < j1; base += 64) {
        int nb = j1 - base; if (nb > 64) nb = 64;
        int tj = (lane < nb) ? recT[base + lane] : 0;
        int j = 0;
        for (; j + 4 <= nb; j += 4) {
            int t0 = __shfl(tj, j), t1 = __shfl(tj, j + 1);
            int t2 = __shfl(tj, j + 2), t3 = __shfl(tj, j + 3);
            a0 += (float)mperm[(size_t)t0 * 64 + lane];
            a1 += (float)mperm[(size_t)t1 * 64 + lane];
            a2 += (float)mperm[(size_t)t2 * 64 + lane];
            a3 += (float)mperm[(size_t)t3 * 64 + lane];
        }
        for (; j < nb; ++j) a0 += (float)mperm[(size_t)__shfl(tj, j) * 64 + lane];
    }
    agg[(size_t)e * 64 + lane] = (a0 + a1) + (a2 + a3);
}

// ---------------------------------------------------------------------------
// fallback triplet kernel (atomic path) if workspace too small
// ---------------------------------------------------------------------------
__global__ __launch_bounds__(256) void ktrip(
        const float* __restrict__ sbf, const int* __restrict__ idx_kj,
        const int* __restrict__ idx_ji, const float* __restrict__ xkd,
        const float* __restrict__ wc_sbf, float* __restrict__ agg, int T) {
    const int lane = threadIdx.x & 63;
    float wc[42];
#pragma unroll
    for (int s = 0; s < 42; ++s) wc[s] = wc_sbf[s * 64 + lane];
    const int wave = blockIdx.x * (blockDim.x >> 6) + (threadIdx.x >> 6);
    const int nw = gridDim.x * (blockDim.x >> 6);
    for (int t = wave; t < T; t += nw) {
        const float* srow = sbf + (size_t)t * 42;
        float acc = 0.f;
#pragma unroll
        for (int q = 0; q < 21; ++q) {
            float2 v = *(const float2*)&srow[q * 2];
            acc = fmaf(v.x, wc[q * 2 + 0], acc);
            acc = fmaf(v.y, wc[q * 2 + 1], acc);
        }
        int kj = idx_kj[t];
        int ji = idx_ji[t];
        float m = xkd[(size_t)kj * 64 + lane] * acc;
        atomicAdd(&agg[(size_t)ji * 64 + lane], m);
    }
}

extern "C" void kernel_launch(void* const* d_in, const int* in_sizes, int n_in,
                              void* d_out, int out_size, void* d_ws, size_t ws_size,
                              hipStream_t stream) {
    const float* x      = (const float*)d_in[0];
    const float* rbf    = (const float*)d_in[1];
    const float* sbf    = (const float*)d_in[2];
    const int*   idx_kj = (const int*)d_in[3];
    const int*   idx_ji = (const int*)d_in[4];
    const float* W_rbf1 = (const float*)d_in[5];
    const float* W_rbf2 = (const float*)d_in[6];
    const float* W_sbf1 = (const float*)d_in[7];
    const float* W_sbf2 = (const float*)d_in[8];
    const float* W_kj   = (const float*)d_in[9];
    const float* b_kj   = (const float*)d_in[10];
    const float* W_ji   = (const float*)d_in[11];
    const float* b_ji   = (const float*)d_in[12];
    const float* W_down = (const float*)d_in[13];
    const float* W_up   = (const float*)d_in[14];
    const float* W_rb   = (const float*)d_in[15];
    const float* b_rb   = (const float*)d_in[16];
    const float* W_lin  = (const float*)d_in[17];
    const float* b_lin  = (const float*)d_in[18];
    const float* W_ra   = (const float*)d_in[19];
    const float* b_ra   = (const float*)d_in[20];

    const int E = in_sizes[0] / 128;
    const int T = in_sizes[3];
    const int NB = (E + 1 + SCHUNK - 1) / SCHUNK;
    const int Epad = NB * SCHUNK;

    char* p = (char*)d_ws;
    float* agg  = (float*)p;                p += (size_t)E * 64 * 4;
    float* xkd  = (float*)p;                p += (size_t)E * 64 * 4;
    float* wcrT = (float*)p;                p += 1024 * 4;
    float* wcs  = (float*)p;                p += 2688 * 4;
    __bf16* wcsb = (__bf16*)p;              p += 4096 * 2;
    __bf16* wt  = (__bf16*)p;               p += (size_t)163840 * 2;
    int*   rs     = (int*)p;                p += (size_t)Epad * 4;
    int*   cursor = (int*)p;                p += (size_t)Epad * 4;
    int*   bsum   = (int*)p;                p += (size_t)((NB + 3) & ~3) * 4;
    int*   recT   = (int*)p;                p += (size_t)T * 4;
    __bf16* mperm = (__bf16*)p;             p += (size_t)T * 64 * 2;
    const bool fits = (size_t)(p - (char*)d_ws) <= ws_size;

    kweights<<<16, 256, 0, stream>>>(W_rbf1, W_rbf2, W_sbf1, W_sbf2, wcrT, wcs, wcsb);
    ktrans<<<dim3(16, 11), 256, 0, stream>>>(W_kj, W_ji, W_down, W_up, W_rb, W_lin, W_ra, wt);

    const int gE = (E + 63) / 64;
    kpre_m<<<gE, 256, 0, stream>>>(x, rbf, wt, b_kj, wcrT, xkd, E);

    if (fits) {
        hipMemsetAsync(rs, 0, (size_t)Epad * sizeof(int), stream);
        khist<<<2048, 256, 0, stream>>>(idx_ji, rs, T);
        kscan1<<<NB, 256, 0, stream>>>(rs, bsum);
        kscan2<<<1, 64, 0, stream>>>(bsum, NB);
        kscan3<<<(Epad + 255) / 256, 256, 0, stream>>>(rs, bsum, cursor, Epad);
        kscatter<<<2048, 256, 0, stream>>>(idx_ji, cursor, recT, T);
        kperm<<<(T + PCH - 1) / PCH, 256, 0, stream>>>(sbf, idx_kj, xkd, wcsb, mperm, T);
        kreduce<<<(E + 3) / 4, 256, 0, stream>>>(mperm, recT, rs, agg, E);
    } else {
        hipMemsetAsync(agg, 0, (size_t)E * 64 * sizeof(float), stream);
        ktrip<<<2048, 256, 0, stream>>>(sbf, idx_kj, idx_ji, xkd, wcs, agg, T);
    }

    kpost_m<<<gE, 256, 0, stream>>>(x, agg, wt, b_ji, b_rb, b_lin, b_ra, (float*)d_out, E);
}

// Round 8
// 842.300 us; speedup vs baseline: 1.1536x; 1.1536x over previous
//
#include <hip/hip_runtime.h>
#include <math.h>

#define SCHUNK 2048
#define PCH 128

typedef __bf16 bf16x8 __attribute__((ext_vector_type(8)));
typedef __bf16 bf16x4 __attribute__((ext_vector_type(4)));
typedef float f32x4 __attribute__((ext_vector_type(4)));

#define MFMA16(a, b, c) __builtin_amdgcn_mfma_f32_16x16x32_bf16(a, b, c, 0, 0, 0)

// weight pool offsets (elements)
#define OFF_KJ    0
#define OFF_JI    16384
#define OFF_DOWN  32768
#define OFF_UP    40960
#define OFF_RB0   49152
#define OFF_RB1   65536
#define OFF_LIN   81920
#define OFF_RA00  98304
#define OFF_RA01  114688
#define OFF_RA10  131072
#define OFF_RA11  147456

__device__ __forceinline__ float silu_f(float v) {
    return v * __builtin_amdgcn_rcpf(1.0f + __expf(-v));
}

// ---------------------------------------------------------------------------
// Wave GEMM: NB row-bands (16 rows) x 1 col-tile (16 cols ct0), K contraction.
// At: LDS bf16, row stride STRIDE, swizzle (c ^ ((r&7)<<3)).
// Wf fragment order: Wf[((kc*NTOT + ct)*64 + lane)*8 + j] =
//     W[kc*32 + (lane>>4)*8 + j][ct*16 + (lane&15)]  -> 1KB coalesced per load.
// acc[s]: C-frag rows s*16 + (lane>>4)*4 + j, col ct0*16 + (lane&15)
// ---------------------------------------------------------------------------
template<int K, int NB, int STRIDE, int NTOT>
__device__ __forceinline__ void wgemm(const __bf16* __restrict__ At,
                                      const __bf16* __restrict__ Wf,
                                      int ct0, int lane, f32x4* __restrict__ acc) {
#pragma unroll
    for (int i = 0; i < NB; ++i) acc[i] = (f32x4){0.f, 0.f, 0.f, 0.f};
    const int rl = lane & 15;
    const int kq = (lane >> 4) * 8;
    const int sw = (rl & 7) << 3;
#pragma unroll
    for (int kc = 0; kc < K / 32; ++kc) {
        const int k0 = kc * 32 + kq;
        bf16x8 b = *(const bf16x8*)&Wf[(size_t)((kc * NTOT + ct0) * 64 + lane) * 8];
#pragma unroll
        for (int s = 0; s < NB; ++s) {
            bf16x8 a = *(const bf16x8*)&At[(rl + 16 * s) * STRIDE + (k0 ^ sw)];
            acc[s] = MFMA16(a, b, acc[s]);
        }
    }
}

// stage 64 x COLS f32 rows -> LDS bf16 swizzled tile, row stride 128
template<int COLS, int NTHR>
__device__ __forceinline__ void stage(const float* __restrict__ g, long grow0,
                                      int vr, __bf16* __restrict__ At, int tid) {
    constexpr int QUADS = COLS / 4;
#pragma unroll
    for (int i = tid; i < 64 * QUADS; i += NTHR) {
        int r = i / QUADS, q = i - r * QUADS;
        float4 v = make_float4(0.f, 0.f, 0.f, 0.f);
        if (r < vr) v = *(const float4*)&g[(grow0 + r) * (size_t)COLS + q * 4];
        bf16x4 w; w[0] = (__bf16)v.x; w[1] = (__bf16)v.y; w[2] = (__bf16)v.z; w[3] = (__bf16)v.w;
        *(bf16x4*)&At[r * 128 + ((q * 4) ^ ((r & 7) << 3))] = w;
    }
}

// At <- silu(acc + b)  (16 cols per wave)
__device__ __forceinline__ void epi_store(__bf16* __restrict__ At, const f32x4* __restrict__ acc,
                                          const float* __restrict__ bias, int lane, int colbase) {
    const int rl = lane & 15, rg = (lane >> 4) << 2;
    const int col = colbase + rl;
    const float bv = bias[col];
#pragma unroll
    for (int s = 0; s < 4; ++s)
#pragma unroll
        for (int j = 0; j < 4; ++j) {
            const int row = s * 16 + rg + j;
            At[row * 128 + (col ^ ((row & 7) << 3))] = (__bf16)silu_f(acc[s][j] + bv);
        }
}

// hreg += silu(acc + b); optionally At <- bf16(hreg)
template<bool WRITE>
__device__ __forceinline__ void epi_add(__bf16* __restrict__ At, f32x4* __restrict__ hreg,
                                        const f32x4* __restrict__ acc,
                                        const float* __restrict__ bias, int lane, int colbase) {
    const int rl = lane & 15, rg = (lane >> 4) << 2;
    const int col = colbase + rl;
    const float bv = bias[col];
#pragma unroll
    for (int s = 0; s < 4; ++s)
#pragma unroll
        for (int j = 0; j < 4; ++j) {
            const int row = s * 16 + rg + j;
            float v = hreg[s][j] + silu_f(acc[s][j] + bv);
            hreg[s][j] = v;
            if (WRITE) At[row * 128 + (col ^ ((row & 7) << 3))] = (__bf16)v;
        }
}

// ---------------------------------------------------------------------------
// weight prep: wcrT[128][8]; wc_sbf[42][64] f32 (fallback); wcsb fragment-order
// ---------------------------------------------------------------------------
__global__ void kweights(const float* __restrict__ W_rbf1, const float* __restrict__ W_rbf2,
                         const float* __restrict__ W_sbf1, const float* __restrict__ W_sbf2,
                         float* __restrict__ wcrT, float* __restrict__ wc_sbf,
                         __bf16* __restrict__ wcsb) {
    int tid = blockIdx.x * blockDim.x + threadIdx.x;
    int nt = blockDim.x * gridDim.x;
    for (int idx = tid; idx < 128 * 8; idx += nt) {
        int c = idx >> 3, s = idx & 7;
        float v = 0.f;
        if (s < 6) {
#pragma unroll
            for (int b = 0; b < 8; ++b) v += W_rbf1[s * 8 + b] * W_rbf2[b * 128 + c];
        }
        wcrT[idx] = v;
    }
    for (int idx = tid; idx < 42 * 64; idx += nt) {
        int r = idx / 64, c = idx - r * 64;
        float s = 0.f;
#pragma unroll
        for (int b = 0; b < 8; ++b) s += W_sbf1[r * 8 + b] * W_sbf2[b * 64 + c];
        wc_sbf[idx] = s;
    }
    // wcsb fragment order: K=64 (pad from 42), N=64, NTOT=4
    for (int idx = tid; idx < 4096; idx += nt) {
        int j = idx & 7, l = (idx >> 3) & 63, r2 = idx >> 9;
        int ct = r2 & 3, kc = r2 >> 2;
        int k = kc * 32 + ((l >> 4) << 3) + j;
        int c = ct * 16 + (l & 15);
        float v = 0.f;
        if (k < 42) {
#pragma unroll
            for (int b = 0; b < 8; ++b) v += W_sbf1[k * 8 + b] * W_sbf2[b * 64 + c];
        }
        wcsb[idx] = (__bf16)v;
    }
}

// fragment-order weight conversion
__global__ void ktrans(const float* __restrict__ W_kj, const float* __restrict__ W_ji,
                       const float* __restrict__ W_down, const float* __restrict__ W_up,
                       const float* __restrict__ W_rb, const float* __restrict__ W_lin,
                       const float* __restrict__ W_ra, __bf16* __restrict__ wt) {
    const float* src; __bf16* dst; int K, N;
    switch (blockIdx.y) {
        case 0:  src = W_kj;          dst = wt + OFF_KJ;    K = 128; N = 128; break;
        case 1:  src = W_ji;          dst = wt + OFF_JI;    K = 128; N = 128; break;
        case 2:  src = W_down;        dst = wt + OFF_DOWN;  K = 128; N = 64;  break;
        case 3:  src = W_up;          dst = wt + OFF_UP;    K = 64;  N = 128; break;
        case 4:  src = W_rb;          dst = wt + OFF_RB0;   K = 128; N = 128; break;
        case 5:  src = W_rb + 16384;  dst = wt + OFF_RB1;   K = 128; N = 128; break;
        case 6:  src = W_lin;         dst = wt + OFF_LIN;   K = 128; N = 128; break;
        case 7:  src = W_ra;          dst = wt + OFF_RA00;  K = 128; N = 128; break;
        case 8:  src = W_ra + 16384;  dst = wt + OFF_RA01;  K = 128; N = 128; break;
        case 9:  src = W_ra + 32768;  dst = wt + OFF_RA10;  K = 128; N = 128; break;
        default: src = W_ra + 49152;  dst = wt + OFF_RA11;  K = 128; N = 128; break;
    }
    const int ntot = N / 16;
    for (int i = blockIdx.x * blockDim.x + threadIdx.x; i < K * N; i += gridDim.x * blockDim.x) {
        int j = i & 7, l = (i >> 3) & 63, r2 = i >> 9;
        int ct = r2 % ntot, kc = r2 / ntot;
        int k = kc * 32 + ((l >> 4) << 3) + j;
        int n = ct * 16 + (l & 15);
        dst[i] = (__bf16)src[(size_t)k * N + n];
    }
}

// ---------------------------------------------------------------------------
// pre phase: xkd = silu( (silu(x@W_kj+b_kj) * (rbf@Wc_rbf)) @ W_down )  [E,64]
// 64 rows/block, 8 waves x 16 cols
// ---------------------------------------------------------------------------
__global__ __launch_bounds__(512, 4) void kpre_m(
        const float* __restrict__ x, const float* __restrict__ rbf,
        const __bf16* __restrict__ wt, const float* __restrict__ b_kj,
        const float* __restrict__ wcrT, float* __restrict__ xkd, int E) {
    __shared__ __bf16 A0[64 * 128];
    __shared__ __bf16 A1[64 * 128];
    __shared__ float rbt[64 * 8];
    const int tid = threadIdx.x, lane = tid & 63, wv = tid >> 6;
    const long r0 = (long)blockIdx.x * 64;
    if (r0 >= E) return;
    const int vr = (E - r0) < 64 ? (int)(E - r0) : 64;
    const int rl = lane & 15, rg = (lane >> 4) << 2;
    const int col = wv * 16 + rl;

    stage<128, 512>(x, r0, vr, A0, tid);
    for (int i = tid; i < 64 * 8; i += 512) {
        int r = i >> 3, s = i & 7;
        rbt[i] = (s < 6 && r < vr) ? rbf[(r0 + r) * 6 + s] : 0.f;
    }
    __syncthreads();

    f32x4 acc[4];
    wgemm<128, 4, 128, 8>(A0, wt + OFF_KJ, wv, lane, acc);

    const float bv = b_kj[col];
    float wv6[6];
#pragma unroll
    for (int s = 0; s < 6; ++s) wv6[s] = wcrT[col * 8 + s];
#pragma unroll
    for (int s = 0; s < 4; ++s)
#pragma unroll
        for (int j = 0; j < 4; ++j) {
            const int row = s * 16 + rg + j;
            float4 r4 = *(const float4*)&rbt[row * 8];
            float2 r2 = *(const float2*)&rbt[row * 8 + 4];
            float re = r4.x * wv6[0] + r4.y * wv6[1] + r4.z * wv6[2]
                     + r4.w * wv6[3] + r2.x * wv6[4] + r2.y * wv6[5];
            float v = silu_f(acc[s][j] + bv) * re;
            A1[row * 128 + (col ^ ((row & 7) << 3))] = (__bf16)v;
        }
    __syncthreads();

    // W_down: N=64, NTOT=4; waves split 2-way over row halves
    const int hw = wv >> 2, ct = wv & 3;
    f32x4 acc2[2];
    wgemm<128, 2, 128, 4>(A1 + hw * 32 * 128, wt + OFF_DOWN, ct, lane, acc2);
    const int col2 = ct * 16 + rl;
#pragma unroll
    for (int s = 0; s < 2; ++s)
#pragma unroll
        for (int j = 0; j < 4; ++j) {
            const int row = hw * 32 + s * 16 + rg + j;
            if (row < vr) xkd[(r0 + row) * 64 + col2] = silu_f(acc2[s][j]);
        }
}

// ---------------------------------------------------------------------------
// post phase: 9 GEMMs, 1 barrier each (A0/A1 ping-pong), 8 waves x 16 cols
// ---------------------------------------------------------------------------
__global__ __launch_bounds__(512, 4) void kpost_m(
        const float* __restrict__ x, const float* __restrict__ agg,
        const __bf16* __restrict__ wt, const float* __restrict__ b_ji,
        const float* __restrict__ b_rb, const float* __restrict__ b_lin,
        const float* __restrict__ b_ra, float* __restrict__ out, int E) {
    __shared__ __bf16 A0[64 * 128];
    __shared__ __bf16 A1[64 * 128];
    const int tid = threadIdx.x, lane = tid & 63, wv = tid >> 6;
    const int colbase = wv * 16;
    const long r0 = (long)blockIdx.x * 64;
    if (r0 >= E) return;
    const int vr = (E - r0) < 64 ? (int)(E - r0) : 64;
    const int rl = lane & 15, rg = (lane >> 4) << 2;
    const int col = colbase + rl;
    f32x4 acc[4], hreg[4];

    stage<64, 512>(agg, r0, vr, A0, tid);
    stage<128, 512>(x, r0, vr, A1, tid);
    __syncthreads();

    // hreg = silu(agg @ W_up); acc = x @ W_ji
    wgemm<64, 4, 128, 8>(A0, wt + OFF_UP, wv, lane, acc);
#pragma unroll
    for (int i = 0; i < 4; ++i)
#pragma unroll
        for (int j = 0; j < 4; ++j) hreg[i][j] = silu_f(acc[i][j]);
    wgemm<128, 4, 128, 8>(A1, wt + OFF_JI, wv, lane, acc);
    __syncthreads();
    epi_add<true>(A0, hreg, acc, b_ji, lane, colbase);   // A0 <- h
    __syncthreads();

    // res_before
    wgemm<128, 4, 128, 8>(A0, wt + OFF_RB0, wv, lane, acc);
    epi_store(A1, acc, b_rb, lane, colbase);
    __syncthreads();
    wgemm<128, 4, 128, 8>(A1, wt + OFF_RB1, wv, lane, acc);
    epi_add<true>(A0, hreg, acc, b_rb + 128, lane, colbase);
    __syncthreads();

    // h = silu(h @ W_lin + b_lin) + x
    wgemm<128, 4, 128, 8>(A0, wt + OFF_LIN, wv, lane, acc);
    {
        const float bv = b_lin[col];
#pragma unroll
        for (int s = 0; s < 4; ++s)
#pragma unroll
            for (int j = 0; j < 4; ++j) {
                const int row = s * 16 + rg + j;
                float xv = (row < vr) ? x[(r0 + row) * 128 + col] : 0.f;
                float v = silu_f(acc[s][j] + bv) + xv;
                hreg[s][j] = v;
                A1[row * 128 + (col ^ ((row & 7) << 3))] = (__bf16)v;
            }
    }
    __syncthreads();

    // res_after layer 0
    wgemm<128, 4, 128, 8>(A1, wt + OFF_RA00, wv, lane, acc);
    epi_store(A0, acc, b_ra, lane, colbase);
    __syncthreads();
    wgemm<128, 4, 128, 8>(A0, wt + OFF_RA01, wv, lane, acc);
    epi_add<true>(A1, hreg, acc, b_ra + 128, lane, colbase);
    __syncthreads();

    // res_after layer 1
    wgemm<128, 4, 128, 8>(A1, wt + OFF_RA10, wv, lane, acc);
    epi_store(A0, acc, b_ra + 256, lane, colbase);
    __syncthreads();
    wgemm<128, 4, 128, 8>(A0, wt + OFF_RA11, wv, lane, acc);
    epi_add<false>(nullptr, hreg, acc, b_ra + 384, lane, colbase);

    // out <- hreg
#pragma unroll
    for (int s = 0; s < 4; ++s)
#pragma unroll
        for (int j = 0; j < 4; ++j) {
            const int row = s * 16 + rg + j;
            if (row < vr) out[(r0 + row) * 128 + col] = hreg[s][j];
        }
}

// ---------------------------------------------------------------------------
// CSR: histogram -> scan -> scatter
// ---------------------------------------------------------------------------
__global__ void khist(const int* __restrict__ idx_ji, int* __restrict__ cnt, int T) {
    int t = blockIdx.x * blockDim.x + threadIdx.x;
    int nt = gridDim.x * blockDim.x;
    for (; t < T; t += nt) atomicAdd(&cnt[idx_ji[t]], 1);
}

__global__ __launch_bounds__(256) void kscan1(int* __restrict__ a, int* __restrict__ bsum) {
    __shared__ int sc[256];
    const int tid = threadIdx.x;
    const int base = blockIdx.x * SCHUNK + tid * 8;
    int4 p0 = *(const int4*)&a[base];
    int4 p1 = *(const int4*)&a[base + 4];
    int v[8] = {p0.x, p0.y, p0.z, p0.w, p1.x, p1.y, p1.z, p1.w};
    int s = 0;
#pragma unroll
    for (int i = 0; i < 8; ++i) s += v[i];
    sc[tid] = s;
    __syncthreads();
    for (int off = 1; off < 256; off <<= 1) {
        int t2 = (tid >= off) ? sc[tid - off] : 0;
        __syncthreads();
        sc[tid] += t2;
        __syncthreads();
    }
    int run = sc[tid] - s;
    if (tid == 255) bsum[blockIdx.x] = sc[255];
    int o[8];
#pragma unroll
    for (int i = 0; i < 8; ++i) { o[i] = run; run += v[i]; }
    *(int4*)&a[base]     = make_int4(o[0], o[1], o[2], o[3]);
    *(int4*)&a[base + 4] = make_int4(o[4], o[5], o[6], o[7]);
}

__global__ void kscan2(int* __restrict__ bsum, int nb) {
    if (threadIdx.x == 0 && blockIdx.x == 0) {
        int run = 0;
        for (int i = 0; i < nb; ++i) { int v = bsum[i]; bsum[i] = run; run += v; }
    }
}

__global__ void kscan3(int* __restrict__ a, const int* __restrict__ bsum,
                       int* __restrict__ cursor, int n) {
    int i = blockIdx.x * blockDim.x + threadIdx.x;
    if (i < n) {
        int v = a[i] + bsum[i >> 11];
        a[i] = v;
        cursor[i] = v;
    }
}

__global__ void kscatter(const int* __restrict__ idx_ji, int* __restrict__ cursor,
                         int* __restrict__ recT, int T) {
    int t = blockIdx.x * blockDim.x + threadIdx.x;
    int nt = gridDim.x * blockDim.x;
    for (; t < T; t += nt) {
        int pos = atomicAdd(&cursor[idx_ji[t]], 1);
        recT[pos] = t;
    }
}

// ---------------------------------------------------------------------------
// kperm (MFMA, t-order): P[128,64] = sbf_tile @ Wc; mperm[t,c] = P * xkd[kj(t),c]
// 512 threads: 8 waves = 2 row-halves (64 rows, NB=4) x 4 col-tiles
// ---------------------------------------------------------------------------
__global__ __launch_bounds__(512, 4) void kperm(
        const float* __restrict__ sbf, const int* __restrict__ idx_kj,
        const float* __restrict__ xkd, const __bf16* __restrict__ wcsb,
        __bf16* __restrict__ mperm, int T) {
    __shared__ __bf16 S[PCH * 64];
    __shared__ int kidx[PCH];
    const int tid = threadIdx.x, lane = tid & 63, wv = tid >> 6;
    const long p0 = (long)blockIdx.x * PCH;
    const int np = (T - p0) > PCH ? PCH : (int)(T - p0);

    for (int i = tid; i < PCH * 64 / 8; i += 512)
        *(bf16x8*)&S[i * 8] = (bf16x8){0, 0, 0, 0, 0, 0, 0, 0};
    for (int i = tid; i < PCH; i += 512) kidx[i] = (i < np) ? idx_kj[p0 + i] : 0;
    __syncthreads();
    for (int i = tid; i < np * 21; i += 512) {
        int pos = i / 21, q = i - pos * 21;
        float2 v = *(const float2*)&sbf[(p0 + pos) * 42 + 2 * q];
        __bf16* d = &S[pos * 64 + ((2 * q) ^ ((pos & 7) << 3))];
        d[0] = (__bf16)v.x; d[1] = (__bf16)v.y;
    }
    __syncthreads();

    const int rh = wv & 1, ct = wv >> 1;   // rh: 64-row half; ct: 16-col tile
    f32x4 acc[4];
    wgemm<64, 4, 64, 4>(S + rh * 64 * 64, wcsb, ct, lane, acc);

    const int rl = lane & 15, rg = (lane >> 4) << 2;
    const int col = ct * 16 + rl;
#pragma unroll
    for (int s = 0; s < 4; ++s)
#pragma unroll
        for (int j = 0; j < 4; ++j) {
            const int pos = rh * 64 + s * 16 + rg + j;
            if (pos < np) {
                const int kj = kidx[pos];
                float xv = xkd[(size_t)kj * 64 + col];
                mperm[(p0 + pos) * 64 + col] = (__bf16)(acc[s][j] * xv);
            }
        }
}

// ---------------------------------------------------------------------------
// kreduce: agg[e,lane] = sum over bucket of gathered mperm rows
// ---------------------------------------------------------------------------
__global__ __launch_bounds__(256) void kreduce(
        const __bf16* __restrict__ mperm, const int* __restrict__ recT,
        const int* __restrict__ rs, float* __restrict__ agg, int E) {
    const int lane = threadIdx.x & 63;
    const int e = blockIdx.x * 4 + (threadIdx.x >> 6);
    if (e >= E) return;
    const int j0 = rs[e], j1 = rs[e + 1];
    float a0 = 0.f, a1 = 0.f, a2 = 0.f, a3 = 0.f;
    for (int base = j0; base < j1; base += 64) {
        int nb = j1 - base; if (nb > 64) nb = 64;
        int tj = (lane < nb) ? recT[base + lane] : 0;
        int j = 0;
        for (; j + 4 <= nb; j += 4) {
            int t0 = __shfl(tj, j), t1 = __shfl(tj, j + 1);
            int t2 = __shfl(tj, j + 2), t3 = __shfl(tj, j + 3);
            a0 += (float)mperm[(size_t)t0 * 64 + lane];
            a1 += (float)mperm[(size_t)t1 * 64 + lane];
            a2 += (float)mperm[(size_t)t2 * 64 + lane];
            a3 += (float)mperm[(size_t)t3 * 64 + lane];
        }
        for (; j < nb; ++j) a0 += (float)mperm[(size_t)__shfl(tj, j) * 64 + lane];
    }
    agg[(size_t)e * 64 + lane] = (a0 + a1) + (a2 + a3);
}

// ---------------------------------------------------------------------------
// fallback triplet kernel (atomic path) if workspace too small
// ---------------------------------------------------------------------------
__global__ __launch_bounds__(256) void ktrip(
        const float* __restrict__ sbf, const int* __restrict__ idx_kj,
        const int* __restrict__ idx_ji, const float* __restrict__ xkd,
        const float* __restrict__ wc_sbf, float* __restrict__ agg, int T) {
    const int lane = threadIdx.x & 63;
    float wc[42];
#pragma unroll
    for (int s = 0; s < 42; ++s) wc[s] = wc_sbf[s * 64 + lane];
    const int wave = blockIdx.x * (blockDim.x >> 6) + (threadIdx.x >> 6);
    const int nw = gridDim.x * (blockDim.x >> 6);
    for (int t = wave; t < T; t += nw) {
        const float* srow = sbf + (size_t)t * 42;
        float acc = 0.f;
#pragma unroll
        for (int q = 0; q < 21; ++q) {
            float2 v = *(const float2*)&srow[q * 2];
            acc = fmaf(v.x, wc[q * 2 + 0], acc);
            acc = fmaf(v.y, wc[q * 2 + 1], acc);
        }
        int kj = idx_kj[t];
        int ji = idx_ji[t];
        float m = xkd[(size_t)kj * 64 + lane] * acc;
        atomicAdd(&agg[(size_t)ji * 64 + lane], m);
    }
}

extern "C" void kernel_launch(void* const* d_in, const int* in_sizes, int n_in,
                              void* d_out, int out_size, void* d_ws, size_t ws_size,
                              hipStream_t stream) {
    const float* x      = (const float*)d_in[0];
    const float* rbf    = (const float*)d_in[1];
    const float* sbf    = (const float*)d_in[2];
    const int*   idx_kj = (const int*)d_in[3];
    const int*   idx_ji = (const int*)d_in[4];
    const float* W_rbf1 = (const float*)d_in[5];
    const float* W_rbf2 = (const float*)d_in[6];
    const float* W_sbf1 = (const float*)d_in[7];
    const float* W_sbf2 = (const float*)d_in[8];
    const float* W_kj   = (const float*)d_in[9];
    const float* b_kj   = (const float*)d_in[10];
    const float* W_ji   = (const float*)d_in[11];
    const float* b_ji   = (const float*)d_in[12];
    const float* W_down = (const float*)d_in[13];
    const float* W_up   = (const float*)d_in[14];
    const float* W_rb   = (const float*)d_in[15];
    const float* b_rb   = (const float*)d_in[16];
    const float* W_lin  = (const float*)d_in[17];
    const float* b_lin  = (const float*)d_in[18];
    const float* W_ra   = (const float*)d_in[19];
    const float* b_ra   = (const float*)d_in[20];

    const int E = in_sizes[0] / 128;
    const int T = in_sizes[3];
    const int NB = (E + 1 + SCHUNK - 1) / SCHUNK;
    const int Epad = NB * SCHUNK;

    char* p = (char*)d_ws;
    float* agg  = (float*)p;                p += (size_t)E * 64 * 4;
    float* xkd  = (float*)p;                p += (size_t)E * 64 * 4;
    float* wcrT = (float*)p;                p += 1024 * 4;
    float* wcs  = (float*)p;                p += 2688 * 4;
    __bf16* wcsb = (__bf16*)p;              p += 4096 * 2;
    __bf16* wt  = (__bf16*)p;               p += (size_t)163840 * 2;
    int*   rs     = (int*)p;                p += (size_t)Epad * 4;
    int*   cursor = (int*)p;                p += (size_t)Epad * 4;
    int*   bsum   = (int*)p;                p += (size_t)((NB + 3) & ~3) * 4;
    int*   recT   = (int*)p;                p += (size_t)T * 4;
    __bf16* mperm = (__bf16*)p;             p += (size_t)T * 64 * 2;
    const bool fits = (size_t)(p - (char*)d_ws) <= ws_size;

    kweights<<<16, 256, 0, stream>>>(W_rbf1, W_rbf2, W_sbf1, W_sbf2, wcrT, wcs, wcsb);
    ktrans<<<dim3(16, 11), 256, 0, stream>>>(W_kj, W_ji, W_down, W_up, W_rb, W_lin, W_ra, wt);

    const int gE = (E + 63) / 64;
    kpre_m<<<gE, 512, 0, stream>>>(x, rbf, wt, b_kj, wcrT, xkd, E);

    if (fits) {
        hipMemsetAsync(rs, 0, (size_t)Epad * sizeof(int), stream);
        khist<<<2048, 256, 0, stream>>>(idx_ji, rs, T);
        kscan1<<<NB, 256, 0, stream>>>(rs, bsum);
        kscan2<<<1, 64, 0, stream>>>(bsum, NB);
        kscan3<<<(Epad + 255) / 256, 256, 0, stream>>>(rs, bsum, cursor, Epad);
        kscatter<<<2048, 256, 0, stream>>>(idx_ji, cursor, recT, T);
        kperm<<<(T + PCH - 1) / PCH, 512, 0, stream>>>(sbf, idx_kj, xkd, wcsb, mperm, T);
        kreduce<<<(E + 3) / 4, 256, 0, stream>>>(mperm, recT, rs, agg, E);
    } else {
        hipMemsetAsync(agg, 0, (size_t)E * 64 * sizeof(float), stream);
        ktrip<<<2048, 256, 0, stream>>>(sbf, idx_kj, idx_ji, xkd, wcs, agg, T);
    }

    kpost_m<<<gE, 512, 0, stream>>>(x, agg, wt, b_ji, b_rb, b_lin, b_ra, (float*)d_out, E);
}

// Round 9
// 780.442 us; speedup vs baseline: 1.2450x; 1.0793x over previous
//
#include <hip/hip_runtime.h>
#include <math.h>

#define SCHUNK 2048
#define PCH 128

typedef __bf16 bf16x8 __attribute__((ext_vector_type(8)));
typedef __bf16 bf16x4 __attribute__((ext_vector_type(4)));
typedef float f32x4 __attribute__((ext_vector_type(4)));

#define MFMA16(a, b, c) __builtin_amdgcn_mfma_f32_16x16x32_bf16(a, b, c, 0, 0, 0)

// weight pool offsets (elements)
#define OFF_KJ    0
#define OFF_JI    16384
#define OFF_DOWN  32768
#define OFF_UP    40960
#define OFF_RB0   49152
#define OFF_RB1   65536
#define OFF_LIN   81920
#define OFF_RA00  98304
#define OFF_RA01  114688
#define OFF_RA10  131072
#define OFF_RA11  147456

__device__ __forceinline__ float silu_f(float v) {
    return v * __builtin_amdgcn_rcpf(1.0f + __expf(-v));
}

// ---------------------------------------------------------------------------
// Wave GEMM: NB row-bands (16 rows) x 1 col-tile (16 cols ct0), K contraction.
// At: LDS bf16, row stride STRIDE, swizzle (c ^ ((r&7)<<3)).
// Wf fragment order: Wf[((kc*NTOT + ct)*64 + lane)*8 + j] =
//     W[kc*32 + (lane>>4)*8 + j][ct*16 + (lane&15)]  -> 1KB coalesced per load.
// acc[s]: C-frag rows s*16 + (lane>>4)*4 + j, col ct0*16 + (lane&15)
// ---------------------------------------------------------------------------
template<int K, int NB, int STRIDE, int NTOT>
__device__ __forceinline__ void wgemm(const __bf16* __restrict__ At,
                                      const __bf16* __restrict__ Wf,
                                      int ct0, int lane, f32x4* __restrict__ acc) {
#pragma unroll
    for (int i = 0; i < NB; ++i) acc[i] = (f32x4){0.f, 0.f, 0.f, 0.f};
    const int rl = lane & 15;
    const int kq = (lane >> 4) * 8;
    const int sw = (rl & 7) << 3;
#pragma unroll
    for (int kc = 0; kc < K / 32; ++kc) {
        const int k0 = kc * 32 + kq;
        bf16x8 b = *(const bf16x8*)&Wf[(size_t)((kc * NTOT + ct0) * 64 + lane) * 8];
#pragma unroll
        for (int s = 0; s < NB; ++s) {
            bf16x8 a = *(const bf16x8*)&At[(rl + 16 * s) * STRIDE + (k0 ^ sw)];
            acc[s] = MFMA16(a, b, acc[s]);
        }
    }
}

// stage 64 x COLS f32 rows -> LDS bf16 swizzled tile, row stride 128
template<int COLS, int NTHR>
__device__ __forceinline__ void stage(const float* __restrict__ g, long grow0,
                                      int vr, __bf16* __restrict__ At, int tid) {
    constexpr int QUADS = COLS / 4;
#pragma unroll
    for (int i = tid; i < 64 * QUADS; i += NTHR) {
        int r = i / QUADS, q = i - r * QUADS;
        float4 v = make_float4(0.f, 0.f, 0.f, 0.f);
        if (r < vr) v = *(const float4*)&g[(grow0 + r) * (size_t)COLS + q * 4];
        bf16x4 w; w[0] = (__bf16)v.x; w[1] = (__bf16)v.y; w[2] = (__bf16)v.z; w[3] = (__bf16)v.w;
        *(bf16x4*)&At[r * 128 + ((q * 4) ^ ((r & 7) << 3))] = w;
    }
}

// At <- silu(acc + b)  (16 cols per wave)
__device__ __forceinline__ void epi_store(__bf16* __restrict__ At, const f32x4* __restrict__ acc,
                                          const float* __restrict__ bias, int lane, int colbase) {
    const int rl = lane & 15, rg = (lane >> 4) << 2;
    const int col = colbase + rl;
    const float bv = bias[col];
#pragma unroll
    for (int s = 0; s < 4; ++s)
#pragma unroll
        for (int j = 0; j < 4; ++j) {
            const int row = s * 16 + rg + j;
            At[row * 128 + (col ^ ((row & 7) << 3))] = (__bf16)silu_f(acc[s][j] + bv);
        }
}

// hreg += silu(acc + b); optionally At <- bf16(hreg)
template<bool WRITE>
__device__ __forceinline__ void epi_add(__bf16* __restrict__ At, f32x4* __restrict__ hreg,
                                        const f32x4* __restrict__ acc,
                                        const float* __restrict__ bias, int lane, int colbase) {
    const int rl = lane & 15, rg = (lane >> 4) << 2;
    const int col = colbase + rl;
    const float bv = bias[col];
#pragma unroll
    for (int s = 0; s < 4; ++s)
#pragma unroll
        for (int j = 0; j < 4; ++j) {
            const int row = s * 16 + rg + j;
            float v = hreg[s][j] + silu_f(acc[s][j] + bv);
            hreg[s][j] = v;
            if (WRITE) At[row * 128 + (col ^ ((row & 7) << 3))] = (__bf16)v;
        }
}

// ---------------------------------------------------------------------------
// weight prep: wcrT[128][8]; wc_sbf[42][64] f32 (fallback); wcsb fragment-order
// ---------------------------------------------------------------------------
__global__ void kweights(const float* __restrict__ W_rbf1, const float* __restrict__ W_rbf2,
                         const float* __restrict__ W_sbf1, const float* __restrict__ W_sbf2,
                         float* __restrict__ wcrT, float* __restrict__ wc_sbf,
                         __bf16* __restrict__ wcsb) {
    int tid = blockIdx.x * blockDim.x + threadIdx.x;
    int nt = blockDim.x * gridDim.x;
    for (int idx = tid; idx < 128 * 8; idx += nt) {
        int c = idx >> 3, s = idx & 7;
        float v = 0.f;
        if (s < 6) {
#pragma unroll
            for (int b = 0; b < 8; ++b) v += W_rbf1[s * 8 + b] * W_rbf2[b * 128 + c];
        }
        wcrT[idx] = v;
    }
    for (int idx = tid; idx < 42 * 64; idx += nt) {
        int r = idx / 64, c = idx - r * 64;
        float s = 0.f;
#pragma unroll
        for (int b = 0; b < 8; ++b) s += W_sbf1[r * 8 + b] * W_sbf2[b * 64 + c];
        wc_sbf[idx] = s;
    }
    // wcsb fragment order: K=64 (pad from 42), N=64, NTOT=4
    for (int idx = tid; idx < 4096; idx += nt) {
        int j = idx & 7, l = (idx >> 3) & 63, r2 = idx >> 9;
        int ct = r2 & 3, kc = r2 >> 2;
        int k = kc * 32 + ((l >> 4) << 3) + j;
        int c = ct * 16 + (l & 15);
        float v = 0.f;
        if (k < 42) {
#pragma unroll
            for (int b = 0; b < 8; ++b) v += W_sbf1[k * 8 + b] * W_sbf2[b * 64 + c];
        }
        wcsb[idx] = (__bf16)v;
    }
}

// fragment-order weight conversion
__global__ void ktrans(const float* __restrict__ W_kj, const float* __restrict__ W_ji,
                       const float* __restrict__ W_down, const float* __restrict__ W_up,
                       const float* __restrict__ W_rb, const float* __restrict__ W_lin,
                       const float* __restrict__ W_ra, __bf16* __restrict__ wt) {
    const float* src; __bf16* dst; int K, N;
    switch (blockIdx.y) {
        case 0:  src = W_kj;          dst = wt + OFF_KJ;    K = 128; N = 128; break;
        case 1:  src = W_ji;          dst = wt + OFF_JI;    K = 128; N = 128; break;
        case 2:  src = W_down;        dst = wt + OFF_DOWN;  K = 128; N = 64;  break;
        case 3:  src = W_up;          dst = wt + OFF_UP;    K = 64;  N = 128; break;
        case 4:  src = W_rb;          dst = wt + OFF_RB0;   K = 128; N = 128; break;
        case 5:  src = W_rb + 16384;  dst = wt + OFF_RB1;   K = 128; N = 128; break;
        case 6:  src = W_lin;         dst = wt + OFF_LIN;   K = 128; N = 128; break;
        case 7:  src = W_ra;          dst = wt + OFF_RA00;  K = 128; N = 128; break;
        case 8:  src = W_ra + 16384;  dst = wt + OFF_RA01;  K = 128; N = 128; break;
        case 9:  src = W_ra + 32768;  dst = wt + OFF_RA10;  K = 128; N = 128; break;
        default: src = W_ra + 49152;  dst = wt + OFF_RA11;  K = 128; N = 128; break;
    }
    const int ntot = N / 16;
    for (int i = blockIdx.x * blockDim.x + threadIdx.x; i < K * N; i += gridDim.x * blockDim.x) {
        int j = i & 7, l = (i >> 3) & 63, r2 = i >> 9;
        int ct = r2 % ntot, kc = r2 / ntot;
        int k = kc * 32 + ((l >> 4) << 3) + j;
        int n = ct * 16 + (l & 15);
        dst[i] = (__bf16)src[(size_t)k * N + n];
    }
}

// ---------------------------------------------------------------------------
// pre phase: xkd = silu( (silu(x@W_kj+b_kj) * (rbf@Wc_rbf)) @ W_down )  [E,64] bf16
// 64 rows/block, 8 waves x 16 cols
// ---------------------------------------------------------------------------
__global__ __launch_bounds__(512, 4) void kpre_m(
        const float* __restrict__ x, const float* __restrict__ rbf,
        const __bf16* __restrict__ wt, const float* __restrict__ b_kj,
        const float* __restrict__ wcrT, __bf16* __restrict__ xkd, int E) {
    __shared__ __bf16 A0[64 * 128];
    __shared__ __bf16 A1[64 * 128];
    __shared__ float rbt[64 * 8];
    const int tid = threadIdx.x, lane = tid & 63, wv = tid >> 6;
    const long r0 = (long)blockIdx.x * 64;
    if (r0 >= E) return;
    const int vr = (E - r0) < 64 ? (int)(E - r0) : 64;
    const int rl = lane & 15, rg = (lane >> 4) << 2;
    const int col = wv * 16 + rl;

    stage<128, 512>(x, r0, vr, A0, tid);
    for (int i = tid; i < 64 * 8; i += 512) {
        int r = i >> 3, s = i & 7;
        rbt[i] = (s < 6 && r < vr) ? rbf[(r0 + r) * 6 + s] : 0.f;
    }
    __syncthreads();

    f32x4 acc[4];
    wgemm<128, 4, 128, 8>(A0, wt + OFF_KJ, wv, lane, acc);

    const float bv = b_kj[col];
    float wv6[6];
#pragma unroll
    for (int s = 0; s < 6; ++s) wv6[s] = wcrT[col * 8 + s];
#pragma unroll
    for (int s = 0; s < 4; ++s)
#pragma unroll
        for (int j = 0; j < 4; ++j) {
            const int row = s * 16 + rg + j;
            float4 r4 = *(const float4*)&rbt[row * 8];
            float2 r2 = *(const float2*)&rbt[row * 8 + 4];
            float re = r4.x * wv6[0] + r4.y * wv6[1] + r4.z * wv6[2]
                     + r4.w * wv6[3] + r2.x * wv6[4] + r2.y * wv6[5];
            float v = silu_f(acc[s][j] + bv) * re;
            A1[row * 128 + (col ^ ((row & 7) << 3))] = (__bf16)v;
        }
    __syncthreads();

    // W_down: N=64, NTOT=4; waves split 2-way over row halves
    const int hw = wv >> 2, ct = wv & 3;
    f32x4 acc2[2];
    wgemm<128, 2, 128, 4>(A1 + hw * 32 * 128, wt + OFF_DOWN, ct, lane, acc2);
    const int col2 = ct * 16 + rl;
#pragma unroll
    for (int s = 0; s < 2; ++s)
#pragma unroll
        for (int j = 0; j < 4; ++j) {
            const int row = hw * 32 + s * 16 + rg + j;
            if (row < vr) xkd[(r0 + row) * 64 + col2] = (__bf16)silu_f(acc2[s][j]);
        }
}

// ---------------------------------------------------------------------------
// post phase: 9 GEMMs, 1 barrier each (A0/A1 ping-pong), 8 waves x 16 cols
// ---------------------------------------------------------------------------
__global__ __launch_bounds__(512, 4) void kpost_m(
        const float* __restrict__ x, const float* __restrict__ agg,
        const __bf16* __restrict__ wt, const float* __restrict__ b_ji,
        const float* __restrict__ b_rb, const float* __restrict__ b_lin,
        const float* __restrict__ b_ra, float* __restrict__ out, int E) {
    __shared__ __bf16 A0[64 * 128];
    __shared__ __bf16 A1[64 * 128];
    const int tid = threadIdx.x, lane = tid & 63, wv = tid >> 6;
    const int colbase = wv * 16;
    const long r0 = (long)blockIdx.x * 64;
    if (r0 >= E) return;
    const int vr = (E - r0) < 64 ? (int)(E - r0) : 64;
    const int rl = lane & 15, rg = (lane >> 4) << 2;
    const int col = colbase + rl;
    f32x4 acc[4], hreg[4];

    stage<64, 512>(agg, r0, vr, A0, tid);
    stage<128, 512>(x, r0, vr, A1, tid);
    __syncthreads();

    // hreg = silu(agg @ W_up); acc = x @ W_ji
    wgemm<64, 4, 128, 8>(A0, wt + OFF_UP, wv, lane, acc);
#pragma unroll
    for (int i = 0; i < 4; ++i)
#pragma unroll
        for (int j = 0; j < 4; ++j) hreg[i][j] = silu_f(acc[i][j]);
    wgemm<128, 4, 128, 8>(A1, wt + OFF_JI, wv, lane, acc);
    __syncthreads();
    epi_add<true>(A0, hreg, acc, b_ji, lane, colbase);   // A0 <- h
    __syncthreads();

    // res_before
    wgemm<128, 4, 128, 8>(A0, wt + OFF_RB0, wv, lane, acc);
    epi_store(A1, acc, b_rb, lane, colbase);
    __syncthreads();
    wgemm<128, 4, 128, 8>(A1, wt + OFF_RB1, wv, lane, acc);
    epi_add<true>(A0, hreg, acc, b_rb + 128, lane, colbase);
    __syncthreads();

    // h = silu(h @ W_lin + b_lin) + x
    wgemm<128, 4, 128, 8>(A0, wt + OFF_LIN, wv, lane, acc);
    {
        const float bv = b_lin[col];
#pragma unroll
        for (int s = 0; s < 4; ++s)
#pragma unroll
            for (int j = 0; j < 4; ++j) {
                const int row = s * 16 + rg + j;
                float xv = (row < vr) ? x[(r0 + row) * 128 + col] : 0.f;
                float v = silu_f(acc[s][j] + bv) + xv;
                hreg[s][j] = v;
                A1[row * 128 + (col ^ ((row & 7) << 3))] = (__bf16)v;
            }
    }
    __syncthreads();

    // res_after layer 0
    wgemm<128, 4, 128, 8>(A1, wt + OFF_RA00, wv, lane, acc);
    epi_store(A0, acc, b_ra, lane, colbase);
    __syncthreads();
    wgemm<128, 4, 128, 8>(A0, wt + OFF_RA01, wv, lane, acc);
    epi_add<true>(A1, hreg, acc, b_ra + 128, lane, colbase);
    __syncthreads();

    // res_after layer 1
    wgemm<128, 4, 128, 8>(A1, wt + OFF_RA10, wv, lane, acc);
    epi_store(A0, acc, b_ra + 256, lane, colbase);
    __syncthreads();
    wgemm<128, 4, 128, 8>(A0, wt + OFF_RA11, wv, lane, acc);
    epi_add<false>(nullptr, hreg, acc, b_ra + 384, lane, colbase);

    // out <- hreg
#pragma unroll
    for (int s = 0; s < 4; ++s)
#pragma unroll
        for (int j = 0; j < 4; ++j) {
            const int row = s * 16 + rg + j;
            if (row < vr) out[(r0 + row) * 128 + col] = hreg[s][j];
        }
}

// ---------------------------------------------------------------------------
// CSR: histogram -> scan -> scatter
// ---------------------------------------------------------------------------
__global__ void khist(const int* __restrict__ idx_ji, int* __restrict__ cnt, int T) {
    int t = blockIdx.x * blockDim.x + threadIdx.x;
    int nt = gridDim.x * blockDim.x;
    for (; t < T; t += nt) atomicAdd(&cnt[idx_ji[t]], 1);
}

__global__ __launch_bounds__(256) void kscan1(int* __restrict__ a, int* __restrict__ bsum) {
    __shared__ int sc[256];
    const int tid = threadIdx.x;
    const int base = blockIdx.x * SCHUNK + tid * 8;
    int4 p0 = *(const int4*)&a[base];
    int4 p1 = *(const int4*)&a[base + 4];
    int v[8] = {p0.x, p0.y, p0.z, p0.w, p1.x, p1.y, p1.z, p1.w};
    int s = 0;
#pragma unroll
    for (int i = 0; i < 8; ++i) s += v[i];
    sc[tid] = s;
    __syncthreads();
    for (int off = 1; off < 256; off <<= 1) {
        int t2 = (tid >= off) ? sc[tid - off] : 0;
        __syncthreads();
        sc[tid] += t2;
        __syncthreads();
    }
    int run = sc[tid] - s;
    if (tid == 255) bsum[blockIdx.x] = sc[255];
    int o[8];
#pragma unroll
    for (int i = 0; i < 8; ++i) { o[i] = run; run += v[i]; }
    *(int4*)&a[base]     = make_int4(o[0], o[1], o[2], o[3]);
    *(int4*)&a[base + 4] = make_int4(o[4], o[5], o[6], o[7]);
}

__global__ void kscan2(int* __restrict__ bsum, int nb) {
    if (threadIdx.x == 0 && blockIdx.x == 0) {
        int run = 0;
        for (int i = 0; i < nb; ++i) { int v = bsum[i]; bsum[i] = run; run += v; }
    }
}

__global__ void kscan3(int* __restrict__ a, const int* __restrict__ bsum,
                       int* __restrict__ cursor, int n) {
    int i = blockIdx.x * blockDim.x + threadIdx.x;
    if (i < n) {
        int v = a[i] + bsum[i >> 11];
        a[i] = v;
        cursor[i] = v;
    }
}

__global__ void kscatter(const int* __restrict__ idx_ji, int* __restrict__ cursor,
                         int* __restrict__ recT, int T) {
    int t = blockIdx.x * blockDim.x + threadIdx.x;
    int nt = gridDim.x * blockDim.x;
    for (; t < T; t += nt) {
        int pos = atomicAdd(&cursor[idx_ji[t]], 1);
        recT[pos] = t;
    }
}

// ---------------------------------------------------------------------------
// kperm (MFMA, t-order): P[128,64] = sbf_tile @ Wc; mperm[t,c] = P * xkd[kj(t),c]
// 512 threads: 8 waves = 2 row-halves x 4 col-tiles. Output staged in LDS so
// global writes are fully-coalesced 16B chunks (128B lines).
// ---------------------------------------------------------------------------
__global__ __launch_bounds__(512, 4) void kperm(
        const float* __restrict__ sbf, const int* __restrict__ idx_kj,
        const __bf16* __restrict__ xkd, const __bf16* __restrict__ wcsb,
        __bf16* __restrict__ mperm, int T) {
    __shared__ __bf16 S[PCH * 64];
    __shared__ __bf16 O[PCH * 72];   // pad 72: breaks 4-row bank aliasing
    __shared__ int kidx[PCH];
    const int tid = threadIdx.x, lane = tid & 63, wv = tid >> 6;
    const long p0 = (long)blockIdx.x * PCH;
    const int np = (T - p0) > PCH ? PCH : (int)(T - p0);

    for (int i = tid; i < PCH * 64 / 8; i += 512)
        *(bf16x8*)&S[i * 8] = (bf16x8){0, 0, 0, 0, 0, 0, 0, 0};
    for (int i = tid; i < PCH; i += 512) kidx[i] = (i < np) ? idx_kj[p0 + i] : 0;
    __syncthreads();
    for (int i = tid; i < np * 21; i += 512) {
        int pos = i / 21, q = i - pos * 21;
        float2 v = *(const float2*)&sbf[(p0 + pos) * 42 + 2 * q];
        __bf16* d = &S[pos * 64 + ((2 * q) ^ ((pos & 7) << 3))];
        d[0] = (__bf16)v.x; d[1] = (__bf16)v.y;
    }
    __syncthreads();

    const int rh = wv & 1, ct = wv >> 1;   // rh: 64-row half; ct: 16-col tile
    f32x4 acc[4];
    wgemm<64, 4, 64, 4>(S + rh * 64 * 64, wcsb, ct, lane, acc);

    const int rl = lane & 15, rg = (lane >> 4) << 2;
    const int col = ct * 16 + rl;
#pragma unroll
    for (int s = 0; s < 4; ++s)
#pragma unroll
        for (int j = 0; j < 4; ++j) {
            const int pos = rh * 64 + s * 16 + rg + j;
            const int kj = kidx[pos];
            float xv = (float)xkd[(size_t)kj * 64 + col];
            O[pos * 72 + col] = (__bf16)(acc[s][j] * xv);
        }
    __syncthreads();

    // coalesced write-out: consecutive threads -> consecutive 16B chunks
    for (int i = tid; i < np * 8; i += 512) {
        int pos = i >> 3, q = i & 7;
        *(bf16x8*)&mperm[(p0 + pos) * 64 + q * 8] = *(const bf16x8*)&O[pos * 72 + q * 8];
    }
}

// ---------------------------------------------------------------------------
// kreduce: agg[e,lane] = sum over bucket of gathered mperm rows
// ---------------------------------------------------------------------------
__global__ __launch_bounds__(256) void kreduce(
        const __bf16* __restrict__ mperm, const int* __restrict__ recT,
        const int* __restrict__ rs, float* __restrict__ agg, int E) {
    const int lane = threadIdx.x & 63;
    const int e = blockIdx.x * 4 + (threadIdx.x >> 6);
    if (e >= E) return;
    const int j0 = rs[e], j1 = rs[e + 1];
    float a0 = 0.f, a1 = 0.f, a2 = 0.f, a3 = 0.f;
    for (int base = j0; base < j1; base += 64) {
        int nb = j1 - base; if (nb > 64) nb = 64;
        int tj = (lane < nb) ? recT[base + lane] : 0;
        int j = 0;
        for (; j + 4 <= nb; j += 4) {
            int t0 = __shfl(tj, j), t1 = __shfl(tj, j + 1);
            int t2 = __shfl(tj, j + 2), t3 = __shfl(tj, j + 3);
            a0 += (float)mperm[(size_t)t0 * 64 + lane];
            a1 += (float)mperm[(size_t)t1 * 64 + lane];
            a2 += (float)mperm[(size_t)t2 * 64 + lane];
            a3 += (float)mperm[(size_t)t3 * 64 + lane];
        }
        for (; j < nb; ++j) a0 += (float)mperm[(size_t)__shfl(tj, j) * 64 + lane];
    }
    agg[(size_t)e * 64 + lane] = (a0 + a1) + (a2 + a3);
}

// ---------------------------------------------------------------------------
// fallback triplet kernel (atomic path) if workspace too small
// ---------------------------------------------------------------------------
__global__ __launch_bounds__(256) void ktrip(
        const float* __restrict__ sbf, const int* __restrict__ idx_kj,
        const int* __restrict__ idx_ji, const __bf16* __restrict__ xkd,
        const float* __restrict__ wc_sbf, float* __restrict__ agg, int T) {
    const int lane = threadIdx.x & 63;
    float wc[42];
#pragma unroll
    for (int s = 0; s < 42; ++s) wc[s] = wc_sbf[s * 64 + lane];
    const int wave = blockIdx.x * (blockDim.x >> 6) + (threadIdx.x >> 6);
    const int nw = gridDim.x * (blockDim.x >> 6);
    for (int t = wave; t < T; t += nw) {
        const float* srow = sbf + (size_t)t * 42;
        float acc = 0.f;
#pragma unroll
        for (int q = 0; q < 21; ++q) {
            float2 v = *(const float2*)&srow[q * 2];
            acc = fmaf(v.x, wc[q * 2 + 0], acc);
            acc = fmaf(v.y, wc[q * 2 + 1], acc);
        }
        int kj = idx_kj[t];
        int ji = idx_ji[t];
        float m = (float)xkd[(size_t)kj * 64 + lane] * acc;
        atomicAdd(&agg[(size_t)ji * 64 + lane], m);
    }
}

extern "C" void kernel_launch(void* const* d_in, const int* in_sizes, int n_in,
                              void* d_out, int out_size, void* d_ws, size_t ws_size,
                              hipStream_t stream) {
    const float* x      = (const float*)d_in[0];
    const float* rbf    = (const float*)d_in[1];
    const float* sbf    = (const float*)d_in[2];
    const int*   idx_kj = (const int*)d_in[3];
    const int*   idx_ji = (const int*)d_in[4];
    const float* W_rbf1 = (const float*)d_in[5];
    const float* W_rbf2 = (const float*)d_in[6];
    const float* W_sbf1 = (const float*)d_in[7];
    const float* W_sbf2 = (const float*)d_in[8];
    const float* W_kj   = (const float*)d_in[9];
    const float* b_kj   = (const float*)d_in[10];
    const float* W_ji   = (const float*)d_in[11];
    const float* b_ji   = (const float*)d_in[12];
    const float* W_down = (const float*)d_in[13];
    const float* W_up   = (const float*)d_in[14];
    const float* W_rb   = (const float*)d_in[15];
    const float* b_rb   = (const float*)d_in[16];
    const float* W_lin  = (const float*)d_in[17];
    const float* b_lin  = (const float*)d_in[18];
    const float* W_ra   = (const float*)d_in[19];
    const float* b_ra   = (const float*)d_in[20];

    const int E = in_sizes[0] / 128;
    const int T = in_sizes[3];
    const int NB = (E + 1 + SCHUNK - 1) / SCHUNK;
    const int Epad = NB * SCHUNK;

    char* p = (char*)d_ws;
    float* agg  = (float*)p;                p += (size_t)E * 64 * 4;
    __bf16* xkd = (__bf16*)p;               p += (size_t)E * 64 * 2;
    float* wcrT = (float*)p;                p += 1024 * 4;
    float* wcs  = (float*)p;                p += 2688 * 4;
    __bf16* wcsb = (__bf16*)p;              p += 4096 * 2;
    __bf16* wt  = (__bf16*)p;               p += (size_t)163840 * 2;
    int*   rs     = (int*)p;                p += (size_t)Epad * 4;
    int*   cursor = (int*)p;                p += (size_t)Epad * 4;
    int*   bsum   = (int*)p;                p += (size_t)((NB + 3) & ~3) * 4;
    int*   recT   = (int*)p;                p += (size_t)T * 4;
    __bf16* mperm = (__bf16*)p;             p += (size_t)T * 64 * 2;
    const bool fits = (size_t)(p - (char*)d_ws) <= ws_size;

    kweights<<<16, 256, 0, stream>>>(W_rbf1, W_rbf2, W_sbf1, W_sbf2, wcrT, wcs, wcsb);
    ktrans<<<dim3(16, 11), 256, 0, stream>>>(W_kj, W_ji, W_down, W_up, W_rb, W_lin, W_ra, wt);

    const int gE = (E + 63) / 64;
    kpre_m<<<gE, 512, 0, stream>>>(x, rbf, wt, b_kj, wcrT, xkd, E);

    if (fits) {
        hipMemsetAsync(rs, 0, (size_t)Epad * sizeof(int), stream);
        khist<<<2048, 256, 0, stream>>>(idx_ji, rs, T);
        kscan1<<<NB, 256, 0, stream>>>(rs, bsum);
        kscan2<<<1, 64, 0, stream>>>(bsum, NB);
        kscan3<<<(Epad + 255) / 256, 256, 0, stream>>>(rs, bsum, cursor, Epad);
        kscatter<<<2048, 256, 0, stream>>>(idx_ji, cursor, recT, T);
        kperm<<<(T + PCH - 1) / PCH, 512, 0, stream>>>(sbf, idx_kj, xkd, wcsb, mperm, T);
        kreduce<<<(E + 3) / 4, 256, 0, stream>>>(mperm, recT, rs, agg, E);
    } else {
        hipMemsetAsync(agg, 0, (size_t)E * 64 * sizeof(float), stream);
        ktrip<<<2048, 256, 0, stream>>>(sbf, idx_kj, idx_ji, xkd, wcs, agg, T);
    }

    kpost_m<<<gE, 512, 0, stream>>>(x, agg, wt, b_ji, b_rb, b_lin, b_ra, (float*)d_out, E);
}

// Round 10
// 691.044 us; speedup vs baseline: 1.4061x; 1.1294x over previous
//
#include <hip/hip_runtime.h>
#include <math.h>

#define SCHUNK 2048
#define PCH 128

typedef __bf16 bf16x8 __attribute__((ext_vector_type(8)));
typedef __bf16 bf16x4 __attribute__((ext_vector_type(4)));
typedef float f32x4 __attribute__((ext_vector_type(4)));

#define MFMA16(a, b, c) __builtin_amdgcn_mfma_f32_16x16x32_bf16(a, b, c, 0, 0, 0)

// weight pool offsets (elements)
#define OFF_KJ    0
#define OFF_JI    16384
#define OFF_DOWN  32768
#define OFF_UP    40960
#define OFF_RB0   49152
#define OFF_RB1   65536
#define OFF_LIN   81920
#define OFF_RA00  98304
#define OFF_RA01  114688
#define OFF_RA10  131072
#define OFF_RA11  147456

__device__ __forceinline__ float silu_f(float v) {
    return v * __builtin_amdgcn_rcpf(1.0f + __expf(-v));
}

// ---------------------------------------------------------------------------
// Wave GEMM: NB row-bands (16 rows) x 1 col-tile (16 cols ct0), K contraction.
// At: LDS bf16, row stride STRIDE, swizzle (c ^ ((r&7)<<3)).
// Wf fragment order: Wf[((kc*NTOT + ct)*64 + lane)*8 + j] =
//     W[kc*32 + (lane>>4)*8 + j][ct*16 + (lane&15)]  -> 1KB coalesced per load.
// acc[s]: C-frag rows s*16 + (lane>>4)*4 + j, col ct0*16 + (lane&15)
// ---------------------------------------------------------------------------
template<int K, int NB, int STRIDE, int NTOT>
__device__ __forceinline__ void wgemm(const __bf16* __restrict__ At,
                                      const __bf16* __restrict__ Wf,
                                      int ct0, int lane, f32x4* __restrict__ acc) {
#pragma unroll
    for (int i = 0; i < NB; ++i) acc[i] = (f32x4){0.f, 0.f, 0.f, 0.f};
    const int rl = lane & 15;
    const int kq = (lane >> 4) * 8;
    const int sw = (rl & 7) << 3;
#pragma unroll
    for (int kc = 0; kc < K / 32; ++kc) {
        const int k0 = kc * 32 + kq;
        bf16x8 b = *(const bf16x8*)&Wf[(size_t)((kc * NTOT + ct0) * 64 + lane) * 8];
#pragma unroll
        for (int s = 0; s < NB; ++s) {
            bf16x8 a = *(const bf16x8*)&At[(rl + 16 * s) * STRIDE + (k0 ^ sw)];
            acc[s] = MFMA16(a, b, acc[s]);
        }
    }
}

// stage 64 x COLS f32 rows -> LDS bf16 swizzled tile, row stride 128
template<int COLS, int NTHR>
__device__ __forceinline__ void stage(const float* __restrict__ g, long grow0,
                                      int vr, __bf16* __restrict__ At, int tid) {
    constexpr int QUADS = COLS / 4;
#pragma unroll
    for (int i = tid; i < 64 * QUADS; i += NTHR) {
        int r = i / QUADS, q = i - r * QUADS;
        float4 v = make_float4(0.f, 0.f, 0.f, 0.f);
        if (r < vr) v = *(const float4*)&g[(grow0 + r) * (size_t)COLS + q * 4];
        bf16x4 w; w[0] = (__bf16)v.x; w[1] = (__bf16)v.y; w[2] = (__bf16)v.z; w[3] = (__bf16)v.w;
        *(bf16x4*)&At[r * 128 + ((q * 4) ^ ((r & 7) << 3))] = w;
    }
}

// At <- silu(acc + b)  (16 cols per wave)
__device__ __forceinline__ void epi_store(__bf16* __restrict__ At, const f32x4* __restrict__ acc,
                                          const float* __restrict__ bias, int lane, int colbase) {
    const int rl = lane & 15, rg = (lane >> 4) << 2;
    const int col = colbase + rl;
    const float bv = bias[col];
#pragma unroll
    for (int s = 0; s < 4; ++s)
#pragma unroll
        for (int j = 0; j < 4; ++j) {
            const int row = s * 16 + rg + j;
            At[row * 128 + (col ^ ((row & 7) << 3))] = (__bf16)silu_f(acc[s][j] + bv);
        }
}

// hreg += silu(acc + b); optionally At <- bf16(hreg)
template<bool WRITE>
__device__ __forceinline__ void epi_add(__bf16* __restrict__ At, f32x4* __restrict__ hreg,
                                        const f32x4* __restrict__ acc,
                                        const float* __restrict__ bias, int lane, int colbase) {
    const int rl = lane & 15, rg = (lane >> 4) << 2;
    const int col = colbase + rl;
    const float bv = bias[col];
#pragma unroll
    for (int s = 0; s < 4; ++s)
#pragma unroll
        for (int j = 0; j < 4; ++j) {
            const int row = s * 16 + rg + j;
            float v = hreg[s][j] + silu_f(acc[s][j] + bv);
            hreg[s][j] = v;
            if (WRITE) At[row * 128 + (col ^ ((row & 7) << 3))] = (__bf16)v;
        }
}

// ---------------------------------------------------------------------------
// weight prep: wcrT[128][8]; wc_sbf[42][64] f32 (fallback); wcsb fragment-order
// ---------------------------------------------------------------------------
__global__ void kweights(const float* __restrict__ W_rbf1, const float* __restrict__ W_rbf2,
                         const float* __restrict__ W_sbf1, const float* __restrict__ W_sbf2,
                         float* __restrict__ wcrT, float* __restrict__ wc_sbf,
                         __bf16* __restrict__ wcsb) {
    int tid = blockIdx.x * blockDim.x + threadIdx.x;
    int nt = blockDim.x * gridDim.x;
    for (int idx = tid; idx < 128 * 8; idx += nt) {
        int c = idx >> 3, s = idx & 7;
        float v = 0.f;
        if (s < 6) {
#pragma unroll
            for (int b = 0; b < 8; ++b) v += W_rbf1[s * 8 + b] * W_rbf2[b * 128 + c];
        }
        wcrT[idx] = v;
    }
    for (int idx = tid; idx < 42 * 64; idx += nt) {
        int r = idx / 64, c = idx - r * 64;
        float s = 0.f;
#pragma unroll
        for (int b = 0; b < 8; ++b) s += W_sbf1[r * 8 + b] * W_sbf2[b * 64 + c];
        wc_sbf[idx] = s;
    }
    // wcsb fragment order: K=64 (pad from 42), N=64, NTOT=4
    for (int idx = tid; idx < 4096; idx += nt) {
        int j = idx & 7, l = (idx >> 3) & 63, r2 = idx >> 9;
        int ct = r2 & 3, kc = r2 >> 2;
        int k = kc * 32 + ((l >> 4) << 3) + j;
        int c = ct * 16 + (l & 15);
        float v = 0.f;
        if (k < 42) {
#pragma unroll
            for (int b = 0; b < 8; ++b) v += W_sbf1[k * 8 + b] * W_sbf2[b * 64 + c];
        }
        wcsb[idx] = (__bf16)v;
    }
}

// fragment-order weight conversion
__global__ void ktrans(const float* __restrict__ W_kj, const float* __restrict__ W_ji,
                       const float* __restrict__ W_down, const float* __restrict__ W_up,
                       const float* __restrict__ W_rb, const float* __restrict__ W_lin,
                       const float* __restrict__ W_ra, __bf16* __restrict__ wt) {
    const float* src; __bf16* dst; int K, N;
    switch (blockIdx.y) {
        case 0:  src = W_kj;          dst = wt + OFF_KJ;    K = 128; N = 128; break;
        case 1:  src = W_ji;          dst = wt + OFF_JI;    K = 128; N = 128; break;
        case 2:  src = W_down;        dst = wt + OFF_DOWN;  K = 128; N = 64;  break;
        case 3:  src = W_up;          dst = wt + OFF_UP;    K = 64;  N = 128; break;
        case 4:  src = W_rb;          dst = wt + OFF_RB0;   K = 128; N = 128; break;
        case 5:  src = W_rb + 16384;  dst = wt + OFF_RB1;   K = 128; N = 128; break;
        case 6:  src = W_lin;         dst = wt + OFF_LIN;   K = 128; N = 128; break;
        case 7:  src = W_ra;          dst = wt + OFF_RA00;  K = 128; N = 128; break;
        case 8:  src = W_ra + 16384;  dst = wt + OFF_RA01;  K = 128; N = 128; break;
        case 9:  src = W_ra + 32768;  dst = wt + OFF_RA10;  K = 128; N = 128; break;
        default: src = W_ra + 49152;  dst = wt + OFF_RA11;  K = 128; N = 128; break;
    }
    const int ntot = N / 16;
    for (int i = blockIdx.x * blockDim.x + threadIdx.x; i < K * N; i += gridDim.x * blockDim.x) {
        int j = i & 7, l = (i >> 3) & 63, r2 = i >> 9;
        int ct = r2 % ntot, kc = r2 / ntot;
        int k = kc * 32 + ((l >> 4) << 3) + j;
        int n = ct * 16 + (l & 15);
        dst[i] = (__bf16)src[(size_t)k * N + n];
    }
}

// ---------------------------------------------------------------------------
// pre phase: xkd = silu( (silu(x@W_kj+b_kj) * (rbf@Wc_rbf)) @ W_down )  [E,64] bf16
// 64 rows/block, 8 waves x 16 cols
// ---------------------------------------------------------------------------
__global__ __launch_bounds__(512, 4) void kpre_m(
        const float* __restrict__ x, const float* __restrict__ rbf,
        const __bf16* __restrict__ wt, const float* __restrict__ b_kj,
        const float* __restrict__ wcrT, __bf16* __restrict__ xkd, int E) {
    __shared__ __bf16 A0[64 * 128];
    __shared__ __bf16 A1[64 * 128];
    __shared__ float rbt[64 * 8];
    const int tid = threadIdx.x, lane = tid & 63, wv = tid >> 6;
    const long r0 = (long)blockIdx.x * 64;
    if (r0 >= E) return;
    const int vr = (E - r0) < 64 ? (int)(E - r0) : 64;
    const int rl = lane & 15, rg = (lane >> 4) << 2;
    const int col = wv * 16 + rl;

    stage<128, 512>(x, r0, vr, A0, tid);
    for (int i = tid; i < 64 * 8; i += 512) {
        int r = i >> 3, s = i & 7;
        rbt[i] = (s < 6 && r < vr) ? rbf[(r0 + r) * 6 + s] : 0.f;
    }
    __syncthreads();

    f32x4 acc[4];
    wgemm<128, 4, 128, 8>(A0, wt + OFF_KJ, wv, lane, acc);

    const float bv = b_kj[col];
    float wv6[6];
#pragma unroll
    for (int s = 0; s < 6; ++s) wv6[s] = wcrT[col * 8 + s];
#pragma unroll
    for (int s = 0; s < 4; ++s)
#pragma unroll
        for (int j = 0; j < 4; ++j) {
            const int row = s * 16 + rg + j;
            float4 r4 = *(const float4*)&rbt[row * 8];
            float2 r2 = *(const float2*)&rbt[row * 8 + 4];
            float re = r4.x * wv6[0] + r4.y * wv6[1] + r4.z * wv6[2]
                     + r4.w * wv6[3] + r2.x * wv6[4] + r2.y * wv6[5];
            float v = silu_f(acc[s][j] + bv) * re;
            A1[row * 128 + (col ^ ((row & 7) << 3))] = (__bf16)v;
        }
    __syncthreads();

    // W_down: N=64, NTOT=4; waves split 2-way over row halves
    const int hw = wv >> 2, ct = wv & 3;
    f32x4 acc2[2];
    wgemm<128, 2, 128, 4>(A1 + hw * 32 * 128, wt + OFF_DOWN, ct, lane, acc2);
    const int col2 = ct * 16 + rl;
#pragma unroll
    for (int s = 0; s < 2; ++s)
#pragma unroll
        for (int j = 0; j < 4; ++j) {
            const int row = hw * 32 + s * 16 + rg + j;
            if (row < vr) xkd[(r0 + row) * 64 + col2] = (__bf16)silu_f(acc2[s][j]);
        }
}

// ---------------------------------------------------------------------------
// post phase: 9 GEMMs, 1 barrier each (A0/A1 ping-pong), 8 waves x 16 cols
// ---------------------------------------------------------------------------
__global__ __launch_bounds__(512, 4) void kpost_m(
        const float* __restrict__ x, const float* __restrict__ agg,
        const __bf16* __restrict__ wt, const float* __restrict__ b_ji,
        const float* __restrict__ b_rb, const float* __restrict__ b_lin,
        const float* __restrict__ b_ra, float* __restrict__ out, int E) {
    __shared__ __bf16 A0[64 * 128];
    __shared__ __bf16 A1[64 * 128];
    const int tid = threadIdx.x, lane = tid & 63, wv = tid >> 6;
    const int colbase = wv * 16;
    const long r0 = (long)blockIdx.x * 64;
    if (r0 >= E) return;
    const int vr = (E - r0) < 64 ? (int)(E - r0) : 64;
    const int rl = lane & 15, rg = (lane >> 4) << 2;
    const int col = colbase + rl;
    f32x4 acc[4], hreg[4];

    stage<64, 512>(agg, r0, vr, A0, tid);
    stage<128, 512>(x, r0, vr, A1, tid);
    __syncthreads();

    // hreg = silu(agg @ W_up); acc = x @ W_ji
    wgemm<64, 4, 128, 8>(A0, wt + OFF_UP, wv, lane, acc);
#pragma unroll
    for (int i = 0; i < 4; ++i)
#pragma unroll
        for (int j = 0; j < 4; ++j) hreg[i][j] = silu_f(acc[i][j]);
    wgemm<128, 4, 128, 8>(A1, wt + OFF_JI, wv, lane, acc);
    __syncthreads();
    epi_add<true>(A0, hreg, acc, b_ji, lane, colbase);   // A0 <- h
    __syncthreads();

    // res_before
    wgemm<128, 4, 128, 8>(A0, wt + OFF_RB0, wv, lane, acc);
    epi_store(A1, acc, b_rb, lane, colbase);
    __syncthreads();
    wgemm<128, 4, 128, 8>(A1, wt + OFF_RB1, wv, lane, acc);
    epi_add<true>(A0, hreg, acc, b_rb + 128, lane, colbase);
    __syncthreads();

    // h = silu(h @ W_lin + b_lin) + x
    wgemm<128, 4, 128, 8>(A0, wt + OFF_LIN, wv, lane, acc);
    {
        const float bv = b_lin[col];
#pragma unroll
        for (int s = 0; s < 4; ++s)
#pragma unroll
            for (int j = 0; j < 4; ++j) {
                const int row = s * 16 + rg + j;
                float xv = (row < vr) ? x[(r0 + row) * 128 + col] : 0.f;
                float v = silu_f(acc[s][j] + bv) + xv;
                hreg[s][j] = v;
                A1[row * 128 + (col ^ ((row & 7) << 3))] = (__bf16)v;
            }
    }
    __syncthreads();

    // res_after layer 0
    wgemm<128, 4, 128, 8>(A1, wt + OFF_RA00, wv, lane, acc);
    epi_store(A0, acc, b_ra, lane, colbase);
    __syncthreads();
    wgemm<128, 4, 128, 8>(A0, wt + OFF_RA01, wv, lane, acc);
    epi_add<true>(A1, hreg, acc, b_ra + 128, lane, colbase);
    __syncthreads();

    // res_after layer 1
    wgemm<128, 4, 128, 8>(A1, wt + OFF_RA10, wv, lane, acc);
    epi_store(A0, acc, b_ra + 256, lane, colbase);
    __syncthreads();
    wgemm<128, 4, 128, 8>(A0, wt + OFF_RA11, wv, lane, acc);
    epi_add<false>(nullptr, hreg, acc, b_ra + 384, lane, colbase);

    // out <- hreg
#pragma unroll
    for (int s = 0; s < 4; ++s)
#pragma unroll
        for (int j = 0; j < 4; ++j) {
            const int row = s * 16 + rg + j;
            if (row < vr) out[(r0 + row) * 128 + col] = hreg[s][j];
        }
}

// ---------------------------------------------------------------------------
// CSR: histogram -> scan -> scatter (pos in t-order: coalesced writes)
// ---------------------------------------------------------------------------
__global__ void khist(const int* __restrict__ idx_ji, int* __restrict__ cnt, int T) {
    int t = blockIdx.x * blockDim.x + threadIdx.x;
    int nt = gridDim.x * blockDim.x;
    for (; t < T; t += nt) atomicAdd(&cnt[idx_ji[t]], 1);
}

__global__ __launch_bounds__(256) void kscan1(int* __restrict__ a, int* __restrict__ bsum) {
    __shared__ int sc[256];
    const int tid = threadIdx.x;
    const int base = blockIdx.x * SCHUNK + tid * 8;
    int4 p0 = *(const int4*)&a[base];
    int4 p1 = *(const int4*)&a[base + 4];
    int v[8] = {p0.x, p0.y, p0.z, p0.w, p1.x, p1.y, p1.z, p1.w};
    int s = 0;
#pragma unroll
    for (int i = 0; i < 8; ++i) s += v[i];
    sc[tid] = s;
    __syncthreads();
    for (int off = 1; off < 256; off <<= 1) {
        int t2 = (tid >= off) ? sc[tid - off] : 0;
        __syncthreads();
        sc[tid] += t2;
        __syncthreads();
    }
    int run = sc[tid] - s;
    if (tid == 255) bsum[blockIdx.x] = sc[255];
    int o[8];
#pragma unroll
    for (int i = 0; i < 8; ++i) { o[i] = run; run += v[i]; }
    *(int4*)&a[base]     = make_int4(o[0], o[1], o[2], o[3]);
    *(int4*)&a[base + 4] = make_int4(o[4], o[5], o[6], o[7]);
}

__global__ void kscan2(int* __restrict__ bsum, int nb) {
    if (threadIdx.x == 0 && blockIdx.x == 0) {
        int run = 0;
        for (int i = 0; i < nb; ++i) { int v = bsum[i]; bsum[i] = run; run += v; }
    }
}

__global__ void kscan3(int* __restrict__ a, const int* __restrict__ bsum,
                       int* __restrict__ cursor, int n) {
    int i = blockIdx.x * blockDim.x + threadIdx.x;
    if (i < n) {
        int v = a[i] + bsum[i >> 11];
        a[i] = v;
        cursor[i] = v;
    }
}

// pos[t] = destination slot of triplet t (coalesced write; atomics L2-resident)
__global__ void kscatter(const int* __restrict__ idx_ji, int* __restrict__ cursor,
                         int* __restrict__ pos, int T) {
    int t = blockIdx.x * blockDim.x + threadIdx.x;
    int nt = gridDim.x * blockDim.x;
    for (; t < T; t += nt) {
        pos[t] = atomicAdd(&cursor[idx_ji[t]], 1);
    }
}

// ---------------------------------------------------------------------------
// kperm (MFMA, t-order compute): P[128,64] = sbf_tile @ Wc;
// row written to mperm[pos[t]] -- scattered but full-128B-line stores.
// 512 threads: 8 waves = 2 row-halves x 4 col-tiles.
// ---------------------------------------------------------------------------
__global__ __launch_bounds__(512, 4) void kperm(
        const float* __restrict__ sbf, const int* __restrict__ idx_kj,
        const int* __restrict__ pos, const __bf16* __restrict__ xkd,
        const __bf16* __restrict__ wcsb, __bf16* __restrict__ mperm, int T) {
    __shared__ __bf16 S[PCH * 64];
    __shared__ __bf16 O[PCH * 72];   // pad 72: breaks 4-row bank aliasing
    __shared__ int kidx[PCH];
    __shared__ int posv[PCH];
    const int tid = threadIdx.x, lane = tid & 63, wv = tid >> 6;
    const long p0 = (long)blockIdx.x * PCH;
    const int np = (T - p0) > PCH ? PCH : (int)(T - p0);

    for (int i = tid; i < PCH * 64 / 8; i += 512)
        *(bf16x8*)&S[i * 8] = (bf16x8){0, 0, 0, 0, 0, 0, 0, 0};
    for (int i = tid; i < PCH; i += 512) {
        kidx[i] = (i < np) ? idx_kj[p0 + i] : 0;
        posv[i] = (i < np) ? pos[p0 + i] : 0;
    }
    __syncthreads();
    for (int i = tid; i < np * 21; i += 512) {
        int posi = i / 21, q = i - posi * 21;
        float2 v = *(const float2*)&sbf[(p0 + posi) * 42 + 2 * q];
        __bf16* d = &S[posi * 64 + ((2 * q) ^ ((posi & 7) << 3))];
        d[0] = (__bf16)v.x; d[1] = (__bf16)v.y;
    }
    __syncthreads();

    const int rh = wv & 1, ct = wv >> 1;   // rh: 64-row half; ct: 16-col tile
    f32x4 acc[4];
    wgemm<64, 4, 64, 4>(S + rh * 64 * 64, wcsb, ct, lane, acc);

    const int rl = lane & 15, rg = (lane >> 4) << 2;
    const int col = ct * 16 + rl;
#pragma unroll
    for (int s = 0; s < 4; ++s)
#pragma unroll
        for (int j = 0; j < 4; ++j) {
            const int r = rh * 64 + s * 16 + rg + j;
            const int kj = kidx[r];
            float xv = (float)xkd[(size_t)kj * 64 + col];
            O[r * 72 + col] = (__bf16)(acc[s][j] * xv);
        }
    __syncthreads();

    // write-out: 8 consecutive threads cover one row = one full 128B line
    for (int i = tid; i < np * 8; i += 512) {
        int r = i >> 3, q = i & 7;
        size_t dst = (size_t)posv[r];
        *(bf16x8*)&mperm[dst * 64 + q * 8] = *(const bf16x8*)&O[r * 72 + q * 8];
    }
}

// ---------------------------------------------------------------------------
// kreduce: agg[e,lane] = sum of contiguous mperm rows [rs[e], rs[e+1])
// ---------------------------------------------------------------------------
__global__ __launch_bounds__(256) void kreduce(
        const __bf16* __restrict__ mperm, const int* __restrict__ rs,
        float* __restrict__ agg, int E) {
    const int lane = threadIdx.x & 63;
    const int e = blockIdx.x * 4 + (threadIdx.x >> 6);
    if (e >= E) return;
    const int j0 = rs[e], j1 = rs[e + 1];
    const __bf16* p = mperm + (size_t)j0 * 64 + lane;
    const int n = j1 - j0;
    float a0 = 0.f, a1 = 0.f, a2 = 0.f, a3 = 0.f;
    int j = 0;
    for (; j + 4 <= n; j += 4) {
        a0 += (float)p[(size_t)(j + 0) * 64];
        a1 += (float)p[(size_t)(j + 1) * 64];
        a2 += (float)p[(size_t)(j + 2) * 64];
        a3 += (float)p[(size_t)(j + 3) * 64];
    }
    for (; j < n; ++j) a0 += (float)p[(size_t)j * 64];
    agg[(size_t)e * 64 + lane] = (a0 + a1) + (a2 + a3);
}

// ---------------------------------------------------------------------------
// fallback triplet kernel (atomic path) if workspace too small
// ---------------------------------------------------------------------------
__global__ __launch_bounds__(256) void ktrip(
        const float* __restrict__ sbf, const int* __restrict__ idx_kj,
        const int* __restrict__ idx_ji, const __bf16* __restrict__ xkd,
        const float* __restrict__ wc_sbf, float* __restrict__ agg, int T) {
    const int lane = threadIdx.x & 63;
    float wc[42];
#pragma unroll
    for (int s = 0; s < 42; ++s) wc[s] = wc_sbf[s * 64 + lane];
    const int wave = blockIdx.x * (blockDim.x >> 6) + (threadIdx.x >> 6);
    const int nw = gridDim.x * (blockDim.x >> 6);
    for (int t = wave; t < T; t += nw) {
        const float* srow = sbf + (size_t)t * 42;
        float acc = 0.f;
#pragma unroll
        for (int q = 0; q < 21; ++q) {
            float2 v = *(const float2*)&srow[q * 2];
            acc = fmaf(v.x, wc[q * 2 + 0], acc);
            acc = fmaf(v.y, wc[q * 2 + 1], acc);
        }
        int kj = idx_kj[t];
        int ji = idx_ji[t];
        float m = (float)xkd[(size_t)kj * 64 + lane] * acc;
        atomicAdd(&agg[(size_t)ji * 64 + lane], m);
    }
}

extern "C" void kernel_launch(void* const* d_in, const int* in_sizes, int n_in,
                              void* d_out, int out_size, void* d_ws, size_t ws_size,
                              hipStream_t stream) {
    const float* x      = (const float*)d_in[0];
    const float* rbf    = (const float*)d_in[1];
    const float* sbf    = (const float*)d_in[2];
    const int*   idx_kj = (const int*)d_in[3];
    const int*   idx_ji = (const int*)d_in[4];
    const float* W_rbf1 = (const float*)d_in[5];
    const float* W_rbf2 = (const float*)d_in[6];
    const float* W_sbf1 = (const float*)d_in[7];
    const float* W_sbf2 = (const float*)d_in[8];
    const float* W_kj   = (const float*)d_in[9];
    const float* b_kj   = (const float*)d_in[10];
    const float* W_ji   = (const float*)d_in[11];
    const float* b_ji   = (const float*)d_in[12];
    const float* W_down = (const float*)d_in[13];
    const float* W_up   = (const float*)d_in[14];
    const float* W_rb   = (const float*)d_in[15];
    const float* b_rb   = (const float*)d_in[16];
    const float* W_lin  = (const float*)d_in[17];
    const float* b_lin  = (const float*)d_in[18];
    const float* W_ra   = (const float*)d_in[19];
    const float* b_ra   = (const float*)d_in[20];

    const int E = in_sizes[0] / 128;
    const int T = in_sizes[3];
    const int NB = (E + 1 + SCHUNK - 1) / SCHUNK;
    const int Epad = NB * SCHUNK;

    char* p = (char*)d_ws;
    float* agg  = (float*)p;                p += (size_t)E * 64 * 4;
    __bf16* xkd = (__bf16*)p;               p += (size_t)E * 64 * 2;
    float* wcrT = (float*)p;                p += 1024 * 4;
    float* wcs  = (float*)p;                p += 2688 * 4;
    __bf16* wcsb = (__bf16*)p;              p += 4096 * 2;
    __bf16* wt  = (__bf16*)p;               p += (size_t)163840 * 2;
    int*   rs     = (int*)p;                p += (size_t)Epad * 4;
    int*   cursor = (int*)p;                p += (size_t)Epad * 4;
    int*   bsum   = (int*)p;                p += (size_t)((NB + 3) & ~3) * 4;
    int*   pos    = (int*)p;                p += (size_t)T * 4;
    __bf16* mperm = (__bf16*)p;             p += (size_t)T * 64 * 2;
    const bool fits = (size_t)(p - (char*)d_ws) <= ws_size;

    kweights<<<16, 256, 0, stream>>>(W_rbf1, W_rbf2, W_sbf1, W_sbf2, wcrT, wcs, wcsb);
    ktrans<<<dim3(16, 11), 256, 0, stream>>>(W_kj, W_ji, W_down, W_up, W_rb, W_lin, W_ra, wt);

    const int gE = (E + 63) / 64;
    kpre_m<<<gE, 512, 0, stream>>>(x, rbf, wt, b_kj, wcrT, xkd, E);

    if (fits) {
        hipMemsetAsync(rs, 0, (size_t)Epad * sizeof(int), stream);
        khist<<<2048, 256, 0, stream>>>(idx_ji, rs, T);
        kscan1<<<NB, 256, 0, stream>>>(rs, bsum);
        kscan2<<<1, 64, 0, stream>>>(bsum, NB);
        kscan3<<<(Epad + 255) / 256, 256, 0, stream>>>(rs, bsum, cursor, Epad);
        kscatter<<<2048, 256, 0, stream>>>(idx_ji, cursor, pos, T);
        kperm<<<(T + PCH - 1) / PCH, 512, 0, stream>>>(sbf, idx_kj, pos, xkd, wcsb, mperm, T);
        kreduce<<<(E + 3) / 4, 256, 0, stream>>>(mperm, rs, agg, E);
    } else {
        hipMemsetAsync(agg, 0, (size_t)E * 64 * sizeof(float), stream);
        ktrip<<<2048, 256, 0, stream>>>(sbf, idx_kj, idx_ji, xkd, wcs, agg, T);
    }

    kpost_m<<<gE, 512, 0, stream>>>(x, agg, wt, b_ji, b_rb, b_lin, b_ra, (float*)d_out, E);
}

// Round 11
// 615.983 us; speedup vs baseline: 1.5775x; 1.1219x over previous
//
#include <hip/hip_runtime.h>
#include <math.h>
#include <stdint.h>

#define SCHUNK 2048
#define PCH 128

typedef __bf16 bf16x8 __attribute__((ext_vector_type(8)));
typedef __bf16 bf16x4 __attribute__((ext_vector_type(4)));
typedef float f32x4 __attribute__((ext_vector_type(4)));

#define MFMA16(a, b, c) __builtin_amdgcn_mfma_f32_16x16x32_bf16(a, b, c, 0, 0, 0)

// weight pool offsets (elements)
#define OFF_KJ    0
#define OFF_JI    16384
#define OFF_DOWN  32768
#define OFF_UP    40960
#define OFF_RB0   49152
#define OFF_RB1   65536
#define OFF_LIN   81920
#define OFF_RA00  98304
#define OFF_RA01  114688
#define OFF_RA10  131072
#define OFF_RA11  147456

__device__ __forceinline__ float silu_f(float v) {
    return v * __builtin_amdgcn_rcpf(1.0f + __expf(-v));
}

// ---------------------------------------------------------------------------
// Wave GEMM: NB row-bands (16 rows) x 1 col-tile (16 cols ct0), K contraction.
// At: LDS bf16, row stride STRIDE, swizzle (c ^ ((r&7)<<3)).
// Wf fragment order: Wf[((kc*NTOT + ct)*64 + lane)*8 + j] =
//     W[kc*32 + (lane>>4)*8 + j][ct*16 + (lane&15)]  -> 1KB coalesced per load.
// acc[s]: C-frag rows s*16 + (lane>>4)*4 + j, col ct0*16 + (lane&15)
// ---------------------------------------------------------------------------
template<int K, int NB, int STRIDE, int NTOT>
__device__ __forceinline__ void wgemm(const __bf16* __restrict__ At,
                                      const __bf16* __restrict__ Wf,
                                      int ct0, int lane, f32x4* __restrict__ acc) {
#pragma unroll
    for (int i = 0; i < NB; ++i) acc[i] = (f32x4){0.f, 0.f, 0.f, 0.f};
    const int rl = lane & 15;
    const int kq = (lane >> 4) * 8;
    const int sw = (rl & 7) << 3;
#pragma unroll
    for (int kc = 0; kc < K / 32; ++kc) {
        const int k0 = kc * 32 + kq;
        bf16x8 b = *(const bf16x8*)&Wf[(size_t)((kc * NTOT + ct0) * 64 + lane) * 8];
#pragma unroll
        for (int s = 0; s < NB; ++s) {
            bf16x8 a = *(const bf16x8*)&At[(rl + 16 * s) * STRIDE + (k0 ^ sw)];
            acc[s] = MFMA16(a, b, acc[s]);
        }
    }
}

// stage 64 x COLS f32 rows -> LDS bf16 swizzled tile, row stride 128
template<int COLS, int NTHR>
__device__ __forceinline__ void stage(const float* __restrict__ g, long grow0,
                                      int vr, __bf16* __restrict__ At, int tid) {
    constexpr int QUADS = COLS / 4;
#pragma unroll
    for (int i = tid; i < 64 * QUADS; i += NTHR) {
        int r = i / QUADS, q = i - r * QUADS;
        float4 v = make_float4(0.f, 0.f, 0.f, 0.f);
        if (r < vr) v = *(const float4*)&g[(grow0 + r) * (size_t)COLS + q * 4];
        bf16x4 w; w[0] = (__bf16)v.x; w[1] = (__bf16)v.y; w[2] = (__bf16)v.z; w[3] = (__bf16)v.w;
        *(bf16x4*)&At[r * 128 + ((q * 4) ^ ((r & 7) << 3))] = w;
    }
}

// stage 64 x COLS bf16 rows -> LDS swizzled tile (8-col chunks keep swizzle intact)
template<int COLS, int NTHR>
__device__ __forceinline__ void stage_bf(const __bf16* __restrict__ g, long grow0,
                                         int vr, __bf16* __restrict__ At, int tid) {
    constexpr int CH = COLS / 8;
#pragma unroll
    for (int i = tid; i < 64 * CH; i += NTHR) {
        int r = i / CH, q = i - r * CH;
        bf16x8 v = (bf16x8){0, 0, 0, 0, 0, 0, 0, 0};
        if (r < vr) v = *(const bf16x8*)&g[(grow0 + r) * (size_t)COLS + q * 8];
        *(bf16x8*)&At[r * 128 + ((q * 8) ^ ((r & 7) << 3))] = v;
    }
}

// At <- silu(acc + b)  (16 cols per wave)
__device__ __forceinline__ void epi_store(__bf16* __restrict__ At, const f32x4* __restrict__ acc,
                                          const float* __restrict__ bias, int lane, int colbase) {
    const int rl = lane & 15, rg = (lane >> 4) << 2;
    const int col = colbase + rl;
    const float bv = bias[col];
#pragma unroll
    for (int s = 0; s < 4; ++s)
#pragma unroll
        for (int j = 0; j < 4; ++j) {
            const int row = s * 16 + rg + j;
            At[row * 128 + (col ^ ((row & 7) << 3))] = (__bf16)silu_f(acc[s][j] + bv);
        }
}

// hreg += silu(acc + b); optionally At <- bf16(hreg)
template<bool WRITE>
__device__ __forceinline__ void epi_add(__bf16* __restrict__ At, f32x4* __restrict__ hreg,
                                        const f32x4* __restrict__ acc,
                                        const float* __restrict__ bias, int lane, int colbase) {
    const int rl = lane & 15, rg = (lane >> 4) << 2;
    const int col = colbase + rl;
    const float bv = bias[col];
#pragma unroll
    for (int s = 0; s < 4; ++s)
#pragma unroll
        for (int j = 0; j < 4; ++j) {
            const int row = s * 16 + rg + j;
            float v = hreg[s][j] + silu_f(acc[s][j] + bv);
            hreg[s][j] = v;
            if (WRITE) At[row * 128 + (col ^ ((row & 7) << 3))] = (__bf16)v;
        }
}

// ---------------------------------------------------------------------------
// weight prep: wcrT[128][8]; wc_sbf[42][64] f32 (fallback); wcsb fragment-order
// ---------------------------------------------------------------------------
__global__ void kweights(const float* __restrict__ W_rbf1, const float* __restrict__ W_rbf2,
                         const float* __restrict__ W_sbf1, const float* __restrict__ W_sbf2,
                         float* __restrict__ wcrT, float* __restrict__ wc_sbf,
                         __bf16* __restrict__ wcsb) {
    int tid = blockIdx.x * blockDim.x + threadIdx.x;
    int nt = blockDim.x * gridDim.x;
    for (int idx = tid; idx < 128 * 8; idx += nt) {
        int c = idx >> 3, s = idx & 7;
        float v = 0.f;
        if (s < 6) {
#pragma unroll
            for (int b = 0; b < 8; ++b) v += W_rbf1[s * 8 + b] * W_rbf2[b * 128 + c];
        }
        wcrT[idx] = v;
    }
    for (int idx = tid; idx < 42 * 64; idx += nt) {
        int r = idx / 64, c = idx - r * 64;
        float s = 0.f;
#pragma unroll
        for (int b = 0; b < 8; ++b) s += W_sbf1[r * 8 + b] * W_sbf2[b * 64 + c];
        wc_sbf[idx] = s;
    }
    // wcsb fragment order: K=64 (pad from 42), N=64, NTOT=4
    for (int idx = tid; idx < 4096; idx += nt) {
        int j = idx & 7, l = (idx >> 3) & 63, r2 = idx >> 9;
        int ct = r2 & 3, kc = r2 >> 2;
        int k = kc * 32 + ((l >> 4) << 3) + j;
        int c = ct * 16 + (l & 15);
        float v = 0.f;
        if (k < 42) {
#pragma unroll
            for (int b = 0; b < 8; ++b) v += W_sbf1[k * 8 + b] * W_sbf2[b * 64 + c];
        }
        wcsb[idx] = (__bf16)v;
    }
}

// fragment-order weight conversion
__global__ void ktrans(const float* __restrict__ W_kj, const float* __restrict__ W_ji,
                       const float* __restrict__ W_down, const float* __restrict__ W_up,
                       const float* __restrict__ W_rb, const float* __restrict__ W_lin,
                       const float* __restrict__ W_ra, __bf16* __restrict__ wt) {
    const float* src; __bf16* dst; int K, N;
    switch (blockIdx.y) {
        case 0:  src = W_kj;          dst = wt + OFF_KJ;    K = 128; N = 128; break;
        case 1:  src = W_ji;          dst = wt + OFF_JI;    K = 128; N = 128; break;
        case 2:  src = W_down;        dst = wt + OFF_DOWN;  K = 128; N = 64;  break;
        case 3:  src = W_up;          dst = wt + OFF_UP;    K = 64;  N = 128; break;
        case 4:  src = W_rb;          dst = wt + OFF_RB0;   K = 128; N = 128; break;
        case 5:  src = W_rb + 16384;  dst = wt + OFF_RB1;   K = 128; N = 128; break;
        case 6:  src = W_lin;         dst = wt + OFF_LIN;   K = 128; N = 128; break;
        case 7:  src = W_ra;          dst = wt + OFF_RA00;  K = 128; N = 128; break;
        case 8:  src = W_ra + 16384;  dst = wt + OFF_RA01;  K = 128; N = 128; break;
        case 9:  src = W_ra + 32768;  dst = wt + OFF_RA10;  K = 128; N = 128; break;
        default: src = W_ra + 49152;  dst = wt + OFF_RA11;  K = 128; N = 128; break;
    }
    const int ntot = N / 16;
    for (int i = blockIdx.x * blockDim.x + threadIdx.x; i < K * N; i += gridDim.x * blockDim.x) {
        int j = i & 7, l = (i >> 3) & 63, r2 = i >> 9;
        int ct = r2 % ntot, kc = r2 / ntot;
        int k = kc * 32 + ((l >> 4) << 3) + j;
        int n = ct * 16 + (l & 15);
        dst[i] = (__bf16)src[(size_t)k * N + n];
    }
}

// ---------------------------------------------------------------------------
// pre phase: xkd = silu( (silu(x@W_kj+b_kj) * (rbf@Wc_rbf)) @ W_down )  [E,64] bf16
// 64 rows/block, 8 waves x 16 cols
// ---------------------------------------------------------------------------
__global__ __launch_bounds__(512, 4) void kpre_m(
        const float* __restrict__ x, const float* __restrict__ rbf,
        const __bf16* __restrict__ wt, const float* __restrict__ b_kj,
        const float* __restrict__ wcrT, __bf16* __restrict__ xkd, int E) {
    __shared__ __bf16 A0[64 * 128];
    __shared__ __bf16 A1[64 * 128];
    __shared__ float rbt[64 * 8];
    const int tid = threadIdx.x, lane = tid & 63, wv = tid >> 6;
    const long r0 = (long)blockIdx.x * 64;
    if (r0 >= E) return;
    const int vr = (E - r0) < 64 ? (int)(E - r0) : 64;
    const int rl = lane & 15, rg = (lane >> 4) << 2;
    const int col = wv * 16 + rl;

    stage<128, 512>(x, r0, vr, A0, tid);
    for (int i = tid; i < 64 * 8; i += 512) {
        int r = i >> 3, s = i & 7;
        rbt[i] = (s < 6 && r < vr) ? rbf[(r0 + r) * 6 + s] : 0.f;
    }
    __syncthreads();

    f32x4 acc[4];
    wgemm<128, 4, 128, 8>(A0, wt + OFF_KJ, wv, lane, acc);

    const float bv = b_kj[col];
    float wv6[6];
#pragma unroll
    for (int s = 0; s < 6; ++s) wv6[s] = wcrT[col * 8 + s];
#pragma unroll
    for (int s = 0; s < 4; ++s)
#pragma unroll
        for (int j = 0; j < 4; ++j) {
            const int row = s * 16 + rg + j;
            float4 r4 = *(const float4*)&rbt[row * 8];
            float2 r2 = *(const float2*)&rbt[row * 8 + 4];
            float re = r4.x * wv6[0] + r4.y * wv6[1] + r4.z * wv6[2]
                     + r4.w * wv6[3] + r2.x * wv6[4] + r2.y * wv6[5];
            float v = silu_f(acc[s][j] + bv) * re;
            A1[row * 128 + (col ^ ((row & 7) << 3))] = (__bf16)v;
        }
    __syncthreads();

    // W_down: N=64, NTOT=4; waves split 2-way over row halves
    const int hw = wv >> 2, ct = wv & 3;
    f32x4 acc2[2];
    wgemm<128, 2, 128, 4>(A1 + hw * 32 * 128, wt + OFF_DOWN, ct, lane, acc2);
    const int col2 = ct * 16 + rl;
#pragma unroll
    for (int s = 0; s < 2; ++s)
#pragma unroll
        for (int j = 0; j < 4; ++j) {
            const int row = hw * 32 + s * 16 + rg + j;
            if (row < vr) xkd[(r0 + row) * 64 + col2] = (__bf16)silu_f(acc2[s][j]);
        }
}

// ---------------------------------------------------------------------------
// post phase: 9 GEMMs, 1 barrier each (A0/A1 ping-pong), 8 waves x 16 cols
// ---------------------------------------------------------------------------
__global__ __launch_bounds__(512, 4) void kpost_m(
        const float* __restrict__ x, const __bf16* __restrict__ agg,
        const __bf16* __restrict__ wt, const float* __restrict__ b_ji,
        const float* __restrict__ b_rb, const float* __restrict__ b_lin,
        const float* __restrict__ b_ra, float* __restrict__ out, int E) {
    __shared__ __bf16 A0[64 * 128];
    __shared__ __bf16 A1[64 * 128];
    const int tid = threadIdx.x, lane = tid & 63, wv = tid >> 6;
    const int colbase = wv * 16;
    const long r0 = (long)blockIdx.x * 64;
    if (r0 >= E) return;
    const int vr = (E - r0) < 64 ? (int)(E - r0) : 64;
    const int rl = lane & 15, rg = (lane >> 4) << 2;
    const int col = colbase + rl;
    f32x4 acc[4], hreg[4];

    stage_bf<64, 512>(agg, r0, vr, A0, tid);
    stage<128, 512>(x, r0, vr, A1, tid);
    __syncthreads();

    // hreg = silu(agg @ W_up); acc = x @ W_ji
    wgemm<64, 4, 128, 8>(A0, wt + OFF_UP, wv, lane, acc);
#pragma unroll
    for (int i = 0; i < 4; ++i)
#pragma unroll
        for (int j = 0; j < 4; ++j) hreg[i][j] = silu_f(acc[i][j]);
    wgemm<128, 4, 128, 8>(A1, wt + OFF_JI, wv, lane, acc);
    __syncthreads();
    epi_add<true>(A0, hreg, acc, b_ji, lane, colbase);   // A0 <- h
    __syncthreads();

    // res_before
    wgemm<128, 4, 128, 8>(A0, wt + OFF_RB0, wv, lane, acc);
    epi_store(A1, acc, b_rb, lane, colbase);
    __syncthreads();
    wgemm<128, 4, 128, 8>(A1, wt + OFF_RB1, wv, lane, acc);
    epi_add<true>(A0, hreg, acc, b_rb + 128, lane, colbase);
    __syncthreads();

    // h = silu(h @ W_lin + b_lin) + x
    wgemm<128, 4, 128, 8>(A0, wt + OFF_LIN, wv, lane, acc);
    {
        const float bv = b_lin[col];
#pragma unroll
        for (int s = 0; s < 4; ++s)
#pragma unroll
            for (int j = 0; j < 4; ++j) {
                const int row = s * 16 + rg + j;
                float xv = (row < vr) ? x[(r0 + row) * 128 + col] : 0.f;
                float v = silu_f(acc[s][j] + bv) + xv;
                hreg[s][j] = v;
                A1[row * 128 + (col ^ ((row & 7) << 3))] = (__bf16)v;
            }
    }
    __syncthreads();

    // res_after layer 0
    wgemm<128, 4, 128, 8>(A1, wt + OFF_RA00, wv, lane, acc);
    epi_store(A0, acc, b_ra, lane, colbase);
    __syncthreads();
    wgemm<128, 4, 128, 8>(A0, wt + OFF_RA01, wv, lane, acc);
    epi_add<true>(A1, hreg, acc, b_ra + 128, lane, colbase);
    __syncthreads();

    // res_after layer 1
    wgemm<128, 4, 128, 8>(A1, wt + OFF_RA10, wv, lane, acc);
    epi_store(A0, acc, b_ra + 256, lane, colbase);
    __syncthreads();
    wgemm<128, 4, 128, 8>(A0, wt + OFF_RA11, wv, lane, acc);
    epi_add<false>(nullptr, hreg, acc, b_ra + 384, lane, colbase);

    // out <- hreg
#pragma unroll
    for (int s = 0; s < 4; ++s)
#pragma unroll
        for (int j = 0; j < 4; ++j) {
            const int row = s * 16 + rg + j;
            if (row < vr) out[(r0 + row) * 128 + col] = hreg[s][j];
        }
}

// ---------------------------------------------------------------------------
// CSR: histogram -> scan -> scatter (pos in t-order: coalesced writes)
// ---------------------------------------------------------------------------
__global__ void khist(const int* __restrict__ idx_ji, int* __restrict__ cnt, int T) {
    int t = blockIdx.x * blockDim.x + threadIdx.x;
    int nt = gridDim.x * blockDim.x;
    for (; t < T; t += nt) atomicAdd(&cnt[idx_ji[t]], 1);
}

__global__ __launch_bounds__(256) void kscan1(int* __restrict__ a, int* __restrict__ bsum) {
    __shared__ int sc[256];
    const int tid = threadIdx.x;
    const int base = blockIdx.x * SCHUNK + tid * 8;
    int4 p0 = *(const int4*)&a[base];
    int4 p1 = *(const int4*)&a[base + 4];
    int v[8] = {p0.x, p0.y, p0.z, p0.w, p1.x, p1.y, p1.z, p1.w};
    int s = 0;
#pragma unroll
    for (int i = 0; i < 8; ++i) s += v[i];
    sc[tid] = s;
    __syncthreads();
    for (int off = 1; off < 256; off <<= 1) {
        int t2 = (tid >= off) ? sc[tid - off] : 0;
        __syncthreads();
        sc[tid] += t2;
        __syncthreads();
    }
    int run = sc[tid] - s;
    if (tid == 255) bsum[blockIdx.x] = sc[255];
    int o[8];
#pragma unroll
    for (int i = 0; i < 8; ++i) { o[i] = run; run += v[i]; }
    *(int4*)&a[base]     = make_int4(o[0], o[1], o[2], o[3]);
    *(int4*)&a[base + 4] = make_int4(o[4], o[5], o[6], o[7]);
}

__global__ void kscan2(int* __restrict__ bsum, int nb) {
    if (threadIdx.x == 0 && blockIdx.x == 0) {
        int run = 0;
        for (int i = 0; i < nb; ++i) { int v = bsum[i]; bsum[i] = run; run += v; }
    }
}

__global__ void kscan3(int* __restrict__ a, const int* __restrict__ bsum,
                       int* __restrict__ cursor, int n) {
    int i = blockIdx.x * blockDim.x + threadIdx.x;
    if (i < n) {
        int v = a[i] + bsum[i >> 11];
        a[i] = v;
        cursor[i] = v;
    }
}

// pos[t] = destination slot of triplet t (coalesced write; atomics L2-resident)
__global__ void kscatter(const int* __restrict__ idx_ji, int* __restrict__ cursor,
                         int* __restrict__ pos, int T) {
    int t = blockIdx.x * blockDim.x + threadIdx.x;
    int nt = gridDim.x * blockDim.x;
    for (; t < T; t += nt) {
        pos[t] = atomicAdd(&cursor[idx_ji[t]], 1);
    }
}

// ---------------------------------------------------------------------------
// kperm (MFMA, t-order compute): P[128,64] = sbf_tile @ Wc;
// row written to mperm[pos[t]] -- scattered but full-128B-line (aligned) stores.
// 512 threads: 8 waves = 2 row-halves x 4 col-tiles.
// ---------------------------------------------------------------------------
__global__ __launch_bounds__(512, 4) void kperm(
        const float* __restrict__ sbf, const int* __restrict__ idx_kj,
        const int* __restrict__ pos, const __bf16* __restrict__ xkd,
        const __bf16* __restrict__ wcsb, __bf16* __restrict__ mperm, int T) {
    __shared__ __bf16 S[PCH * 64];
    __shared__ __bf16 O[PCH * 72];   // pad 72: breaks 4-row bank aliasing
    __shared__ int kidx[PCH];
    __shared__ int posv[PCH];
    const int tid = threadIdx.x, lane = tid & 63, wv = tid >> 6;
    const long p0 = (long)blockIdx.x * PCH;
    const int np = (T - p0) > PCH ? PCH : (int)(T - p0);

    for (int i = tid; i < PCH * 64 / 8; i += 512)
        *(bf16x8*)&S[i * 8] = (bf16x8){0, 0, 0, 0, 0, 0, 0, 0};
    for (int i = tid; i < PCH; i += 512) {
        kidx[i] = (i < np) ? idx_kj[p0 + i] : 0;
        posv[i] = (i < np) ? pos[p0 + i] : 0;
    }
    __syncthreads();
    for (int i = tid; i < np * 21; i += 512) {
        int posi = i / 21, q = i - posi * 21;
        float2 v = *(const float2*)&sbf[(p0 + posi) * 42 + 2 * q];
        __bf16* d = &S[posi * 64 + ((2 * q) ^ ((posi & 7) << 3))];
        d[0] = (__bf16)v.x; d[1] = (__bf16)v.y;
    }
    __syncthreads();

    const int rh = wv & 1, ct = wv >> 1;   // rh: 64-row half; ct: 16-col tile
    f32x4 acc[4];
    wgemm<64, 4, 64, 4>(S + rh * 64 * 64, wcsb, ct, lane, acc);

    const int rl = lane & 15, rg = (lane >> 4) << 2;
    const int col = ct * 16 + rl;
#pragma unroll
    for (int s = 0; s < 4; ++s)
#pragma unroll
        for (int j = 0; j < 4; ++j) {
            const int r = rh * 64 + s * 16 + rg + j;
            const int kj = kidx[r];
            float xv = (float)xkd[(size_t)kj * 64 + col];
            O[r * 72 + col] = (__bf16)(acc[s][j] * xv);
        }
    __syncthreads();

    // write-out: 8 consecutive threads cover one row = one full 128B line
    for (int i = tid; i < np * 8; i += 512) {
        int r = i >> 3, q = i & 7;
        size_t dst = (size_t)posv[r];
        *(bf16x8*)&mperm[dst * 64 + q * 8] = *(const bf16x8*)&O[r * 72 + q * 8];
    }
}

// ---------------------------------------------------------------------------
// kreduce: agg[e,lane] = sum of contiguous mperm rows [rs[e], rs[e+1])  (bf16 out)
// ---------------------------------------------------------------------------
__global__ __launch_bounds__(256) void kreduce(
        const __bf16* __restrict__ mperm, const int* __restrict__ rs,
        __bf16* __restrict__ agg, int E) {
    const int lane = threadIdx.x & 63;
    const int e = blockIdx.x * 4 + (threadIdx.x >> 6);
    if (e >= E) return;
    const int j0 = rs[e], j1 = rs[e + 1];
    const __bf16* p = mperm + (size_t)j0 * 64 + lane;
    const int n = j1 - j0;
    float a0 = 0.f, a1 = 0.f, a2 = 0.f, a3 = 0.f;
    int j = 0;
    for (; j + 4 <= n; j += 4) {
        a0 += (float)p[(size_t)(j + 0) * 64];
        a1 += (float)p[(size_t)(j + 1) * 64];
        a2 += (float)p[(size_t)(j + 2) * 64];
        a3 += (float)p[(size_t)(j + 3) * 64];
    }
    for (; j < n; ++j) a0 += (float)p[(size_t)j * 64];
    agg[(size_t)e * 64 + lane] = (__bf16)((a0 + a1) + (a2 + a3));
}

// ---------------------------------------------------------------------------
// fallback triplet kernels (atomic path) if workspace too small for mperm path
// ---------------------------------------------------------------------------
__global__ __launch_bounds__(256) void ktrip(
        const float* __restrict__ sbf, const int* __restrict__ idx_kj,
        const int* __restrict__ idx_ji, const __bf16* __restrict__ xkd,
        const float* __restrict__ wc_sbf, float* __restrict__ aggf, int T) {
    const int lane = threadIdx.x & 63;
    float wc[42];
#pragma unroll
    for (int s = 0; s < 42; ++s) wc[s] = wc_sbf[s * 64 + lane];
    const int wave = blockIdx.x * (blockDim.x >> 6) + (threadIdx.x >> 6);
    const int nw = gridDim.x * (blockDim.x >> 6);
    for (int t = wave; t < T; t += nw) {
        const float* srow = sbf + (size_t)t * 42;
        float acc = 0.f;
#pragma unroll
        for (int q = 0; q < 21; ++q) {
            float2 v = *(const float2*)&srow[q * 2];
            acc = fmaf(v.x, wc[q * 2 + 0], acc);
            acc = fmaf(v.y, wc[q * 2 + 1], acc);
        }
        int kj = idx_kj[t];
        int ji = idx_ji[t];
        float m = (float)xkd[(size_t)kj * 64 + lane] * acc;
        atomicAdd(&aggf[(size_t)ji * 64 + lane], m);
    }
}

__global__ void kcvt(const float* __restrict__ src, __bf16* __restrict__ dst, int n) {
    int i = blockIdx.x * blockDim.x + threadIdx.x;
    int nt = gridDim.x * blockDim.x;
    for (; i < n; i += nt) dst[i] = (__bf16)src[i];
}

static inline char* alignup256(char* p) {
    return (char*)(((uintptr_t)p + 255) & ~(uintptr_t)255);
}

extern "C" void kernel_launch(void* const* d_in, const int* in_sizes, int n_in,
                              void* d_out, int out_size, void* d_ws, size_t ws_size,
                              hipStream_t stream) {
    const float* x      = (const float*)d_in[0];
    const float* rbf    = (const float*)d_in[1];
    const float* sbf    = (const float*)d_in[2];
    const int*   idx_kj = (const int*)d_in[3];
    const int*   idx_ji = (const int*)d_in[4];
    const float* W_rbf1 = (const float*)d_in[5];
    const float* W_rbf2 = (const float*)d_in[6];
    const float* W_sbf1 = (const float*)d_in[7];
    const float* W_sbf2 = (const float*)d_in[8];
    const float* W_kj   = (const float*)d_in[9];
    const float* b_kj   = (const float*)d_in[10];
    const float* W_ji   = (const float*)d_in[11];
    const float* b_ji   = (const float*)d_in[12];
    const float* W_down = (const float*)d_in[13];
    const float* W_up   = (const float*)d_in[14];
    const float* W_rb   = (const float*)d_in[15];
    const float* b_rb   = (const float*)d_in[16];
    const float* W_lin  = (const float*)d_in[17];
    const float* b_lin  = (const float*)d_in[18];
    const float* W_ra   = (const float*)d_in[19];
    const float* b_ra   = (const float*)d_in[20];

    const int E = in_sizes[0] / 128;
    const int T = in_sizes[3];
    const int NB = (E + 1 + SCHUNK - 1) / SCHUNK;
    const int Epad = NB * SCHUNK;

    // 256B-aligned workspace carve-up (mperm MUST be 128B-aligned: full-line stores)
    char* p = (char*)d_ws;
    __bf16* agg  = (__bf16*)p;  p = alignup256(p + (size_t)E * 64 * 2);
    __bf16* xkd  = (__bf16*)p;  p = alignup256(p + (size_t)E * 64 * 2);
    float* wcrT  = (float*)p;   p = alignup256(p + 1024 * 4);
    float* wcs   = (float*)p;   p = alignup256(p + 2688 * 4);
    __bf16* wcsb = (__bf16*)p;  p = alignup256(p + 4096 * 2);
    __bf16* wt   = (__bf16*)p;  p = alignup256(p + (size_t)163840 * 2);
    int* rs      = (int*)p;     p = alignup256(p + (size_t)Epad * 4);
    int* cursor  = (int*)p;     p = alignup256(p + (size_t)Epad * 4);
    int* bsum    = (int*)p;     p = alignup256(p + (size_t)NB * 4);
    int* pos     = (int*)p;     p = alignup256(p + (size_t)T * 4);
    __bf16* mperm = (__bf16*)p; p = alignup256(p + (size_t)T * 64 * 2);
    const bool fits = (size_t)(p - (char*)d_ws) <= ws_size;
    // fallback f32 agg lives where mperm would be
    float* aggf = (float*)mperm;
    const bool fits_fb = (size_t)((char*)(aggf + (size_t)E * 64) - (char*)d_ws) <= ws_size;

    kweights<<<16, 256, 0, stream>>>(W_rbf1, W_rbf2, W_sbf1, W_sbf2, wcrT, wcs, wcsb);
    ktrans<<<dim3(16, 11), 256, 0, stream>>>(W_kj, W_ji, W_down, W_up, W_rb, W_lin, W_ra, wt);

    const int gE = (E + 63) / 64;
    kpre_m<<<gE, 512, 0, stream>>>(x, rbf, wt, b_kj, wcrT, xkd, E);

    if (fits) {
        hipMemsetAsync(rs, 0, (size_t)Epad * sizeof(int), stream);
        khist<<<2048, 256, 0, stream>>>(idx_ji, rs, T);
        kscan1<<<NB, 256, 0, stream>>>(rs, bsum);
        kscan2<<<1, 64, 0, stream>>>(bsum, NB);
        kscan3<<<(Epad + 255) / 256, 256, 0, stream>>>(rs, bsum, cursor, Epad);
        kscatter<<<2048, 256, 0, stream>>>(idx_ji, cursor, pos, T);
        kperm<<<(T + PCH - 1) / PCH, 512, 0, stream>>>(sbf, idx_kj, pos, xkd, wcsb, mperm, T);
        kreduce<<<(E + 3) / 4, 256, 0, stream>>>(mperm, rs, agg, E);
    } else if (fits_fb) {
        hipMemsetAsync(aggf, 0, (size_t)E * 64 * sizeof(float), stream);
        ktrip<<<2048, 256, 0, stream>>>(sbf, idx_kj, idx_ji, xkd, wcs, aggf, T);
        kcvt<<<2048, 256, 0, stream>>>(aggf, agg, E * 64);
    }

    kpost_m<<<gE, 512, 0, stream>>>(x, agg, wt, b_ji, b_rb, b_lin, b_ra, (float*)d_out, E);
}

// Round 12
// 594.546 us; speedup vs baseline: 1.6343x; 1.0361x over previous
//
#include <hip/hip_runtime.h>
#include <math.h>
#include <stdint.h>

#define SCHUNK 2048
#define PCH 128

typedef __bf16 bf16x8 __attribute__((ext_vector_type(8)));
typedef __bf16 bf16x4 __attribute__((ext_vector_type(4)));
typedef float f32x4 __attribute__((ext_vector_type(4)));

#define MFMA16(a, b, c) __builtin_amdgcn_mfma_f32_16x16x32_bf16(a, b, c, 0, 0, 0)

// weight pool offsets (elements)
#define OFF_KJ    0
#define OFF_JI    16384
#define OFF_DOWN  32768
#define OFF_UP    40960
#define OFF_RB0   49152
#define OFF_RB1   65536
#define OFF_LIN   81920
#define OFF_RA00  98304
#define OFF_RA01  114688
#define OFF_RA10  131072
#define OFF_RA11  147456

__device__ __forceinline__ float silu_f(float v) {
    return v * __builtin_amdgcn_rcpf(1.0f + __expf(-v));
}

// ---------------------------------------------------------------------------
// Wave GEMM: NB row-bands (16 rows) x 1 col-tile (16 cols ct0), K contraction.
// At: LDS bf16, row stride STRIDE, swizzle (c ^ ((r&7)<<3)).
// Wf fragment order: Wf[((kc*NTOT + ct)*64 + lane)*8 + j] =
//     W[kc*32 + (lane>>4)*8 + j][ct*16 + (lane&15)]  -> 1KB coalesced per load.
// acc[s]: C-frag rows s*16 + (lane>>4)*4 + j, col ct0*16 + (lane&15)
// ---------------------------------------------------------------------------
template<int K, int NB, int STRIDE, int NTOT>
__device__ __forceinline__ void wgemm(const __bf16* __restrict__ At,
                                      const __bf16* __restrict__ Wf,
                                      int ct0, int lane, f32x4* __restrict__ acc) {
#pragma unroll
    for (int i = 0; i < NB; ++i) acc[i] = (f32x4){0.f, 0.f, 0.f, 0.f};
    const int rl = lane & 15;
    const int kq = (lane >> 4) * 8;
    const int sw = (rl & 7) << 3;
#pragma unroll
    for (int kc = 0; kc < K / 32; ++kc) {
        const int k0 = kc * 32 + kq;
        bf16x8 b = *(const bf16x8*)&Wf[(size_t)((kc * NTOT + ct0) * 64 + lane) * 8];
#pragma unroll
        for (int s = 0; s < NB; ++s) {
            bf16x8 a = *(const bf16x8*)&At[(rl + 16 * s) * STRIDE + (k0 ^ sw)];
            acc[s] = MFMA16(a, b, acc[s]);
        }
    }
}

// stage 64 x COLS f32 rows -> LDS bf16 swizzled tile, row stride 128
template<int COLS, int NTHR>
__device__ __forceinline__ void stage(const float* __restrict__ g, long grow0,
                                      int vr, __bf16* __restrict__ At, int tid) {
    constexpr int QUADS = COLS / 4;
#pragma unroll
    for (int i = tid; i < 64 * QUADS; i += NTHR) {
        int r = i / QUADS, q = i - r * QUADS;
        float4 v = make_float4(0.f, 0.f, 0.f, 0.f);
        if (r < vr) v = *(const float4*)&g[(grow0 + r) * (size_t)COLS + q * 4];
        bf16x4 w; w[0] = (__bf16)v.x; w[1] = (__bf16)v.y; w[2] = (__bf16)v.z; w[3] = (__bf16)v.w;
        *(bf16x4*)&At[r * 128 + ((q * 4) ^ ((r & 7) << 3))] = w;
    }
}

// stage 64 x COLS bf16 rows -> LDS swizzled tile (8-col chunks keep swizzle intact)
template<int COLS, int NTHR>
__device__ __forceinline__ void stage_bf(const __bf16* __restrict__ g, long grow0,
                                         int vr, __bf16* __restrict__ At, int tid) {
    constexpr int CH = COLS / 8;
#pragma unroll
    for (int i = tid; i < 64 * CH; i += NTHR) {
        int r = i / CH, q = i - r * CH;
        bf16x8 v = (bf16x8){0, 0, 0, 0, 0, 0, 0, 0};
        if (r < vr) v = *(const bf16x8*)&g[(grow0 + r) * (size_t)COLS + q * 8];
        *(bf16x8*)&At[r * 128 + ((q * 8) ^ ((r & 7) << 3))] = v;
    }
}

// At <- silu(acc + b)  (16 cols per wave)
__device__ __forceinline__ void epi_store(__bf16* __restrict__ At, const f32x4* __restrict__ acc,
                                          const float* __restrict__ bias, int lane, int colbase) {
    const int rl = lane & 15, rg = (lane >> 4) << 2;
    const int col = colbase + rl;
    const float bv = bias[col];
#pragma unroll
    for (int s = 0; s < 4; ++s)
#pragma unroll
        for (int j = 0; j < 4; ++j) {
            const int row = s * 16 + rg + j;
            At[row * 128 + (col ^ ((row & 7) << 3))] = (__bf16)silu_f(acc[s][j] + bv);
        }
}

// hreg += silu(acc + b); optionally At <- bf16(hreg)
template<bool WRITE>
__device__ __forceinline__ void epi_add(__bf16* __restrict__ At, f32x4* __restrict__ hreg,
                                        const f32x4* __restrict__ acc,
                                        const float* __restrict__ bias, int lane, int colbase) {
    const int rl = lane & 15, rg = (lane >> 4) << 2;
    const int col = colbase + rl;
    const float bv = bias[col];
#pragma unroll
    for (int s = 0; s < 4; ++s)
#pragma unroll
        for (int j = 0; j < 4; ++j) {
            const int row = s * 16 + rg + j;
            float v = hreg[s][j] + silu_f(acc[s][j] + bv);
            hreg[s][j] = v;
            if (WRITE) At[row * 128 + (col ^ ((row & 7) << 3))] = (__bf16)v;
        }
}

// ---------------------------------------------------------------------------
// weight prep: wcrT[128][8]; wc_sbf[42][64] f32 (fallback); wcsb fragment-order
// ---------------------------------------------------------------------------
__global__ void kweights(const float* __restrict__ W_rbf1, const float* __restrict__ W_rbf2,
                         const float* __restrict__ W_sbf1, const float* __restrict__ W_sbf2,
                         float* __restrict__ wcrT, float* __restrict__ wc_sbf,
                         __bf16* __restrict__ wcsb) {
    int tid = blockIdx.x * blockDim.x + threadIdx.x;
    int nt = blockDim.x * gridDim.x;
    for (int idx = tid; idx < 128 * 8; idx += nt) {
        int c = idx >> 3, s = idx & 7;
        float v = 0.f;
        if (s < 6) {
#pragma unroll
            for (int b = 0; b < 8; ++b) v += W_rbf1[s * 8 + b] * W_rbf2[b * 128 + c];
        }
        wcrT[idx] = v;
    }
    for (int idx = tid; idx < 42 * 64; idx += nt) {
        int r = idx / 64, c = idx - r * 64;
        float s = 0.f;
#pragma unroll
        for (int b = 0; b < 8; ++b) s += W_sbf1[r * 8 + b] * W_sbf2[b * 64 + c];
        wc_sbf[idx] = s;
    }
    // wcsb fragment order: K=64 (pad from 42), N=64, NTOT=4
    for (int idx = tid; idx < 4096; idx += nt) {
        int j = idx & 7, l = (idx >> 3) & 63, r2 = idx >> 9;
        int ct = r2 & 3, kc = r2 >> 2;
        int k = kc * 32 + ((l >> 4) << 3) + j;
        int c = ct * 16 + (l & 15);
        float v = 0.f;
        if (k < 42) {
#pragma unroll
            for (int b = 0; b < 8; ++b) v += W_sbf1[k * 8 + b] * W_sbf2[b * 64 + c];
        }
        wcsb[idx] = (__bf16)v;
    }
}

// fragment-order weight conversion
__global__ void ktrans(const float* __restrict__ W_kj, const float* __restrict__ W_ji,
                       const float* __restrict__ W_down, const float* __restrict__ W_up,
                       const float* __restrict__ W_rb, const float* __restrict__ W_lin,
                       const float* __restrict__ W_ra, __bf16* __restrict__ wt) {
    const float* src; __bf16* dst; int K, N;
    switch (blockIdx.y) {
        case 0:  src = W_kj;          dst = wt + OFF_KJ;    K = 128; N = 128; break;
        case 1:  src = W_ji;          dst = wt + OFF_JI;    K = 128; N = 128; break;
        case 2:  src = W_down;        dst = wt + OFF_DOWN;  K = 128; N = 64;  break;
        case 3:  src = W_up;          dst = wt + OFF_UP;    K = 64;  N = 128; break;
        case 4:  src = W_rb;          dst = wt + OFF_RB0;   K = 128; N = 128; break;
        case 5:  src = W_rb + 16384;  dst = wt + OFF_RB1;   K = 128; N = 128; break;
        case 6:  src = W_lin;         dst = wt + OFF_LIN;   K = 128; N = 128; break;
        case 7:  src = W_ra;          dst = wt + OFF_RA00;  K = 128; N = 128; break;
        case 8:  src = W_ra + 16384;  dst = wt + OFF_RA01;  K = 128; N = 128; break;
        case 9:  src = W_ra + 32768;  dst = wt + OFF_RA10;  K = 128; N = 128; break;
        default: src = W_ra + 49152;  dst = wt + OFF_RA11;  K = 128; N = 128; break;
    }
    const int ntot = N / 16;
    for (int i = blockIdx.x * blockDim.x + threadIdx.x; i < K * N; i += gridDim.x * blockDim.x) {
        int j = i & 7, l = (i >> 3) & 63, r2 = i >> 9;
        int ct = r2 % ntot, kc = r2 / ntot;
        int k = kc * 32 + ((l >> 4) << 3) + j;
        int n = ct * 16 + (l & 15);
        dst[i] = (__bf16)src[(size_t)k * N + n];
    }
}

// ---------------------------------------------------------------------------
// pre phase: xkd = silu( (silu(x@W_kj+b_kj) * (rbf@Wc_rbf)) @ W_down )  [E,64] bf16
// 64 rows/block, 8 waves x 16 cols
// ---------------------------------------------------------------------------
__global__ __launch_bounds__(512, 4) void kpre_m(
        const float* __restrict__ x, const float* __restrict__ rbf,
        const __bf16* __restrict__ wt, const float* __restrict__ b_kj,
        const float* __restrict__ wcrT, __bf16* __restrict__ xkd, int E) {
    __shared__ __bf16 A0[64 * 128];
    __shared__ __bf16 A1[64 * 128];
    __shared__ float rbt[64 * 8];
    const int tid = threadIdx.x, lane = tid & 63, wv = tid >> 6;
    const long r0 = (long)blockIdx.x * 64;
    if (r0 >= E) return;
    const int vr = (E - r0) < 64 ? (int)(E - r0) : 64;
    const int rl = lane & 15, rg = (lane >> 4) << 2;
    const int col = wv * 16 + rl;

    stage<128, 512>(x, r0, vr, A0, tid);
    for (int i = tid; i < 64 * 8; i += 512) {
        int r = i >> 3, s = i & 7;
        rbt[i] = (s < 6 && r < vr) ? rbf[(r0 + r) * 6 + s] : 0.f;
    }
    __syncthreads();

    f32x4 acc[4];
    wgemm<128, 4, 128, 8>(A0, wt + OFF_KJ, wv, lane, acc);

    const float bv = b_kj[col];
    float wv6[6];
#pragma unroll
    for (int s = 0; s < 6; ++s) wv6[s] = wcrT[col * 8 + s];
#pragma unroll
    for (int s = 0; s < 4; ++s)
#pragma unroll
        for (int j = 0; j < 4; ++j) {
            const int row = s * 16 + rg + j;
            float4 r4 = *(const float4*)&rbt[row * 8];
            float2 r2 = *(const float2*)&rbt[row * 8 + 4];
            float re = r4.x * wv6[0] + r4.y * wv6[1] + r4.z * wv6[2]
                     + r4.w * wv6[3] + r2.x * wv6[4] + r2.y * wv6[5];
            float v = silu_f(acc[s][j] + bv) * re;
            A1[row * 128 + (col ^ ((row & 7) << 3))] = (__bf16)v;
        }
    __syncthreads();

    // W_down: N=64, NTOT=4; waves split 2-way over row halves
    const int hw = wv >> 2, ct = wv & 3;
    f32x4 acc2[2];
    wgemm<128, 2, 128, 4>(A1 + hw * 32 * 128, wt + OFF_DOWN, ct, lane, acc2);
    const int col2 = ct * 16 + rl;
#pragma unroll
    for (int s = 0; s < 2; ++s)
#pragma unroll
        for (int j = 0; j < 4; ++j) {
            const int row = hw * 32 + s * 16 + rg + j;
            if (row < vr) xkd[(r0 + row) * 64 + col2] = (__bf16)silu_f(acc2[s][j]);
        }
}

// ---------------------------------------------------------------------------
// post phase: 9 GEMMs, 1 barrier each (A0/A1 ping-pong), 8 waves x 16 cols.
// A0 (= agg tile) is built by fused segment-sum of mperm rows (use_mperm),
// or staged from the fallback agg buffer.
// ---------------------------------------------------------------------------
__global__ __launch_bounds__(512, 4) void kpost_m(
        const float* __restrict__ x, const __bf16* __restrict__ agg,
        const __bf16* __restrict__ mperm, const int* __restrict__ rs,
        const __bf16* __restrict__ wt, const float* __restrict__ b_ji,
        const float* __restrict__ b_rb, const float* __restrict__ b_lin,
        const float* __restrict__ b_ra, float* __restrict__ out, int E,
        int use_mperm) {
    __shared__ __bf16 A0[64 * 128];
    __shared__ __bf16 A1[64 * 128];
    const int tid = threadIdx.x, lane = tid & 63, wv = tid >> 6;
    const int colbase = wv * 16;
    const long r0 = (long)blockIdx.x * 64;
    if (r0 >= E) return;
    const int vr = (E - r0) < 64 ? (int)(E - r0) : 64;
    const int rl = lane & 15, rg = (lane >> 4) << 2;
    const int col = colbase + rl;
    f32x4 acc[4], hreg[4];

    stage<128, 512>(x, r0, vr, A1, tid);

    if (use_mperm) {
        // fused kreduce: thread (e_local = tid>>3, oct = tid&7) sums its
        // bucket's contiguous mperm rows; 8 threads/row = one full 128B line.
        const int el = tid >> 3, oct = tid & 7;
        const long e = r0 + el;
        float s0[8], s1[8];
#pragma unroll
        for (int k = 0; k < 8; ++k) { s0[k] = 0.f; s1[k] = 0.f; }
        if (el < vr) {
            const int j0 = rs[e], j1 = rs[e + 1];
            const __bf16* pm = mperm + (size_t)j0 * 64 + oct * 8;
            const int n = j1 - j0;
            int j = 0;
            for (; j + 2 <= n; j += 2) {
                bf16x8 v0 = *(const bf16x8*)&pm[(size_t)j * 64];
                bf16x8 v1 = *(const bf16x8*)&pm[(size_t)(j + 1) * 64];
#pragma unroll
                for (int k = 0; k < 8; ++k) { s0[k] += (float)v0[k]; s1[k] += (float)v1[k]; }
            }
            if (j < n) {
                bf16x8 v0 = *(const bf16x8*)&pm[(size_t)j * 64];
#pragma unroll
                for (int k = 0; k < 8; ++k) s0[k] += (float)v0[k];
            }
        }
        bf16x8 w;
#pragma unroll
        for (int k = 0; k < 8; ++k) w[k] = (__bf16)(s0[k] + s1[k]);
        *(bf16x8*)&A0[el * 128 + ((oct * 8) ^ ((el & 7) << 3))] = w;
    } else {
        stage_bf<64, 512>(agg, r0, vr, A0, tid);
    }
    __syncthreads();

    // hreg = silu(agg @ W_up); acc = x @ W_ji
    wgemm<64, 4, 128, 8>(A0, wt + OFF_UP, wv, lane, acc);
#pragma unroll
    for (int i = 0; i < 4; ++i)
#pragma unroll
        for (int j = 0; j < 4; ++j) hreg[i][j] = silu_f(acc[i][j]);
    wgemm<128, 4, 128, 8>(A1, wt + OFF_JI, wv, lane, acc);
    __syncthreads();
    epi_add<true>(A0, hreg, acc, b_ji, lane, colbase);   // A0 <- h
    __syncthreads();

    // res_before
    wgemm<128, 4, 128, 8>(A0, wt + OFF_RB0, wv, lane, acc);
    epi_store(A1, acc, b_rb, lane, colbase);
    __syncthreads();
    wgemm<128, 4, 128, 8>(A1, wt + OFF_RB1, wv, lane, acc);
    epi_add<true>(A0, hreg, acc, b_rb + 128, lane, colbase);
    __syncthreads();

    // h = silu(h @ W_lin + b_lin) + x
    wgemm<128, 4, 128, 8>(A0, wt + OFF_LIN, wv, lane, acc);
    {
        const float bv = b_lin[col];
#pragma unroll
        for (int s = 0; s < 4; ++s)
#pragma unroll
            for (int j = 0; j < 4; ++j) {
                const int row = s * 16 + rg + j;
                float xv = (row < vr) ? x[(r0 + row) * 128 + col] : 0.f;
                float v = silu_f(acc[s][j] + bv) + xv;
                hreg[s][j] = v;
                A1[row * 128 + (col ^ ((row & 7) << 3))] = (__bf16)v;
            }
    }
    __syncthreads();

    // res_after layer 0
    wgemm<128, 4, 128, 8>(A1, wt + OFF_RA00, wv, lane, acc);
    epi_store(A0, acc, b_ra, lane, colbase);
    __syncthreads();
    wgemm<128, 4, 128, 8>(A0, wt + OFF_RA01, wv, lane, acc);
    epi_add<true>(A1, hreg, acc, b_ra + 128, lane, colbase);
    __syncthreads();

    // res_after layer 1
    wgemm<128, 4, 128, 8>(A1, wt + OFF_RA10, wv, lane, acc);
    epi_store(A0, acc, b_ra + 256, lane, colbase);
    __syncthreads();
    wgemm<128, 4, 128, 8>(A0, wt + OFF_RA11, wv, lane, acc);
    epi_add<false>(nullptr, hreg, acc, b_ra + 384, lane, colbase);

    // out <- hreg
#pragma unroll
    for (int s = 0; s < 4; ++s)
#pragma unroll
        for (int j = 0; j < 4; ++j) {
            const int row = s * 16 + rg + j;
            if (row < vr) out[(r0 + row) * 128 + col] = hreg[s][j];
        }
}

// ---------------------------------------------------------------------------
// CSR: histogram -> scan -> scatter (pos in t-order: coalesced writes)
// ---------------------------------------------------------------------------
__global__ void khist(const int* __restrict__ idx_ji, int* __restrict__ cnt, int T) {
    int t = blockIdx.x * blockDim.x + threadIdx.x;
    int nt = gridDim.x * blockDim.x;
    for (; t < T; t += nt) atomicAdd(&cnt[idx_ji[t]], 1);
}

__global__ __launch_bounds__(256) void kscan1(int* __restrict__ a, int* __restrict__ bsum) {
    __shared__ int sc[256];
    const int tid = threadIdx.x;
    const int base = blockIdx.x * SCHUNK + tid * 8;
    int4 p0 = *(const int4*)&a[base];
    int4 p1 = *(const int4*)&a[base + 4];
    int v[8] = {p0.x, p0.y, p0.z, p0.w, p1.x, p1.y, p1.z, p1.w};
    int s = 0;
#pragma unroll
    for (int i = 0; i < 8; ++i) s += v[i];
    sc[tid] = s;
    __syncthreads();
    for (int off = 1; off < 256; off <<= 1) {
        int t2 = (tid >= off) ? sc[tid - off] : 0;
        __syncthreads();
        sc[tid] += t2;
        __syncthreads();
    }
    int run = sc[tid] - s;
    if (tid == 255) bsum[blockIdx.x] = sc[255];
    int o[8];
#pragma unroll
    for (int i = 0; i < 8; ++i) { o[i] = run; run += v[i]; }
    *(int4*)&a[base]     = make_int4(o[0], o[1], o[2], o[3]);
    *(int4*)&a[base + 4] = make_int4(o[4], o[5], o[6], o[7]);
}

__global__ void kscan2(int* __restrict__ bsum, int nb) {
    if (threadIdx.x == 0 && blockIdx.x == 0) {
        int run = 0;
        for (int i = 0; i < nb; ++i) { int v = bsum[i]; bsum[i] = run; run += v; }
    }
}

__global__ void kscan3(int* __restrict__ a, const int* __restrict__ bsum,
                       int* __restrict__ cursor, int n) {
    int i = blockIdx.x * blockDim.x + threadIdx.x;
    if (i < n) {
        int v = a[i] + bsum[i >> 11];
        a[i] = v;
        cursor[i] = v;
    }
}

// pos[t] = destination slot of triplet t (coalesced write; atomics L2-resident)
__global__ void kscatter(const int* __restrict__ idx_ji, int* __restrict__ cursor,
                         int* __restrict__ pos, int T) {
    int t = blockIdx.x * blockDim.x + threadIdx.x;
    int nt = gridDim.x * blockDim.x;
    for (; t < T; t += nt) {
        pos[t] = atomicAdd(&cursor[idx_ji[t]], 1);
    }
}

// ---------------------------------------------------------------------------
// kperm (MFMA, t-order compute): P[128,64] = sbf_tile @ Wc;
// row written to mperm[pos[t]] -- scattered but full-128B-line (aligned) stores.
// 512 threads: 8 waves = 2 row-halves x 4 col-tiles.
// ---------------------------------------------------------------------------
__global__ __launch_bounds__(512, 4) void kperm(
        const float* __restrict__ sbf, const int* __restrict__ idx_kj,
        const int* __restrict__ pos, const __bf16* __restrict__ xkd,
        const __bf16* __restrict__ wcsb, __bf16* __restrict__ mperm, int T) {
    __shared__ __bf16 S[PCH * 64];
    __shared__ __bf16 O[PCH * 72];   // pad 72: breaks 4-row bank aliasing
    __shared__ int kidx[PCH];
    __shared__ int posv[PCH];
    const int tid = threadIdx.x, lane = tid & 63, wv = tid >> 6;
    const long p0 = (long)blockIdx.x * PCH;
    const int np = (T - p0) > PCH ? PCH : (int)(T - p0);

    for (int i = tid; i < PCH * 64 / 8; i += 512)
        *(bf16x8*)&S[i * 8] = (bf16x8){0, 0, 0, 0, 0, 0, 0, 0};
    for (int i = tid; i < PCH; i += 512) {
        kidx[i] = (i < np) ? idx_kj[p0 + i] : 0;
        posv[i] = (i < np) ? pos[p0 + i] : 0;
    }
    __syncthreads();
    for (int i = tid; i < np * 21; i += 512) {
        int posi = i / 21, q = i - posi * 21;
        float2 v = *(const float2*)&sbf[(p0 + posi) * 42 + 2 * q];
        __bf16* d = &S[posi * 64 + ((2 * q) ^ ((posi & 7) << 3))];
        d[0] = (__bf16)v.x; d[1] = (__bf16)v.y;
    }
    __syncthreads();

    const int rh = wv & 1, ct = wv >> 1;   // rh: 64-row half; ct: 16-col tile
    f32x4 acc[4];
    wgemm<64, 4, 64, 4>(S + rh * 64 * 64, wcsb, ct, lane, acc);

    const int rl = lane & 15, rg = (lane >> 4) << 2;
    const int col = ct * 16 + rl;
#pragma unroll
    for (int s = 0; s < 4; ++s)
#pragma unroll
        for (int j = 0; j < 4; ++j) {
            const int r = rh * 64 + s * 16 + rg + j;
            const int kj = kidx[r];
            float xv = (float)xkd[(size_t)kj * 64 + col];
            O[r * 72 + col] = (__bf16)(acc[s][j] * xv);
        }
    __syncthreads();

    // write-out: 8 consecutive threads cover one row = one full 128B line
    for (int i = tid; i < np * 8; i += 512) {
        int r = i >> 3, q = i & 7;
        size_t dst = (size_t)posv[r];
        *(bf16x8*)&mperm[dst * 64 + q * 8] = *(const bf16x8*)&O[r * 72 + q * 8];
    }
}

// ---------------------------------------------------------------------------
// fallback triplet kernels (atomic path) if workspace too small for mperm path
// ---------------------------------------------------------------------------
__global__ __launch_bounds__(256) void ktrip(
        const float* __restrict__ sbf, const int* __restrict__ idx_kj,
        const int* __restrict__ idx_ji, const __bf16* __restrict__ xkd,
        const float* __restrict__ wc_sbf, float* __restrict__ aggf, int T) {
    const int lane = threadIdx.x & 63;
    float wc[42];
#pragma unroll
    for (int s = 0; s < 42; ++s) wc[s] = wc_sbf[s * 64 + lane];
    const int wave = blockIdx.x * (blockDim.x >> 6) + (threadIdx.x >> 6);
    const int nw = gridDim.x * (blockDim.x >> 6);
    for (int t = wave; t < T; t += nw) {
        const float* srow = sbf + (size_t)t * 42;
        float acc = 0.f;
#pragma unroll
        for (int q = 0; q < 21; ++q) {
            float2 v = *(const float2*)&srow[q * 2];
            acc = fmaf(v.x, wc[q * 2 + 0], acc);
            acc = fmaf(v.y, wc[q * 2 + 1], acc);
        }
        int kj = idx_kj[t];
        int ji = idx_ji[t];
        float m = (float)xkd[(size_t)kj * 64 + lane] * acc;
        atomicAdd(&aggf[(size_t)ji * 64 + lane], m);
    }
}

__global__ void kcvt(const float* __restrict__ src, __bf16* __restrict__ dst, int n) {
    int i = blockIdx.x * blockDim.x + threadIdx.x;
    int nt = gridDim.x * blockDim.x;
    for (; i < n; i += nt) dst[i] = (__bf16)src[i];
}

static inline char* alignup256(char* p) {
    return (char*)(((uintptr_t)p + 255) & ~(uintptr_t)255);
}

extern "C" void kernel_launch(void* const* d_in, const int* in_sizes, int n_in,
                              void* d_out, int out_size, void* d_ws, size_t ws_size,
                              hipStream_t stream) {
    const float* x      = (const float*)d_in[0];
    const float* rbf    = (const float*)d_in[1];
    const float* sbf    = (const float*)d_in[2];
    const int*   idx_kj = (const int*)d_in[3];
    const int*   idx_ji = (const int*)d_in[4];
    const float* W_rbf1 = (const float*)d_in[5];
    const float* W_rbf2 = (const float*)d_in[6];
    const float* W_sbf1 = (const float*)d_in[7];
    const float* W_sbf2 = (const float*)d_in[8];
    const float* W_kj   = (const float*)d_in[9];
    const float* b_kj   = (const float*)d_in[10];
    const float* W_ji   = (const float*)d_in[11];
    const float* b_ji   = (const float*)d_in[12];
    const float* W_down = (const float*)d_in[13];
    const float* W_up   = (const float*)d_in[14];
    const float* W_rb   = (const float*)d_in[15];
    const float* b_rb   = (const float*)d_in[16];
    const float* W_lin  = (const float*)d_in[17];
    const float* b_lin  = (const float*)d_in[18];
    const float* W_ra   = (const float*)d_in[19];
    const float* b_ra   = (const float*)d_in[20];

    const int E = in_sizes[0] / 128;
    const int T = in_sizes[3];
    const int NB = (E + 1 + SCHUNK - 1) / SCHUNK;
    const int Epad = NB * SCHUNK;

    // 256B-aligned workspace carve-up (mperm MUST be 128B-aligned: full-line stores)
    char* p = (char*)d_ws;
    __bf16* agg  = (__bf16*)p;  p = alignup256(p + (size_t)E * 64 * 2);
    __bf16* xkd  = (__bf16*)p;  p = alignup256(p + (size_t)E * 64 * 2);
    float* wcrT  = (float*)p;   p = alignup256(p + 1024 * 4);
    float* wcs   = (float*)p;   p = alignup256(p + 2688 * 4);
    __bf16* wcsb = (__bf16*)p;  p = alignup256(p + 4096 * 2);
    __bf16* wt   = (__bf16*)p;  p = alignup256(p + (size_t)163840 * 2);
    int* rs      = (int*)p;     p = alignup256(p + (size_t)Epad * 4);
    int* cursor  = (int*)p;     p = alignup256(p + (size_t)Epad * 4);
    int* bsum    = (int*)p;     p = alignup256(p + (size_t)NB * 4);
    int* pos     = (int*)p;     p = alignup256(p + (size_t)T * 4);
    __bf16* mperm = (__bf16*)p; p = alignup256(p + (size_t)T * 64 * 2);
    const bool fits = (size_t)(p - (char*)d_ws) <= ws_size;
    // fallback f32 agg lives where mperm would be
    float* aggf = (float*)mperm;
    const bool fits_fb = (size_t)((char*)(aggf + (size_t)E * 64) - (char*)d_ws) <= ws_size;

    kweights<<<16, 256, 0, stream>>>(W_rbf1, W_rbf2, W_sbf1, W_sbf2, wcrT, wcs, wcsb);
    ktrans<<<dim3(16, 11), 256, 0, stream>>>(W_kj, W_ji, W_down, W_up, W_rb, W_lin, W_ra, wt);

    const int gE = (E + 63) / 64;
    kpre_m<<<gE, 512, 0, stream>>>(x, rbf, wt, b_kj, wcrT, xkd, E);

    if (fits) {
        hipMemsetAsync(rs, 0, (size_t)Epad * sizeof(int), stream);
        khist<<<2048, 256, 0, stream>>>(idx_ji, rs, T);
        kscan1<<<NB, 256, 0, stream>>>(rs, bsum);
        kscan2<<<1, 64, 0, stream>>>(bsum, NB);
        kscan3<<<(Epad + 255) / 256, 256, 0, stream>>>(rs, bsum, cursor, Epad);
        kscatter<<<2048, 256, 0, stream>>>(idx_ji, cursor, pos, T);
        kperm<<<(T + PCH - 1) / PCH, 512, 0, stream>>>(sbf, idx_kj, pos, xkd, wcsb, mperm, T);
        kpost_m<<<gE, 512, 0, stream>>>(x, agg, mperm, rs, wt, b_ji, b_rb, b_lin, b_ra,
                                        (float*)d_out, E, 1);
    } else if (fits_fb) {
        hipMemsetAsync(aggf, 0, (size_t)E * 64 * sizeof(float), stream);
        ktrip<<<2048, 256, 0, stream>>>(sbf, idx_kj, idx_ji, xkd, wcs, aggf, T);
        kcvt<<<2048, 256, 0, stream>>>(aggf, agg, E * 64);
        kpost_m<<<gE, 512, 0, stream>>>(x, agg, mperm, rs, wt, b_ji, b_rb, b_lin, b_ra,
                                        (float*)d_out, E, 0);
    }
}

// Round 13
// 569.178 us; speedup vs baseline: 1.7072x; 1.0446x over previous
//
#include <hip/hip_runtime.h>
#include <math.h>
#include <stdint.h>

#define SCHUNK 2048
#define PCH 128

typedef __bf16 bf16x8 __attribute__((ext_vector_type(8)));
typedef __bf16 bf16x4 __attribute__((ext_vector_type(4)));
typedef float f32x4 __attribute__((ext_vector_type(4)));

#define MFMA16(a, b, c) __builtin_amdgcn_mfma_f32_16x16x32_bf16(a, b, c, 0, 0, 0)

// weight pool offsets (elements)
#define OFF_KJ    0
#define OFF_JI    16384
#define OFF_DOWN  32768
#define OFF_UP    40960
#define OFF_RB0   49152
#define OFF_RB1   65536
#define OFF_LIN   81920
#define OFF_RA00  98304
#define OFF_RA01  114688
#define OFF_RA10  131072
#define OFF_RA11  147456

__device__ __forceinline__ float silu_f(float v) {
    return v * __builtin_amdgcn_rcpf(1.0f + __expf(-v));
}

// ---------------------------------------------------------------------------
// Wave GEMM (operand-swapped): D = Wf_frag · h_frag = (h·W)^T per 16x16 tile.
// acc[s][j]: edge = s*16 + (lane&15), outcol = ct0*16 + (lane>>4)*4 + j
//   -> each lane owns 4 CONSECUTIVE output cols of one edge row per band.
// At: LDS bf16, row stride STRIDE, swizzle (c ^ ((r&7)<<3)).
// Wf fragment order: Wf[((kc*NTOT + ct)*64 + lane)*8 + j] =
//     W[kc*32 + (lane>>4)*8 + j][ct*16 + (lane&15)]  -> 1KB coalesced per load.
// ---------------------------------------------------------------------------
template<int K, int NB, int STRIDE, int NTOT>
__device__ __forceinline__ void wgemm(const __bf16* __restrict__ At,
                                      const __bf16* __restrict__ Wf,
                                      int ct0, int lane, f32x4* __restrict__ acc) {
#pragma unroll
    for (int i = 0; i < NB; ++i) acc[i] = (f32x4){0.f, 0.f, 0.f, 0.f};
    const int rl = lane & 15;
    const int kq = (lane >> 4) * 8;
    const int sw = (rl & 7) << 3;
#pragma unroll
    for (int kc = 0; kc < K / 32; ++kc) {
        const int k0 = kc * 32 + kq;
        bf16x8 wf = *(const bf16x8*)&Wf[(size_t)((kc * NTOT + ct0) * 64 + lane) * 8];
#pragma unroll
        for (int s = 0; s < NB; ++s) {
            bf16x8 ef = *(const bf16x8*)&At[(rl + 16 * s) * STRIDE + (k0 ^ sw)];
            acc[s] = MFMA16(wf, ef, acc[s]);   // swapped: (h·W)^T fragment
        }
    }
}

// stage 64 x COLS f32 rows -> LDS bf16 swizzled tile, row stride 128
template<int COLS, int NTHR>
__device__ __forceinline__ void stage(const float* __restrict__ g, long grow0,
                                      int vr, __bf16* __restrict__ At, int tid) {
    constexpr int QUADS = COLS / 4;
#pragma unroll
    for (int i = tid; i < 64 * QUADS; i += NTHR) {
        int r = i / QUADS, q = i - r * QUADS;
        float4 v = make_float4(0.f, 0.f, 0.f, 0.f);
        if (r < vr) v = *(const float4*)&g[(grow0 + r) * (size_t)COLS + q * 4];
        bf16x4 w; w[0] = (__bf16)v.x; w[1] = (__bf16)v.y; w[2] = (__bf16)v.z; w[3] = (__bf16)v.w;
        *(bf16x4*)&At[r * 128 + ((q * 4) ^ ((r & 7) << 3))] = w;
    }
}

// stage 64 x COLS bf16 rows -> LDS swizzled tile (8-col chunks keep swizzle intact)
template<int COLS, int NTHR>
__device__ __forceinline__ void stage_bf(const __bf16* __restrict__ g, long grow0,
                                         int vr, __bf16* __restrict__ At, int tid) {
    constexpr int CH = COLS / 8;
#pragma unroll
    for (int i = tid; i < 64 * CH; i += NTHR) {
        int r = i / CH, q = i - r * CH;
        bf16x8 v = (bf16x8){0, 0, 0, 0, 0, 0, 0, 0};
        if (r < vr) v = *(const bf16x8*)&g[(grow0 + r) * (size_t)COLS + q * 8];
        *(bf16x8*)&At[r * 128 + ((q * 8) ^ ((r & 7) << 3))] = v;
    }
}

// At <- silu(acc + b)  -- row-fragment layout: bf16x4 store per band
__device__ __forceinline__ void epi_store(__bf16* __restrict__ At, const f32x4* __restrict__ acc,
                                          const float* __restrict__ bias, int lane, int colbase) {
    const int rl = lane & 15, rg = (lane >> 4) << 2;
    const int cb = colbase + rg;
    const float4 bv = *(const float4*)&bias[cb];
#pragma unroll
    for (int s = 0; s < 4; ++s) {
        const int el = s * 16 + rl;
        bf16x4 w;
        w[0] = (__bf16)silu_f(acc[s][0] + bv.x);
        w[1] = (__bf16)silu_f(acc[s][1] + bv.y);
        w[2] = (__bf16)silu_f(acc[s][2] + bv.z);
        w[3] = (__bf16)silu_f(acc[s][3] + bv.w);
        *(bf16x4*)&At[el * 128 + (cb ^ ((el & 7) << 3))] = w;
    }
}

// hreg += silu(acc + b); optionally At <- bf16(hreg)
template<bool WRITE>
__device__ __forceinline__ void epi_add(__bf16* __restrict__ At, f32x4* __restrict__ hreg,
                                        const f32x4* __restrict__ acc,
                                        const float* __restrict__ bias, int lane, int colbase) {
    const int rl = lane & 15, rg = (lane >> 4) << 2;
    const int cb = colbase + rg;
    const float4 bv = *(const float4*)&bias[cb];
#pragma unroll
    for (int s = 0; s < 4; ++s) {
        const int el = s * 16 + rl;
        float v0 = hreg[s][0] + silu_f(acc[s][0] + bv.x);
        float v1 = hreg[s][1] + silu_f(acc[s][1] + bv.y);
        float v2 = hreg[s][2] + silu_f(acc[s][2] + bv.z);
        float v3 = hreg[s][3] + silu_f(acc[s][3] + bv.w);
        hreg[s][0] = v0; hreg[s][1] = v1; hreg[s][2] = v2; hreg[s][3] = v3;
        if (WRITE) {
            bf16x4 w; w[0] = (__bf16)v0; w[1] = (__bf16)v1; w[2] = (__bf16)v2; w[3] = (__bf16)v3;
            *(bf16x4*)&At[el * 128 + (cb ^ ((el & 7) << 3))] = w;
        }
    }
}

// ---------------------------------------------------------------------------
// weight prep: wcrT[128][8]; wc_sbf[42][64] f32 (fallback); wcsb fragment-order
// ---------------------------------------------------------------------------
__global__ void kweights(const float* __restrict__ W_rbf1, const float* __restrict__ W_rbf2,
                         const float* __restrict__ W_sbf1, const float* __restrict__ W_sbf2,
                         float* __restrict__ wcrT, float* __restrict__ wc_sbf,
                         __bf16* __restrict__ wcsb) {
    int tid = blockIdx.x * blockDim.x + threadIdx.x;
    int nt = blockDim.x * gridDim.x;
    for (int idx = tid; idx < 128 * 8; idx += nt) {
        int c = idx >> 3, s = idx & 7;
        float v = 0.f;
        if (s < 6) {
#pragma unroll
            for (int b = 0; b < 8; ++b) v += W_rbf1[s * 8 + b] * W_rbf2[b * 128 + c];
        }
        wcrT[idx] = v;
    }
    for (int idx = tid; idx < 42 * 64; idx += nt) {
        int r = idx / 64, c = idx - r * 64;
        float s = 0.f;
#pragma unroll
        for (int b = 0; b < 8; ++b) s += W_sbf1[r * 8 + b] * W_sbf2[b * 64 + c];
        wc_sbf[idx] = s;
    }
    // wcsb fragment order: K=64 (pad from 42), N=64, NTOT=4
    for (int idx = tid; idx < 4096; idx += nt) {
        int j = idx & 7, l = (idx >> 3) & 63, r2 = idx >> 9;
        int ct = r2 & 3, kc = r2 >> 2;
        int k = kc * 32 + ((l >> 4) << 3) + j;
        int c = ct * 16 + (l & 15);
        float v = 0.f;
        if (k < 42) {
#pragma unroll
            for (int b = 0; b < 8; ++b) v += W_sbf1[k * 8 + b] * W_sbf2[b * 64 + c];
        }
        wcsb[idx] = (__bf16)v;
    }
}

// fragment-order weight conversion
__global__ void ktrans(const float* __restrict__ W_kj, const float* __restrict__ W_ji,
                       const float* __restrict__ W_down, const float* __restrict__ W_up,
                       const float* __restrict__ W_rb, const float* __restrict__ W_lin,
                       const float* __restrict__ W_ra, __bf16* __restrict__ wt) {
    const float* src; __bf16* dst; int K, N;
    switch (blockIdx.y) {
        case 0:  src = W_kj;          dst = wt + OFF_KJ;    K = 128; N = 128; break;
        case 1:  src = W_ji;          dst = wt + OFF_JI;    K = 128; N = 128; break;
        case 2:  src = W_down;        dst = wt + OFF_DOWN;  K = 128; N = 64;  break;
        case 3:  src = W_up;          dst = wt + OFF_UP;    K = 64;  N = 128; break;
        case 4:  src = W_rb;          dst = wt + OFF_RB0;   K = 128; N = 128; break;
        case 5:  src = W_rb + 16384;  dst = wt + OFF_RB1;   K = 128; N = 128; break;
        case 6:  src = W_lin;         dst = wt + OFF_LIN;   K = 128; N = 128; break;
        case 7:  src = W_ra;          dst = wt + OFF_RA00;  K = 128; N = 128; break;
        case 8:  src = W_ra + 16384;  dst = wt + OFF_RA01;  K = 128; N = 128; break;
        case 9:  src = W_ra + 32768;  dst = wt + OFF_RA10;  K = 128; N = 128; break;
        default: src = W_ra + 49152;  dst = wt + OFF_RA11;  K = 128; N = 128; break;
    }
    const int ntot = N / 16;
    for (int i = blockIdx.x * blockDim.x + threadIdx.x; i < K * N; i += gridDim.x * blockDim.x) {
        int j = i & 7, l = (i >> 3) & 63, r2 = i >> 9;
        int ct = r2 % ntot, kc = r2 / ntot;
        int k = kc * 32 + ((l >> 4) << 3) + j;
        int n = ct * 16 + (l & 15);
        dst[i] = (__bf16)src[(size_t)k * N + n];
    }
}

// ---------------------------------------------------------------------------
// pre phase: xkd = silu( (silu(x@W_kj+b_kj) * (rbf@Wc_rbf)) @ W_down )  [E,64] bf16
// ---------------------------------------------------------------------------
__global__ __launch_bounds__(512, 4) void kpre_m(
        const float* __restrict__ x, const float* __restrict__ rbf,
        const __bf16* __restrict__ wt, const float* __restrict__ b_kj,
        const float* __restrict__ wcrT, __bf16* __restrict__ xkd, int E) {
    __shared__ __bf16 A0[64 * 128];
    __shared__ __bf16 A1[64 * 128];
    __shared__ float rbt[64 * 8];
    const int tid = threadIdx.x, lane = tid & 63, wv = tid >> 6;
    const int colbase = wv * 16;
    const long r0 = (long)blockIdx.x * 64;
    if (r0 >= E) return;
    const int vr = (E - r0) < 64 ? (int)(E - r0) : 64;
    const int rl = lane & 15, rg = (lane >> 4) << 2;
    const int cb = colbase + rg;

    stage<128, 512>(x, r0, vr, A0, tid);
    for (int i = tid; i < 64 * 8; i += 512) {
        int r = i >> 3, s = i & 7;
        rbt[i] = (s < 6 && r < vr) ? rbf[(r0 + r) * 6 + s] : 0.f;
    }
    __syncthreads();

    f32x4 acc[4];
    wgemm<128, 4, 128, 8>(A0, wt + OFF_KJ, wv, lane, acc);

    const float4 bv = *(const float4*)&b_kj[cb];
    float wcr[4][6];
#pragma unroll
    for (int j = 0; j < 4; ++j) {
        float4 a4 = *(const float4*)&wcrT[(cb + j) * 8];
        float2 a2 = *(const float2*)&wcrT[(cb + j) * 8 + 4];
        wcr[j][0] = a4.x; wcr[j][1] = a4.y; wcr[j][2] = a4.z;
        wcr[j][3] = a4.w; wcr[j][4] = a2.x; wcr[j][5] = a2.y;
    }
#pragma unroll
    for (int s = 0; s < 4; ++s) {
        const int el = s * 16 + rl;
        float4 r4 = *(const float4*)&rbt[el * 8];
        float2 r2 = *(const float2*)&rbt[el * 8 + 4];
        float bb[4] = {bv.x, bv.y, bv.z, bv.w};
        bf16x4 w;
#pragma unroll
        for (int j = 0; j < 4; ++j) {
            float re = r4.x * wcr[j][0] + r4.y * wcr[j][1] + r4.z * wcr[j][2]
                     + r4.w * wcr[j][3] + r2.x * wcr[j][4] + r2.y * wcr[j][5];
            w[j] = (__bf16)(silu_f(acc[s][j] + bb[j]) * re);
        }
        *(bf16x4*)&A1[el * 128 + (cb ^ ((el & 7) << 3))] = w;
    }
    __syncthreads();

    // W_down: N=64, NTOT=4; waves split 2-way over row halves
    const int hw = wv >> 2, ct = wv & 3;
    const int cb2 = ct * 16 + rg;
    f32x4 acc2[2];
    wgemm<128, 2, 128, 4>(A1 + hw * 32 * 128, wt + OFF_DOWN, ct, lane, acc2);
#pragma unroll
    for (int s = 0; s < 2; ++s) {
        const int el = hw * 32 + s * 16 + rl;
        if (el < vr) {
            bf16x4 w;
#pragma unroll
            for (int j = 0; j < 4; ++j) w[j] = (__bf16)silu_f(acc2[s][j]);
            *(bf16x4*)&xkd[(r0 + el) * 64 + cb2] = w;
        }
    }
}

// ---------------------------------------------------------------------------
// post phase: 9 GEMMs, 1 barrier each (A0/A1 ping-pong), 8 waves x 16 cols.
// A0 (= agg tile) built by fused segment-sum of mperm rows (use_mperm) or staged.
// ---------------------------------------------------------------------------
__global__ __launch_bounds__(512, 4) void kpost_m(
        const float* __restrict__ x, const __bf16* __restrict__ agg,
        const __bf16* __restrict__ mperm, const int* __restrict__ rs,
        const __bf16* __restrict__ wt, const float* __restrict__ b_ji,
        const float* __restrict__ b_rb, const float* __restrict__ b_lin,
        const float* __restrict__ b_ra, float* __restrict__ out, int E,
        int use_mperm) {
    __shared__ __bf16 A0[64 * 128];
    __shared__ __bf16 A1[64 * 128];
    const int tid = threadIdx.x, lane = tid & 63, wv = tid >> 6;
    const int colbase = wv * 16;
    const long r0 = (long)blockIdx.x * 64;
    if (r0 >= E) return;
    const int vr = (E - r0) < 64 ? (int)(E - r0) : 64;
    const int rl = lane & 15, rg = (lane >> 4) << 2;
    const int cb = colbase + rg;
    f32x4 acc[4], hreg[4];

    stage<128, 512>(x, r0, vr, A1, tid);

    if (use_mperm) {
        // fused kreduce: thread (el = tid>>3, oct = tid&7) sums its bucket's
        // contiguous mperm rows; 8 threads/row = one full 128B line.
        const int el = tid >> 3, oct = tid & 7;
        const long e = r0 + el;
        float s0[8], s1[8];
#pragma unroll
        for (int k = 0; k < 8; ++k) { s0[k] = 0.f; s1[k] = 0.f; }
        if (el < vr) {
            const int j0 = rs[e], j1 = rs[e + 1];
            const __bf16* pm = mperm + (size_t)j0 * 64 + oct * 8;
            const int n = j1 - j0;
            int j = 0;
            for (; j + 2 <= n; j += 2) {
                bf16x8 v0 = *(const bf16x8*)&pm[(size_t)j * 64];
                bf16x8 v1 = *(const bf16x8*)&pm[(size_t)(j + 1) * 64];
#pragma unroll
                for (int k = 0; k < 8; ++k) { s0[k] += (float)v0[k]; s1[k] += (float)v1[k]; }
            }
            if (j < n) {
                bf16x8 v0 = *(const bf16x8*)&pm[(size_t)j * 64];
#pragma unroll
                for (int k = 0; k < 8; ++k) s0[k] += (float)v0[k];
            }
        }
        bf16x8 w;
#pragma unroll
        for (int k = 0; k < 8; ++k) w[k] = (__bf16)(s0[k] + s1[k]);
        *(bf16x8*)&A0[el * 128 + ((oct * 8) ^ ((el & 7) << 3))] = w;
    } else {
        stage_bf<64, 512>(agg, r0, vr, A0, tid);
    }
    __syncthreads();

    // hreg = silu(agg @ W_up); acc = x @ W_ji
    wgemm<64, 4, 128, 8>(A0, wt + OFF_UP, wv, lane, acc);
#pragma unroll
    for (int i = 0; i < 4; ++i)
#pragma unroll
        for (int j = 0; j < 4; ++j) hreg[i][j] = silu_f(acc[i][j]);
    wgemm<128, 4, 128, 8>(A1, wt + OFF_JI, wv, lane, acc);
    __syncthreads();
    epi_add<true>(A0, hreg, acc, b_ji, lane, colbase);   // A0 <- h
    __syncthreads();

    // res_before
    wgemm<128, 4, 128, 8>(A0, wt + OFF_RB0, wv, lane, acc);
    epi_store(A1, acc, b_rb, lane, colbase);
    __syncthreads();
    wgemm<128, 4, 128, 8>(A1, wt + OFF_RB1, wv, lane, acc);
    epi_add<true>(A0, hreg, acc, b_rb + 128, lane, colbase);
    __syncthreads();

    // h = silu(h @ W_lin + b_lin) + x
    wgemm<128, 4, 128, 8>(A0, wt + OFF_LIN, wv, lane, acc);
    {
        const float4 bv = *(const float4*)&b_lin[cb];
        const float bb[4] = {bv.x, bv.y, bv.z, bv.w};
#pragma unroll
        for (int s = 0; s < 4; ++s) {
            const int el = s * 16 + rl;
            float4 xv = make_float4(0.f, 0.f, 0.f, 0.f);
            if (el < vr) xv = *(const float4*)&x[(r0 + el) * 128 + cb];
            const float xx[4] = {xv.x, xv.y, xv.z, xv.w};
            bf16x4 w;
#pragma unroll
            for (int j = 0; j < 4; ++j) {
                float v = silu_f(acc[s][j] + bb[j]) + xx[j];
                hreg[s][j] = v;
                w[j] = (__bf16)v;
            }
            *(bf16x4*)&A1[el * 128 + (cb ^ ((el & 7) << 3))] = w;
        }
    }
    __syncthreads();

    // res_after layer 0
    wgemm<128, 4, 128, 8>(A1, wt + OFF_RA00, wv, lane, acc);
    epi_store(A0, acc, b_ra, lane, colbase);
    __syncthreads();
    wgemm<128, 4, 128, 8>(A0, wt + OFF_RA01, wv, lane, acc);
    epi_add<true>(A1, hreg, acc, b_ra + 128, lane, colbase);
    __syncthreads();

    // res_after layer 1
    wgemm<128, 4, 128, 8>(A1, wt + OFF_RA10, wv, lane, acc);
    epi_store(A0, acc, b_ra + 256, lane, colbase);
    __syncthreads();
    wgemm<128, 4, 128, 8>(A0, wt + OFF_RA11, wv, lane, acc);
    epi_add<false>(nullptr, hreg, acc, b_ra + 384, lane, colbase);

    // out <- hreg (float4 per band)
#pragma unroll
    for (int s = 0; s < 4; ++s) {
        const int el = s * 16 + rl;
        if (el < vr) *(f32x4*)&out[(r0 + el) * 128 + cb] = hreg[s];
    }
}

// ---------------------------------------------------------------------------
// CSR: histogram -> scan -> scatter (pos in t-order: coalesced writes)
// ---------------------------------------------------------------------------
__global__ void khist(const int* __restrict__ idx_ji, int* __restrict__ cnt, int T) {
    int t = blockIdx.x * blockDim.x + threadIdx.x;
    int nt = gridDim.x * blockDim.x;
    for (; t < T; t += nt) atomicAdd(&cnt[idx_ji[t]], 1);
}

__global__ __launch_bounds__(256) void kscan1(int* __restrict__ a, int* __restrict__ bsum) {
    __shared__ int sc[256];
    const int tid = threadIdx.x;
    const int base = blockIdx.x * SCHUNK + tid * 8;
    int4 p0 = *(const int4*)&a[base];
    int4 p1 = *(const int4*)&a[base + 4];
    int v[8] = {p0.x, p0.y, p0.z, p0.w, p1.x, p1.y, p1.z, p1.w};
    int s = 0;
#pragma unroll
    for (int i = 0; i < 8; ++i) s += v[i];
    sc[tid] = s;
    __syncthreads();
    for (int off = 1; off < 256; off <<= 1) {
        int t2 = (tid >= off) ? sc[tid - off] : 0;
        __syncthreads();
        sc[tid] += t2;
        __syncthreads();
    }
    int run = sc[tid] - s;
    if (tid == 255) bsum[blockIdx.x] = sc[255];
    int o[8];
#pragma unroll
    for (int i = 0; i < 8; ++i) { o[i] = run; run += v[i]; }
    *(int4*)&a[base]     = make_int4(o[0], o[1], o[2], o[3]);
    *(int4*)&a[base + 4] = make_int4(o[4], o[5], o[6], o[7]);
}

__global__ void kscan2(int* __restrict__ bsum, int nb) {
    if (threadIdx.x == 0 && blockIdx.x == 0) {
        int run = 0;
        for (int i = 0; i < nb; ++i) { int v = bsum[i]; bsum[i] = run; run += v; }
    }
}

__global__ void kscan3(int* __restrict__ a, const int* __restrict__ bsum,
                       int* __restrict__ cursor, int n) {
    int i = blockIdx.x * blockDim.x + threadIdx.x;
    if (i < n) {
        int v = a[i] + bsum[i >> 11];
        a[i] = v;
        cursor[i] = v;
    }
}

// pos[t] = destination slot of triplet t (coalesced write; atomics L2-resident)
__global__ void kscatter(const int* __restrict__ idx_ji, int* __restrict__ cursor,
                         int* __restrict__ pos, int T) {
    int t = blockIdx.x * blockDim.x + threadIdx.x;
    int nt = gridDim.x * blockDim.x;
    for (; t < T; t += nt) {
        pos[t] = atomicAdd(&cursor[idx_ji[t]], 1);
    }
}

// ---------------------------------------------------------------------------
// kperm (MFMA, t-order compute): P[128,64] = sbf_tile @ Wc;
// row written to mperm[pos[t]] -- scattered but full-128B-line (aligned) stores.
// 512 threads: 8 waves = 2 row-halves x 4 col-tiles.
// ---------------------------------------------------------------------------
__global__ __launch_bounds__(512, 4) void kperm(
        const float* __restrict__ sbf, const int* __restrict__ idx_kj,
        const int* __restrict__ pos, const __bf16* __restrict__ xkd,
        const __bf16* __restrict__ wcsb, __bf16* __restrict__ mperm, int T) {
    __shared__ __bf16 S[PCH * 64];
    __shared__ __bf16 O[PCH * 72];   // pad 72: breaks 4-row bank aliasing
    __shared__ int kidx[PCH];
    __shared__ int posv[PCH];
    const int tid = threadIdx.x, lane = tid & 63, wv = tid >> 6;
    const long p0 = (long)blockIdx.x * PCH;
    const int np = (T - p0) > PCH ? PCH : (int)(T - p0);

    for (int i = tid; i < PCH * 64 / 8; i += 512)
        *(bf16x8*)&S[i * 8] = (bf16x8){0, 0, 0, 0, 0, 0, 0, 0};
    for (int i = tid; i < PCH; i += 512) {
        kidx[i] = (i < np) ? idx_kj[p0 + i] : 0;
        posv[i] = (i < np) ? pos[p0 + i] : 0;
    }
    __syncthreads();
    for (int i = tid; i < np * 21; i += 512) {
        int posi = i / 21, q = i - posi * 21;
        float2 v = *(const float2*)&sbf[(p0 + posi) * 42 + 2 * q];
        __bf16* d = &S[posi * 64 + ((2 * q) ^ ((posi & 7) << 3))];
        d[0] = (__bf16)v.x; d[1] = (__bf16)v.y;
    }
    __syncthreads();

    const int rh = wv & 1, ct = wv >> 1;   // rh: 64-row half; ct: 16-col tile
    f32x4 acc[4];
    wgemm<64, 4, 64, 4>(S + rh * 64 * 64, wcsb, ct, lane, acc);

    const int rl = lane & 15, rg = (lane >> 4) << 2;
    const int cb = ct * 16 + rg;
#pragma unroll
    for (int s = 0; s < 4; ++s) {
        const int r = rh * 64 + s * 16 + rl;
        const int kj = kidx[r];
        bf16x4 xk = *(const bf16x4*)&xkd[(size_t)kj * 64 + cb];
        bf16x4 w;
#pragma unroll
        for (int j = 0; j < 4; ++j) w[j] = (__bf16)(acc[s][j] * (float)xk[j]);
        *(bf16x4*)&O[r * 72 + cb] = w;
    }
    __syncthreads();

    // write-out: 8 consecutive threads cover one row = one full 128B line
    for (int i = tid; i < np * 8; i += 512) {
        int r = i >> 3, q = i & 7;
        size_t dst = (size_t)posv[r];
        *(bf16x8*)&mperm[dst * 64 + q * 8] = *(const bf16x8*)&O[r * 72 + q * 8];
    }
}

// ---------------------------------------------------------------------------
// fallback triplet kernels (atomic path) if workspace too small for mperm path
// ---------------------------------------------------------------------------
__global__ __launch_bounds__(256) void ktrip(
        const float* __restrict__ sbf, const int* __restrict__ idx_kj,
        const int* __restrict__ idx_ji, const __bf16* __restrict__ xkd,
        const float* __restrict__ wc_sbf, float* __restrict__ aggf, int T) {
    const int lane = threadIdx.x & 63;
    float wc[42];
#pragma unroll
    for (int s = 0; s < 42; ++s) wc[s] = wc_sbf[s * 64 + lane];
    const int wave = blockIdx.x * (blockDim.x >> 6) + (threadIdx.x >> 6);
    const int nw = gridDim.x * (blockDim.x >> 6);
    for (int t = wave; t < T; t += nw) {
        const float* srow = sbf + (size_t)t * 42;
        float acc = 0.f;
#pragma unroll
        for (int q = 0; q < 21; ++q) {
            float2 v = *(const float2*)&srow[q * 2];
            acc = fmaf(v.x, wc[q * 2 + 0], acc);
            acc = fmaf(v.y, wc[q * 2 + 1], acc);
        }
        int kj = idx_kj[t];
        int ji = idx_ji[t];
        float m = (float)xkd[(size_t)kj * 64 + lane] * acc;
        atomicAdd(&aggf[(size_t)ji * 64 + lane], m);
    }
}

__global__ void kcvt(const float* __restrict__ src, __bf16* __restrict__ dst, int n) {
    int i = blockIdx.x * blockDim.x + threadIdx.x;
    int nt = gridDim.x * blockDim.x;
    for (; i < n; i += nt) dst[i] = (__bf16)src[i];
}

static inline char* alignup256(char* p) {
    return (char*)(((uintptr_t)p + 255) & ~(uintptr_t)255);
}

extern "C" void kernel_launch(void* const* d_in, const int* in_sizes, int n_in,
                              void* d_out, int out_size, void* d_ws, size_t ws_size,
                              hipStream_t stream) {
    const float* x      = (const float*)d_in[0];
    const float* rbf    = (const float*)d_in[1];
    const float* sbf    = (const float*)d_in[2];
    const int*   idx_kj = (const int*)d_in[3];
    const int*   idx_ji = (const int*)d_in[4];
    const float* W_rbf1 = (const float*)d_in[5];
    const float* W_rbf2 = (const float*)d_in[6];
    const float* W_sbf1 = (const float*)d_in[7];
    const float* W_sbf2 = (const float*)d_in[8];
    const float* W_kj   = (const float*)d_in[9];
    const float* b_kj   = (const float*)d_in[10];
    const float* W_ji   = (const float*)d_in[11];
    const float* b_ji   = (const float*)d_in[12];
    const float* W_down = (const float*)d_in[13];
    const float* W_up   = (const float*)d_in[14];
    const float* W_rb   = (const float*)d_in[15];
    const float* b_rb   = (const float*)d_in[16];
    const float* W_lin  = (const float*)d_in[17];
    const float* b_lin  = (const float*)d_in[18];
    const float* W_ra   = (const float*)d_in[19];
    const float* b_ra   = (const float*)d_in[20];

    const int E = in_sizes[0] / 128;
    const int T = in_sizes[3];
    const int NB = (E + 1 + SCHUNK - 1) / SCHUNK;
    const int Epad = NB * SCHUNK;

    // 256B-aligned workspace carve-up (mperm MUST be 128B-aligned: full-line stores)
    char* p = (char*)d_ws;
    __bf16* agg  = (__bf16*)p;  p = alignup256(p + (size_t)E * 64 * 2);
    __bf16* xkd  = (__bf16*)p;  p = alignup256(p + (size_t)E * 64 * 2);
    float* wcrT  = (float*)p;   p = alignup256(p + 1024 * 4);
    float* wcs   = (float*)p;   p = alignup256(p + 2688 * 4);
    __bf16* wcsb = (__bf16*)p;  p = alignup256(p + 4096 * 2);
    __bf16* wt   = (__bf16*)p;  p = alignup256(p + (size_t)163840 * 2);
    int* rs      = (int*)p;     p = alignup256(p + (size_t)Epad * 4);
    int* cursor  = (int*)p;     p = alignup256(p + (size_t)Epad * 4);
    int* bsum    = (int*)p;     p = alignup256(p + (size_t)NB * 4);
    int* pos     = (int*)p;     p = alignup256(p + (size_t)T * 4);
    __bf16* mperm = (__bf16*)p; p = alignup256(p + (size_t)T * 64 * 2);
    const bool fits = (size_t)(p - (char*)d_ws) <= ws_size;
    // fallback f32 agg lives where mperm would be
    float* aggf = (float*)mperm;
    const bool fits_fb = (size_t)((char*)(aggf + (size_t)E * 64) - (char*)d_ws) <= ws_size;

    kweights<<<16, 256, 0, stream>>>(W_rbf1, W_rbf2, W_sbf1, W_sbf2, wcrT, wcs, wcsb);
    ktrans<<<dim3(16, 11), 256, 0, stream>>>(W_kj, W_ji, W_down, W_up, W_rb, W_lin, W_ra, wt);

    const int gE = (E + 63) / 64;
    kpre_m<<<gE, 512, 0, stream>>>(x, rbf, wt, b_kj, wcrT, xkd, E);

    if (fits) {
        hipMemsetAsync(rs, 0, (size_t)Epad * sizeof(int), stream);
        khist<<<2048, 256, 0, stream>>>(idx_ji, rs, T);
        kscan1<<<NB, 256, 0, stream>>>(rs, bsum);
        kscan2<<<1, 64, 0, stream>>>(bsum, NB);
        kscan3<<<(Epad + 255) / 256, 256, 0, stream>>>(rs, bsum, cursor, Epad);
        kscatter<<<2048, 256, 0, stream>>>(idx_ji, cursor, pos, T);
        kperm<<<(T + PCH - 1) / PCH, 512, 0, stream>>>(sbf, idx_kj, pos, xkd, wcsb, mperm, T);
        kpost_m<<<gE, 512, 0, stream>>>(x, agg, mperm, rs, wt, b_ji, b_rb, b_lin, b_ra,
                                        (float*)d_out, E, 1);
    } else if (fits_fb) {
        hipMemsetAsync(aggf, 0, (size_t)E * 64 * sizeof(float), stream);
        ktrip<<<2048, 256, 0, stream>>>(sbf, idx_kj, idx_ji, xkd, wcs, aggf, T);
        kcvt<<<2048, 256, 0, stream>>>(aggf, agg, E * 64);
        kpost_m<<<gE, 512, 0, stream>>>(x, agg, mperm, rs, wt, b_ji, b_rb, b_lin, b_ra,
                                        (float*)d_out, E, 0);
    }
}